// Round 1
// baseline (4181.340 us; speedup 1.0000x reference)
//
#include <hip/hip_runtime.h>
#include <cstdint>
#include <cstddef>

#define NU 500000
#define NI 50000
#define NE 1000000
#define HC 128   // H*C
#define NH 4

// ---------------------------------------------------------------------------
// Generic row GEMM: out[M,N] = act(in[M,K] @ W[K,N] + b[N])
// blockDim = (N, 256/N). W staged in dynamic LDS once per block; grid-stride rows.
// ---------------------------------------------------------------------------
__global__ void gemm_rows(const float* __restrict__ in, const float* __restrict__ W,
                          const float* __restrict__ b, float* __restrict__ out,
                          int M, int K, int N, int act)
{
    extern __shared__ float Wlds[];
    const int nthreads = blockDim.x * blockDim.y;
    const int tid = threadIdx.y * blockDim.x + threadIdx.x;
    for (int i = tid; i < K * N; i += nthreads) Wlds[i] = W[i];
    __syncthreads();

    const int rpb = blockDim.y;
    const int c = threadIdx.x;
    const float bias = b[c];

    for (int row = blockIdx.x * rpb + threadIdx.y; row < M; row += gridDim.x * rpb) {
        const float* inr = in + (size_t)row * K;
        float acc = bias;
        #pragma unroll 4
        for (int k = 0; k < K; ++k) acc = fmaf(inr[k], Wlds[k * N + c], acc);
        if (act == 1) acc = fmaxf(acc, 0.f);
        out[(size_t)row * N + c] = acc;
    }
}

// ---------------------------------------------------------------------------
// Edge pass 1: per-edge per-head score e -> ex = exp(e); atomicAdd denominator.
// One wave (64 lanes) per edge; lane handles channels 2l, 2l+1.
// Head h = channels [32h,32h+32) = lanes [16h,16h+16).
// ---------------------------------------------------------------------------
__global__ void edge_score(const float* __restrict__ xl, const float* __restrict__ xr,
                           const int* __restrict__ srcI, const int* __restrict__ dstI,
                           const float* __restrict__ eattr, const float* __restrict__ We,
                           const float* __restrict__ att,
                           float* __restrict__ ex_out, float* __restrict__ s_acc,
                           int E, int hasE)
{
    __shared__ float attL[HC];
    __shared__ float WeL[3 * HC];
    const int tid = threadIdx.x;
    if (tid < HC) attL[tid] = att[tid];
    if (hasE) {
        for (int i = tid; i < 3 * HC; i += blockDim.x) WeL[i] = We[i];
    }
    __syncthreads();

    const int lane = tid & 63;
    const int wid = tid >> 6;
    const int wavesTotal = (gridDim.x * blockDim.x) >> 6;
    const int ch = lane * 2;
    const float a0c = attL[ch], a1c = attL[ch + 1];

    for (int e = blockIdx.x * (blockDim.x >> 6) + wid; e < E; e += wavesTotal) {
        const int s = srcI[e];
        const int d = dstI[e];
        const float2 vl = *(const float2*)(xl + (size_t)s * HC + ch);
        const float2 vr = *(const float2*)(xr + (size_t)d * HC + ch);
        float h0 = vl.x + vr.x;
        float h1 = vl.y + vr.y;
        if (hasE) {
            const float e0 = eattr[(size_t)e * 3 + 0];
            const float e1 = eattr[(size_t)e * 3 + 1];
            const float e2 = eattr[(size_t)e * 3 + 2];
            h0 += e0 * WeL[ch]     + e1 * WeL[HC + ch]     + e2 * WeL[2 * HC + ch];
            h1 += e0 * WeL[ch + 1] + e1 * WeL[HC + ch + 1] + e2 * WeL[2 * HC + ch + 1];
        }
        const float l0 = h0 > 0.f ? h0 : 0.2f * h0;
        const float l1 = h1 > 0.f ? h1 : 0.2f * h1;
        float p = l0 * a0c + l1 * a1c;
        // reduce across the 16 lanes of this head
        p += __shfl_xor(p, 8, 16);
        p += __shfl_xor(p, 4, 16);
        p += __shfl_xor(p, 2, 16);
        p += __shfl_xor(p, 1, 16);
        if ((lane & 15) == 0) {
            const int h = lane >> 4;
            const float ex = expf(p);
            ex_out[(size_t)e * NH + h] = ex;
            atomicAdd(&s_acc[(size_t)d * NH + h], ex);
        }
    }
}

// ---------------------------------------------------------------------------
// Edge pass 2: alpha = ex / (s[dst]+eps); acc[dst] += alpha * xl[src]
// ---------------------------------------------------------------------------
__global__ void edge_aggr(const float* __restrict__ xl,
                          const int* __restrict__ srcI, const int* __restrict__ dstI,
                          const float* __restrict__ ex_in, const float* __restrict__ s_acc,
                          float* __restrict__ acc, int E)
{
    const int tid = threadIdx.x;
    const int lane = tid & 63;
    const int wid = tid >> 6;
    const int wavesTotal = (gridDim.x * blockDim.x) >> 6;
    const int ch = lane * 2;
    const int h = lane >> 4;

    for (int e = blockIdx.x * (blockDim.x >> 6) + wid; e < E; e += wavesTotal) {
        const int s = srcI[e];
        const int d = dstI[e];
        const float alpha = ex_in[(size_t)e * NH + h] /
                            (s_acc[(size_t)d * NH + h] + 1e-16f);
        const float2 v = *(const float2*)(xl + (size_t)s * HC + ch);
        atomicAdd(&acc[(size_t)d * HC + ch],     alpha * v.x);
        atomicAdd(&acc[(size_t)d * HC + ch + 1], alpha * v.y);
    }
}

// ---------------------------------------------------------------------------
// Elementwise: x = relu(x + bias[col])
// ---------------------------------------------------------------------------
__global__ void bias_relu_k(float* __restrict__ x, const float* __restrict__ b, int n)
{
    for (int i = blockIdx.x * blockDim.x + threadIdx.x; i < n;
         i += gridDim.x * blockDim.x) {
        x[i] = fmaxf(x[i] + b[i & (HC - 1)], 0.f);
    }
}

// ---------------------------------------------------------------------------
// Classifier: per user row r (one wave each):
//   x = uacc[r] + c2_bias ; hid_j = relu(x . W1[:,j] + b1[j]) (lane j)
//   score = sigmoid(hid . W2 + b2)
// ---------------------------------------------------------------------------
__global__ void classifier_k(const float* __restrict__ uacc, const float* __restrict__ c2bias,
                             const float* __restrict__ W1, const float* __restrict__ b1,
                             const float* __restrict__ W2, const float* __restrict__ b2,
                             float* __restrict__ out, int M)
{
    __shared__ float W1L[HC * 64];
    __shared__ float W2L[64];
    __shared__ float bL[HC];
    const int tid = threadIdx.x;
    for (int i = tid; i < HC * 64; i += blockDim.x) W1L[i] = W1[i];
    if (tid < 64) W2L[tid] = W2[tid];
    if (tid < HC) bL[tid] = c2bias[tid];
    __syncthreads();

    const int lane = tid & 63;
    const int wid = tid >> 6;
    const int wavesTotal = (gridDim.x * blockDim.x) >> 6;
    const float b1v = b1[lane];
    const float b2v = b2[0];
    const float w2v = W2L[lane];

    for (int r = blockIdx.x * (blockDim.x >> 6) + wid; r < M; r += wavesTotal) {
        const float* row = uacc + (size_t)r * HC;
        float hid = b1v;
        #pragma unroll 8
        for (int k = 0; k < HC; ++k) {
            hid = fmaf(row[k] + bL[k], W1L[k * 64 + lane], hid);
        }
        hid = fmaxf(hid, 0.f);
        float p = hid * w2v;
        p += __shfl_xor(p, 32, 64);
        p += __shfl_xor(p, 16, 64);
        p += __shfl_xor(p, 8, 64);
        p += __shfl_xor(p, 4, 64);
        p += __shfl_xor(p, 2, 64);
        p += __shfl_xor(p, 1, 64);
        if (lane == 0) out[r] = 1.f / (1.f + expf(-(p + b2v)));
    }
}

// ---------------------------------------------------------------------------
extern "C" void kernel_launch(void* const* d_in, const int* in_sizes, int n_in,
                              void* d_out, int out_size, void* d_ws, size_t ws_size,
                              hipStream_t stream)
{
    const float* customer_x = (const float*)d_in[0];
    const float* fund_x     = (const float*)d_in[1];
    const float* edge_attr  = (const float*)d_in[2];
    const int*   edge_src   = (const int*)d_in[3];
    const int*   edge_dst   = (const int*)d_in[4];
    const float* user_W = (const float*)d_in[5];
    const float* user_b = (const float*)d_in[6];
    const float* item_W = (const float*)d_in[7];
    const float* item_b = (const float*)d_in[8];
    const float* c1_Wl  = (const float*)d_in[9];
    const float* c1_bl  = (const float*)d_in[10];
    const float* c1_Wr  = (const float*)d_in[11];
    const float* c1_br  = (const float*)d_in[12];
    const float* c1_We  = (const float*)d_in[13];
    const float* c1_att = (const float*)d_in[14];
    const float* c1_bias= (const float*)d_in[15];
    const float* c2_Wl  = (const float*)d_in[16];
    const float* c2_bl  = (const float*)d_in[17];
    const float* c2_Wr  = (const float*)d_in[18];
    const float* c2_br  = (const float*)d_in[19];
    const float* c2_att = (const float*)d_in[20];
    const float* c2_bias= (const float*)d_in[21];
    const float* cls_W1 = (const float*)d_in[22];
    const float* cls_b1 = (const float*)d_in[23];
    const float* cls_W2 = (const float*)d_in[24];
    const float* cls_b2 = (const float*)d_in[25];
    float* out = (float*)d_out;

    float* ws = (float*)d_ws;
    size_t off = 0;
    float* A  = ws + off; off += (size_t)NU * 32;    // user_x          64 MB
    float* Ix = ws + off; off += (size_t)NI * 32;    // item_x          6.4 MB
    float* B  = ws + off; off += (size_t)NU * HC;    // xl1 / xr2       256 MB
    float* C  = ws + off; off += (size_t)NI * HC;    // xr1             25.6 MB
    float* D  = ws + off; off += (size_t)NE * NH;    // ex              16 MB
    float* S1 = ws + off; off += (size_t)NI * NH;    // denom conv1     0.8 MB
    float* F  = ws + off; off += (size_t)NI * HC;    // item acc/h      25.6 MB
    float* G  = ws + off; off += (size_t)NI * HC;    // xl2             25.6 MB
    float* S2 = ws + off; off += (size_t)NU * NH;    // denom conv2     8 MB
    float* Kb = ws + off; off += (size_t)NU * HC;    // user acc        256 MB

    // zero accumulators
    hipMemsetAsync(S1, 0, (size_t)NI * NH * sizeof(float), stream);
    hipMemsetAsync(F,  0, (size_t)NI * HC * sizeof(float), stream);
    hipMemsetAsync(S2, 0, (size_t)NU * NH * sizeof(float), stream);
    hipMemsetAsync(Kb, 0, (size_t)NU * HC * sizeof(float), stream);

    const dim3 b32(32, 8, 1);
    const dim3 b128(128, 2, 1);

    // 1) user_x = customer_x @ user_W + user_b        [NU,101]@[101,32]
    gemm_rows<<<4096, b32, 101 * 32 * 4, stream>>>(customer_x, user_W, user_b, A,
                                                   NU, 101, 32, 0);
    // 2) item_x = fund_x @ item_W + item_b            [NI,1]@[1,32]
    gemm_rows<<<1024, b32, 1 * 32 * 4, stream>>>(fund_x, item_W, item_b, Ix,
                                                 NI, 1, 32, 0);
    // 3) xl1 = user_x @ c1_Wl + c1_bl                 [NU,32]@[32,128]
    gemm_rows<<<8192, b128, 32 * 128 * 4, stream>>>(A, c1_Wl, c1_bl, B,
                                                    NU, 32, HC, 0);
    // 4) xr1 = item_x @ c1_Wr + c1_br                 [NI,32]@[32,128]
    gemm_rows<<<2048, b128, 32 * 128 * 4, stream>>>(Ix, c1_Wr, c1_br, C,
                                                    NI, 32, HC, 0);
    // 5) conv1 edge passes (src=edge_src user, dst=edge_dst fund)
    edge_score<<<8192, 256, 0, stream>>>(B, C, edge_src, edge_dst,
                                         edge_attr, c1_We, c1_att,
                                         D, S1, NE, 1);
    edge_aggr<<<8192, 256, 0, stream>>>(B, edge_src, edge_dst, D, S1, F, NE);
    // 6) item_h = relu(F + c1_bias)
    bias_relu_k<<<4096, 256, 0, stream>>>(F, c1_bias, NI * HC);
    // 7) xl2 = item_h @ c2_Wl + c2_bl                 [NI,128]@[128,128]
    gemm_rows<<<2048, b128, 128 * 128 * 4, stream>>>(F, c2_Wl, c2_bl, G,
                                                     NI, HC, HC, 0);
    // 8) xr2 = user_x @ c2_Wr + c2_br                 [NU,32]@[32,128] (reuse B)
    gemm_rows<<<8192, b128, 32 * 128 * 4, stream>>>(A, c2_Wr, c2_br, B,
                                                    NU, 32, HC, 0);
    // 9) conv2 edge passes (src index = edge_dst fund, dst index = edge_src user)
    edge_score<<<8192, 256, 0, stream>>>(G, B, edge_dst, edge_src,
                                         nullptr, nullptr, c2_att,
                                         D, S2, NE, 0);
    edge_aggr<<<8192, 256, 0, stream>>>(G, edge_dst, edge_src, D, S2, Kb, NE);
    // 10) classifier (adds c2_bias internally)
    classifier_k<<<2048, 256, 0, stream>>>(Kb, c2_bias, cls_W1, cls_b1,
                                           cls_W2, cls_b2, out, NU);
}

// Round 2
// 3429.726 us; speedup vs baseline: 1.2191x; 1.2191x over previous
//
#include <hip/hip_runtime.h>
#include <cstdint>
#include <cstddef>

#define NU 500000
#define NI 50000
#define NE 1000000
#define HC 128   // H*C
#define NH 4

// ---------------------------------------------------------------------------
// Generic row GEMM: out[M,N] = act(in[M,K] @ W[K,N] + b[N])
// blockDim = (N, 256/N). W staged in dynamic LDS once per block; grid-stride rows.
// ---------------------------------------------------------------------------
__global__ void gemm_rows(const float* __restrict__ in, const float* __restrict__ W,
                          const float* __restrict__ b, float* __restrict__ out,
                          int M, int K, int N, int act)
{
    extern __shared__ float Wlds[];
    const int nthreads = blockDim.x * blockDim.y;
    const int tid = threadIdx.y * blockDim.x + threadIdx.x;
    for (int i = tid; i < K * N; i += nthreads) Wlds[i] = W[i];
    __syncthreads();

    const int rpb = blockDim.y;
    const int c = threadIdx.x;
    const float bias = b[c];

    for (int row = blockIdx.x * rpb + threadIdx.y; row < M; row += gridDim.x * rpb) {
        const float* inr = in + (size_t)row * K;
        float acc = bias;
        #pragma unroll 4
        for (int k = 0; k < K; ++k) acc = fmaf(inr[k], Wlds[k * N + c], acc);
        if (act == 1) acc = fmaxf(acc, 0.f);
        out[(size_t)row * N + c] = acc;
    }
}

// ---------------------------------------------------------------------------
// CSR build: histogram both bucketings in one pass
// ---------------------------------------------------------------------------
__global__ void hist_both(const int* __restrict__ src, const int* __restrict__ dst,
                          int* __restrict__ cntU, int* __restrict__ cntI, int E)
{
    for (int i = blockIdx.x * blockDim.x + threadIdx.x; i < E;
         i += gridDim.x * blockDim.x) {
        atomicAdd(&cntU[src[i]], 1);
        atomicAdd(&cntI[dst[i]], 1);
    }
}

// exclusive scan, 1024 elements per block (256 thr x 4)
__global__ void scan_blocks(const int* __restrict__ in, int* __restrict__ out,
                            int* __restrict__ blockSums, int n)
{
    __shared__ int lds[256];
    const int tid = threadIdx.x;
    const int base = blockIdx.x * 1024 + tid * 4;
    int v[4];
    #pragma unroll
    for (int j = 0; j < 4; ++j) { int idx = base + j; v[j] = (idx < n) ? in[idx] : 0; }
    int t = v[0] + v[1] + v[2] + v[3];
    lds[tid] = t;
    __syncthreads();
    for (int off = 1; off < 256; off <<= 1) {
        int x = (tid >= off) ? lds[tid - off] : 0;
        __syncthreads();
        lds[tid] += x;
        __syncthreads();
    }
    int excl = lds[tid] - t;
    if (tid == 255 && blockSums) blockSums[blockIdx.x] = lds[255];
    int run = excl;
    #pragma unroll
    for (int j = 0; j < 4; ++j) {
        int idx = base + j;
        if (idx < n) out[idx] = run;
        run += v[j];
    }
}

__global__ void scan_add(int* __restrict__ out, const int* __restrict__ bss, int n)
{
    const int add = bss[blockIdx.x];
    const int base = blockIdx.x * 1024 + threadIdx.x * 4;
    #pragma unroll
    for (int j = 0; j < 4; ++j) { int idx = base + j; if (idx < n) out[idx] += add; }
}

// scatter edges into both CSR orders; bumps off arrays to bucket ends
__global__ void scatter_both(const int* __restrict__ src, const int* __restrict__ dst,
                             const float* __restrict__ eattr,
                             int* __restrict__ offU, int* __restrict__ offI,
                             int* __restrict__ sFund, int* __restrict__ sSrc1,
                             float* __restrict__ sAtt1, int E)
{
    for (int i = blockIdx.x * blockDim.x + threadIdx.x; i < E;
         i += gridDim.x * blockDim.x) {
        const int s = src[i];
        const int d = dst[i];
        const float a0 = eattr[3 * (size_t)i];
        const float a1 = eattr[3 * (size_t)i + 1];
        const float a2 = eattr[3 * (size_t)i + 2];
        const int p1 = atomicAdd(&offI[d], 1);
        sSrc1[p1] = s;
        sAtt1[3 * (size_t)p1]     = a0;
        sAtt1[3 * (size_t)p1 + 1] = a1;
        sAtt1[3 * (size_t)p1 + 2] = a2;
        const int p2 = atomicAdd(&offU[s], 1);
        sFund[p2] = d;
    }
}

// ---------------------------------------------------------------------------
// conv1 fused: one wave per fund d. Single pass over its edges:
//   out[d] = relu( (sum_e ex_e * xl[src_e]) / (sum_e ex_e) + c1_bias )
// lane l handles channels 2l,2l+1; head h = lanes [16h,16h+16).
// off_end[d] = end of bucket d (after scatter bump); start = end - cnt[d].
// ---------------------------------------------------------------------------
__global__ void conv1_fused(const float* __restrict__ xl, const float* __restrict__ xr,
                            const int* __restrict__ off_end, const int* __restrict__ cnt,
                            const int* __restrict__ sSrc, const float* __restrict__ sAtt,
                            const float* __restrict__ We, const float* __restrict__ att,
                            const float* __restrict__ bias,
                            float* __restrict__ outF, int ndst)
{
    __shared__ float WeL[3 * HC];
    __shared__ float attL[HC];
    __shared__ float bL[HC];
    const int tid = threadIdx.x;
    for (int i = tid; i < 3 * HC; i += blockDim.x) WeL[i] = We[i];
    if (tid < HC) { attL[tid] = att[tid]; bL[tid] = bias[tid]; }
    __syncthreads();

    const int lane = tid & 63;
    const int wid = tid >> 6;
    const int d = blockIdx.x * 4 + wid;   // grid sized exactly: ndst/4 blocks
    if (d >= ndst) return;

    const int ch = lane * 2;
    const float a0c = attL[ch], a1c = attL[ch + 1];
    const float w00 = WeL[ch],          w01 = WeL[ch + 1];
    const float w10 = WeL[HC + ch],     w11 = WeL[HC + ch + 1];
    const float w20 = WeL[2 * HC + ch], w21 = WeL[2 * HC + ch + 1];

    const float2 vr = *(const float2*)(xr + (size_t)d * HC + ch);

    const int end = off_end[d];
    const int start = end - cnt[d];

    float acc0 = 0.f, acc1 = 0.f, s = 0.f;
    for (int pos = start; pos < end; ++pos) {
        const int sidx = sSrc[pos];
        const float2 vl = *(const float2*)(xl + (size_t)sidx * HC + ch);
        const float e0 = sAtt[3 * (size_t)pos];
        const float e1 = sAtt[3 * (size_t)pos + 1];
        const float e2 = sAtt[3 * (size_t)pos + 2];
        float h0 = vl.x + vr.x + e0 * w00 + e1 * w10 + e2 * w20;
        float h1 = vl.y + vr.y + e0 * w01 + e1 * w11 + e2 * w21;
        h0 = h0 > 0.f ? h0 : 0.2f * h0;
        h1 = h1 > 0.f ? h1 : 0.2f * h1;
        float p = h0 * a0c + h1 * a1c;
        p += __shfl_xor(p, 8, 16);
        p += __shfl_xor(p, 4, 16);
        p += __shfl_xor(p, 2, 16);
        p += __shfl_xor(p, 1, 16);
        const float ex = __expf(p);
        acc0 += ex * vl.x;
        acc1 += ex * vl.y;
        s += ex;
    }
    const float inv = 1.f / (s + 1e-16f);
    float o0 = fmaxf(acc0 * inv + bL[ch], 0.f);
    float o1 = fmaxf(acc1 * inv + bL[ch + 1], 0.f);
    *(float2*)(outF + (size_t)d * HC + ch) = make_float2(o0, o1);
}

// ---------------------------------------------------------------------------
// conv2 + classifier fused: one wave per user u.
//   xr2[u] = user_x[u] @ c2_Wr + c2_br   (on the fly, shuffle broadcast)
//   x = (sum ex*xl2[fund]) / (sum ex) + c2_bias
//   hid_j = relu(x . W1[:,j] + b1_j); out[u] = sigmoid(hid . W2 + b2)
// ---------------------------------------------------------------------------
__global__ void conv2_cls(const float* __restrict__ xl2, const float* __restrict__ user_x,
                          const float* __restrict__ Wr, const float* __restrict__ br,
                          const int* __restrict__ off_end, const int* __restrict__ cnt,
                          const int* __restrict__ sFund,
                          const float* __restrict__ att, const float* __restrict__ cbias,
                          const float* __restrict__ W1, const float* __restrict__ b1,
                          const float* __restrict__ W2, const float* __restrict__ b2,
                          float* __restrict__ out, int nusr)
{
    __shared__ float WrL[32 * HC];   // 16 KB
    __shared__ float W1L[HC * 64];   // 32 KB
    __shared__ float attL[HC];
    __shared__ float brL[HC];
    __shared__ float biasL[HC];
    __shared__ float W2L[64];
    __shared__ float xw[4][HC];      // per-wave x buffer

    const int tid = threadIdx.x;
    for (int i = tid; i < 32 * HC; i += blockDim.x) WrL[i] = Wr[i];
    for (int i = tid; i < HC * 64; i += blockDim.x) W1L[i] = W1[i];
    if (tid < HC) { attL[tid] = att[tid]; brL[tid] = br[tid]; biasL[tid] = cbias[tid]; }
    if (tid < 64) W2L[tid] = W2[tid];
    __syncthreads();

    const int lane = tid & 63;
    const int wid = tid >> 6;
    const int u = blockIdx.x * 4 + wid;   // grid sized exactly: NU/4 blocks
    if (u >= nusr) return;

    const int ch = lane * 2;
    const float a0c = attL[ch], a1c = attL[ch + 1];

    // xr2 row on the fly
    float uv = (lane < 32) ? user_x[(size_t)u * 32 + lane] : 0.f;
    float xr0 = brL[ch], xr1 = brL[ch + 1];
    #pragma unroll
    for (int k = 0; k < 32; ++k) {
        const float uk = __shfl(uv, k, 64);
        xr0 = fmaf(uk, WrL[k * HC + ch], xr0);
        xr1 = fmaf(uk, WrL[k * HC + ch + 1], xr1);
    }

    const int end = off_end[u];
    const int start = end - cnt[u];

    float acc0 = 0.f, acc1 = 0.f, s = 0.f;
    for (int pos = start; pos < end; ++pos) {
        const int f = sFund[pos];
        const float2 vl = *(const float2*)(xl2 + (size_t)f * HC + ch);
        float h0 = vl.x + xr0;
        float h1 = vl.y + xr1;
        h0 = h0 > 0.f ? h0 : 0.2f * h0;
        h1 = h1 > 0.f ? h1 : 0.2f * h1;
        float p = h0 * a0c + h1 * a1c;
        p += __shfl_xor(p, 8, 16);
        p += __shfl_xor(p, 4, 16);
        p += __shfl_xor(p, 2, 16);
        p += __shfl_xor(p, 1, 16);
        const float ex = __expf(p);
        acc0 += ex * vl.x;
        acc1 += ex * vl.y;
        s += ex;
    }
    const float inv = 1.f / (s + 1e-16f);
    const float x0 = acc0 * inv + biasL[ch];
    const float x1 = acc1 * inv + biasL[ch + 1];

    // per-wave LDS transpose: wave-internal, ordered by in-wave LDS issue order
    xw[wid][ch] = x0;
    xw[wid][ch + 1] = x1;

    float hid = b1[lane];
    #pragma unroll 8
    for (int k = 0; k < HC; ++k) hid = fmaf(xw[wid][k], W1L[k * 64 + lane], hid);
    hid = fmaxf(hid, 0.f);

    float p2 = hid * W2L[lane];
    p2 += __shfl_xor(p2, 32, 64);
    p2 += __shfl_xor(p2, 16, 64);
    p2 += __shfl_xor(p2, 8, 64);
    p2 += __shfl_xor(p2, 4, 64);
    p2 += __shfl_xor(p2, 2, 64);
    p2 += __shfl_xor(p2, 1, 64);
    if (lane == 0) out[u] = 1.f / (1.f + expf(-(p2 + b2[0])));
}

// ---------------------------------------------------------------------------
extern "C" void kernel_launch(void* const* d_in, const int* in_sizes, int n_in,
                              void* d_out, int out_size, void* d_ws, size_t ws_size,
                              hipStream_t stream)
{
    const float* customer_x = (const float*)d_in[0];
    const float* fund_x     = (const float*)d_in[1];
    const float* edge_attr  = (const float*)d_in[2];
    const int*   edge_src   = (const int*)d_in[3];
    const int*   edge_dst   = (const int*)d_in[4];
    const float* user_W = (const float*)d_in[5];
    const float* user_b = (const float*)d_in[6];
    const float* item_W = (const float*)d_in[7];
    const float* item_b = (const float*)d_in[8];
    const float* c1_Wl  = (const float*)d_in[9];
    const float* c1_bl  = (const float*)d_in[10];
    const float* c1_Wr  = (const float*)d_in[11];
    const float* c1_br  = (const float*)d_in[12];
    const float* c1_We  = (const float*)d_in[13];
    const float* c1_att = (const float*)d_in[14];
    const float* c1_bias= (const float*)d_in[15];
    const float* c2_Wl  = (const float*)d_in[16];
    const float* c2_bl  = (const float*)d_in[17];
    const float* c2_Wr  = (const float*)d_in[18];
    const float* c2_br  = (const float*)d_in[19];
    const float* c2_att = (const float*)d_in[20];
    const float* c2_bias= (const float*)d_in[21];
    const float* cls_W1 = (const float*)d_in[22];
    const float* cls_b1 = (const float*)d_in[23];
    const float* cls_W2 = (const float*)d_in[24];
    const float* cls_b2 = (const float*)d_in[25];
    float* out = (float*)d_out;

    float* ws = (float*)d_ws;
    size_t off = 0;
    float* A   = ws + off; off += (size_t)NU * 32;   // user_x    64 MB
    float* Ix  = ws + off; off += (size_t)NI * 32;   // item_x    6.4 MB
    float* B   = ws + off; off += (size_t)NU * HC;   // xl1       256 MB
    float* C   = ws + off; off += (size_t)NI * HC;   // xr1       25.6 MB
    float* F   = ws + off; off += (size_t)NI * HC;   // item_h    25.6 MB
    float* G   = ws + off; off += (size_t)NI * HC;   // xl2       25.6 MB
    int* cnt1  = (int*)(ws + off); off += NI;        // fund degree
    int* off1  = (int*)(ws + off); off += NI;        // fund CSR offsets (bumped to ends)
    int* cnt2  = (int*)(ws + off); off += NU;
    int* off2  = (int*)(ws + off); off += NU;
    int* bs    = (int*)(ws + off); off += 1024;      // scan block sums
    int* bss   = (int*)(ws + off); off += 1024;
    int* sSrc1 = (int*)(ws + off); off += NE;        // conv1 CSR: src per slot
    float* sAtt1 = ws + off;       off += (size_t)NE * 3;  // conv1 CSR: edge_attr
    int* sFund = (int*)(ws + off); off += NE;        // conv2 CSR: fund per slot

    // zero degree counters
    hipMemsetAsync(cnt1, 0, NI * sizeof(int), stream);
    hipMemsetAsync(cnt2, 0, NU * sizeof(int), stream);

    // CSR build
    hist_both<<<1024, 256, 0, stream>>>(edge_src, edge_dst, cnt2, cnt1, NE);
    const int nb1 = (NI + 1023) / 1024;   // 49
    const int nb2 = (NU + 1023) / 1024;   // 489
    scan_blocks<<<nb1, 256, 0, stream>>>(cnt1, off1, bs, NI);
    scan_blocks<<<1,   256, 0, stream>>>(bs, bss, nullptr, nb1);
    scan_add<<<nb1, 256, 0, stream>>>(off1, bss, NI);
    scan_blocks<<<nb2, 256, 0, stream>>>(cnt2, off2, bs, NU);
    scan_blocks<<<1,   256, 0, stream>>>(bs, bss, nullptr, nb2);
    scan_add<<<nb2, 256, 0, stream>>>(off2, bss, NU);
    scatter_both<<<1024, 256, 0, stream>>>(edge_src, edge_dst, edge_attr,
                                           off2, off1, sFund, sSrc1, sAtt1, NE);

    const dim3 b32(32, 8, 1);
    const dim3 b128(128, 2, 1);

    // projections
    gemm_rows<<<4096, b32, 101 * 32 * 4, stream>>>(customer_x, user_W, user_b, A,
                                                   NU, 101, 32, 0);
    gemm_rows<<<1024, b32, 1 * 32 * 4, stream>>>(fund_x, item_W, item_b, Ix,
                                                 NI, 1, 32, 0);
    gemm_rows<<<8192, b128, 32 * 128 * 4, stream>>>(A, c1_Wl, c1_bl, B,
                                                    NU, 32, HC, 0);
    gemm_rows<<<2048, b128, 32 * 128 * 4, stream>>>(Ix, c1_Wr, c1_br, C,
                                                    NI, 32, HC, 0);

    // conv1: customer -> fund, fused single pass (+bias+relu)
    conv1_fused<<<NI / 4, 256, 0, stream>>>(B, C, off1, cnt1, sSrc1, sAtt1,
                                            c1_We, c1_att, c1_bias, F, NI);

    // xl2 = item_h @ c2_Wl + c2_bl
    gemm_rows<<<2048, b128, 128 * 128 * 4, stream>>>(F, c2_Wl, c2_bl, G,
                                                     NI, HC, HC, 0);

    // conv2 + classifier fused
    conv2_cls<<<NU / 4, 256, 0, stream>>>(G, A, c2_Wr, c2_br, off2, cnt2, sFund,
                                          c2_att, c2_bias, cls_W1, cls_b1,
                                          cls_W2, cls_b2, out, NU);
}

// Round 3
// 2209.151 us; speedup vs baseline: 1.8927x; 1.5525x over previous
//
#include <hip/hip_runtime.h>
#include <cstdint>
#include <cstddef>

#define NU 500000
#define NI 50000
#define NE 1000000
#define HC 128   // H*C
#define NH 4

// ---------------------------------------------------------------------------
// Generic row GEMM: out[M,N] = act(in[M,K] @ W[K,N] + b[N])
// blockDim = (N, 256/N). W staged in dynamic LDS once per block; grid-stride rows.
// ---------------------------------------------------------------------------
__global__ void gemm_rows(const float* __restrict__ in, const float* __restrict__ W,
                          const float* __restrict__ b, float* __restrict__ out,
                          int M, int K, int N, int act)
{
    extern __shared__ float Wlds[];
    const int nthreads = blockDim.x * blockDim.y;
    const int tid = threadIdx.y * blockDim.x + threadIdx.x;
    for (int i = tid; i < K * N; i += nthreads) Wlds[i] = W[i];
    __syncthreads();

    const int rpb = blockDim.y;
    const int c = threadIdx.x;
    const float bias = b[c];

    for (int row = blockIdx.x * rpb + threadIdx.y; row < M; row += gridDim.x * rpb) {
        const float* inr = in + (size_t)row * K;
        float acc = bias;
        #pragma unroll 4
        for (int k = 0; k < K; ++k) acc = fmaf(inr[k], Wlds[k * N + c], acc);
        if (act == 1) acc = fmaxf(acc, 0.f);
        out[(size_t)row * N + c] = acc;
    }
}

// ---------------------------------------------------------------------------
// CSR build
// ---------------------------------------------------------------------------
__global__ void hist_both(const int* __restrict__ src, const int* __restrict__ dst,
                          int* __restrict__ cntU, int* __restrict__ cntI, int E)
{
    for (int i = blockIdx.x * blockDim.x + threadIdx.x; i < E;
         i += gridDim.x * blockDim.x) {
        atomicAdd(&cntU[src[i]], 1);
        atomicAdd(&cntI[dst[i]], 1);
    }
}

__global__ void scan_blocks(const int* __restrict__ in, int* __restrict__ out,
                            int* __restrict__ blockSums, int n)
{
    __shared__ int lds[256];
    const int tid = threadIdx.x;
    const int base = blockIdx.x * 1024 + tid * 4;
    int v[4];
    #pragma unroll
    for (int j = 0; j < 4; ++j) { int idx = base + j; v[j] = (idx < n) ? in[idx] : 0; }
    int t = v[0] + v[1] + v[2] + v[3];
    lds[tid] = t;
    __syncthreads();
    for (int off = 1; off < 256; off <<= 1) {
        int x = (tid >= off) ? lds[tid - off] : 0;
        __syncthreads();
        lds[tid] += x;
        __syncthreads();
    }
    int excl = lds[tid] - t;
    if (tid == 255 && blockSums) blockSums[blockIdx.x] = lds[255];
    int run = excl;
    #pragma unroll
    for (int j = 0; j < 4; ++j) {
        int idx = base + j;
        if (idx < n) out[idx] = run;
        run += v[j];
    }
}

__global__ void scan_add(int* __restrict__ out, const int* __restrict__ bss, int n)
{
    const int add = bss[blockIdx.x];
    const int base = blockIdx.x * 1024 + threadIdx.x * 4;
    #pragma unroll
    for (int j = 0; j < 4; ++j) { int idx = base + j; if (idx < n) out[idx] += add; }
}

__global__ void scatter_both(const int* __restrict__ src, const int* __restrict__ dst,
                             const float* __restrict__ eattr,
                             int* __restrict__ offU, int* __restrict__ offI,
                             int* __restrict__ sFund, int* __restrict__ sSrc1,
                             float* __restrict__ sAtt1, int E)
{
    for (int i = blockIdx.x * blockDim.x + threadIdx.x; i < E;
         i += gridDim.x * blockDim.x) {
        const int s = src[i];
        const int d = dst[i];
        const float a0 = eattr[3 * (size_t)i];
        const float a1 = eattr[3 * (size_t)i + 1];
        const float a2 = eattr[3 * (size_t)i + 2];
        const int p1 = atomicAdd(&offI[d], 1);
        sSrc1[p1] = s;
        sAtt1[3 * (size_t)p1]     = a0;
        sAtt1[3 * (size_t)p1 + 1] = a1;
        sAtt1[3 * (size_t)p1 + 2] = a2;
        const int p2 = atomicAdd(&offU[s], 1);
        sFund[p2] = d;
    }
}

// ---------------------------------------------------------------------------
// conv1 fused: one wave per fund d (no LDS; constants via L1 broadcast).
//   out[d] = relu( (sum_e ex_e * xl[src_e]) / (sum_e ex_e) + c1_bias )
// ---------------------------------------------------------------------------
__global__ void conv1_fused(const float* __restrict__ xl, const float* __restrict__ xr,
                            const int* __restrict__ off_end, const int* __restrict__ cnt,
                            const int* __restrict__ sSrc, const float* __restrict__ sAtt,
                            const float* __restrict__ We, const float* __restrict__ att,
                            const float* __restrict__ bias,
                            float* __restrict__ outF, int ndst)
{
    const int tid = threadIdx.x;
    const int lane = tid & 63;
    const int wid = tid >> 6;
    const int d = blockIdx.x * 4 + wid;
    if (d >= ndst) return;

    const int ch = lane * 2;
    const float2 av = *(const float2*)(att + ch);
    const float2 w0 = *(const float2*)(We + ch);
    const float2 w1 = *(const float2*)(We + HC + ch);
    const float2 w2 = *(const float2*)(We + 2 * HC + ch);
    const float2 bv = *(const float2*)(bias + ch);
    const float2 vr = *(const float2*)(xr + (size_t)d * HC + ch);

    const int end = off_end[d];
    const int start = end - cnt[d];

    float acc0 = 0.f, acc1 = 0.f, s = 0.f;
    for (int pos = start; pos < end; ++pos) {
        const int sidx = sSrc[pos];
        const float2 vl = *(const float2*)(xl + (size_t)sidx * HC + ch);
        const float e0 = sAtt[3 * (size_t)pos];
        const float e1 = sAtt[3 * (size_t)pos + 1];
        const float e2 = sAtt[3 * (size_t)pos + 2];
        float h0 = vl.x + vr.x + e0 * w0.x + e1 * w1.x + e2 * w2.x;
        float h1 = vl.y + vr.y + e0 * w0.y + e1 * w1.y + e2 * w2.y;
        h0 = h0 > 0.f ? h0 : 0.2f * h0;
        h1 = h1 > 0.f ? h1 : 0.2f * h1;
        float p = h0 * av.x + h1 * av.y;
        p += __shfl_xor(p, 8, 16);
        p += __shfl_xor(p, 4, 16);
        p += __shfl_xor(p, 2, 16);
        p += __shfl_xor(p, 1, 16);
        const float ex = __expf(p);
        acc0 += ex * vl.x;
        acc1 += ex * vl.y;
        s += ex;
    }
    const float inv = 1.f / (s + 1e-16f);
    float o0 = fmaxf(acc0 * inv + bv.x, 0.f);
    float o1 = fmaxf(acc1 * inv + bv.y, 0.f);
    *(float2*)(outF + (size_t)d * HC + ch) = make_float2(o0, o1);
}

// ---------------------------------------------------------------------------
// conv2 fused (no classifier, no LDS): one wave per user u.
//   H[u] = (sum ex*xl2[fund]) / (sum ex) + c2_bias
// ---------------------------------------------------------------------------
__global__ void conv2_fused(const float* __restrict__ xl2, const float* __restrict__ xr2,
                            const int* __restrict__ off_end, const int* __restrict__ cnt,
                            const int* __restrict__ sFund,
                            const float* __restrict__ att, const float* __restrict__ cbias,
                            float* __restrict__ H, int nusr)
{
    const int tid = threadIdx.x;
    const int lane = tid & 63;
    const int wid = tid >> 6;
    const int u = blockIdx.x * 4 + wid;
    if (u >= nusr) return;

    const int ch = lane * 2;
    const float2 av = *(const float2*)(att + ch);
    const float2 bv = *(const float2*)(cbias + ch);
    const float2 vr = *(const float2*)(xr2 + (size_t)u * HC + ch);

    const int end = off_end[u];
    const int start = end - cnt[u];

    float acc0 = 0.f, acc1 = 0.f, s = 0.f;
    for (int pos = start; pos < end; ++pos) {
        const int f = sFund[pos];
        const float2 vl = *(const float2*)(xl2 + (size_t)f * HC + ch);
        float h0 = vl.x + vr.x;
        float h1 = vl.y + vr.y;
        h0 = h0 > 0.f ? h0 : 0.2f * h0;
        h1 = h1 > 0.f ? h1 : 0.2f * h1;
        float p = h0 * av.x + h1 * av.y;
        p += __shfl_xor(p, 8, 16);
        p += __shfl_xor(p, 4, 16);
        p += __shfl_xor(p, 2, 16);
        p += __shfl_xor(p, 1, 16);
        const float ex = __expf(p);
        acc0 += ex * vl.x;
        acc1 += ex * vl.y;
        s += ex;
    }
    const float inv = 1.f / (s + 1e-16f);
    *(float2*)(H + (size_t)u * HC + ch) =
        make_float2(acc0 * inv + bv.x, acc1 * inv + bv.y);
}

// ---------------------------------------------------------------------------
// Classifier: out = sigmoid(relu(X@W1+b1)@W2+b2), X=[M,128], W1=[128,64], W2=[64]
// Tile: 64 rows x 64 cols per block (256 thr); thread computes 4x4 outputs.
// K processed in 2 halves so LDS = 32KB(W1) + 17.4KB(Xs) fits.
// ---------------------------------------------------------------------------
__global__ void classifier_tiled(const float* __restrict__ X,
                                 const float* __restrict__ W1, const float* __restrict__ b1,
                                 const float* __restrict__ W2, const float* __restrict__ b2,
                                 float* __restrict__ out, int M)
{
    __shared__ float W1L[128 * 64];   // 32 KB
    __shared__ float Xs[64 * 68];     // 17.4 KB (pitch 68: 2-way free aliasing)

    const int tid = threadIdx.x;
    for (int i = tid; i < 128 * 64 / 4; i += 256)
        ((float4*)W1L)[i] = ((const float4*)W1)[i];

    const int u0 = blockIdx.x * 64;
    const int rows = min(64, M - u0);

    const int cg = tid & 15;
    const int rg = tid >> 4;
    const int c  = cg * 4;
    const int r0 = rg * 4;

    const float4 b1v = *(const float4*)(b1 + c);
    const float4 w2v = *(const float4*)(W2 + c);

    float acc[4][4] = {{0.f}};

    for (int half = 0; half < 2; ++half) {
        __syncthreads();
        // stage 64x64 half-tile of X
        for (int i = tid; i < 1024; i += 256) {
            const int r = i >> 4;
            const int f4 = i & 15;
            float4 v = make_float4(0.f, 0.f, 0.f, 0.f);
            if (r < rows)
                v = *(const float4*)(X + (size_t)(u0 + r) * HC + half * 64 + f4 * 4);
            *(float4*)(Xs + r * 68 + f4 * 4) = v;
        }
        __syncthreads();

        const float* W1h = W1L + half * 64 * 64;
        #pragma unroll 4
        for (int kc = 0; kc < 64; kc += 4) {
            const float4 wa = *(const float4*)(W1h + (kc    ) * 64 + c);
            const float4 wb = *(const float4*)(W1h + (kc + 1) * 64 + c);
            const float4 wc = *(const float4*)(W1h + (kc + 2) * 64 + c);
            const float4 wd = *(const float4*)(W1h + (kc + 3) * 64 + c);
            #pragma unroll
            for (int i = 0; i < 4; ++i) {
                const float4 xv = *(const float4*)(Xs + (r0 + i) * 68 + kc);
                acc[i][0] = fmaf(xv.x, wa.x, fmaf(xv.y, wb.x, fmaf(xv.z, wc.x, fmaf(xv.w, wd.x, acc[i][0]))));
                acc[i][1] = fmaf(xv.x, wa.y, fmaf(xv.y, wb.y, fmaf(xv.z, wc.y, fmaf(xv.w, wd.y, acc[i][1]))));
                acc[i][2] = fmaf(xv.x, wa.z, fmaf(xv.y, wb.z, fmaf(xv.z, wc.z, fmaf(xv.w, wd.z, acc[i][2]))));
                acc[i][3] = fmaf(xv.x, wa.w, fmaf(xv.y, wb.w, fmaf(xv.z, wc.w, fmaf(xv.w, wd.w, acc[i][3]))));
            }
        }
    }

    float p[4];
    #pragma unroll
    for (int i = 0; i < 4; ++i) {
        float h = fmaxf(acc[i][0] + b1v.x, 0.f) * w2v.x;
        h = fmaf(fmaxf(acc[i][1] + b1v.y, 0.f), w2v.y, h);
        h = fmaf(fmaxf(acc[i][2] + b1v.z, 0.f), w2v.z, h);
        h = fmaf(fmaxf(acc[i][3] + b1v.w, 0.f), w2v.w, h);
        p[i] = h;
    }
    #pragma unroll
    for (int i = 0; i < 4; ++i) {
        p[i] += __shfl_xor(p[i], 1, 16);
        p[i] += __shfl_xor(p[i], 2, 16);
        p[i] += __shfl_xor(p[i], 4, 16);
        p[i] += __shfl_xor(p[i], 8, 16);
    }
    if (cg == 0) {
        const float bb = b2[0];
        #pragma unroll
        for (int i = 0; i < 4; ++i) {
            const int r = r0 + i;
            if (r < rows) out[u0 + r] = 1.f / (1.f + expf(-(p[i] + bb)));
        }
    }
}

// ---------------------------------------------------------------------------
extern "C" void kernel_launch(void* const* d_in, const int* in_sizes, int n_in,
                              void* d_out, int out_size, void* d_ws, size_t ws_size,
                              hipStream_t stream)
{
    const float* customer_x = (const float*)d_in[0];
    const float* fund_x     = (const float*)d_in[1];
    const float* edge_attr  = (const float*)d_in[2];
    const int*   edge_src   = (const int*)d_in[3];
    const int*   edge_dst   = (const int*)d_in[4];
    const float* user_W = (const float*)d_in[5];
    const float* user_b = (const float*)d_in[6];
    const float* item_W = (const float*)d_in[7];
    const float* item_b = (const float*)d_in[8];
    const float* c1_Wl  = (const float*)d_in[9];
    const float* c1_bl  = (const float*)d_in[10];
    const float* c1_Wr  = (const float*)d_in[11];
    const float* c1_br  = (const float*)d_in[12];
    const float* c1_We  = (const float*)d_in[13];
    const float* c1_att = (const float*)d_in[14];
    const float* c1_bias= (const float*)d_in[15];
    const float* c2_Wl  = (const float*)d_in[16];
    const float* c2_bl  = (const float*)d_in[17];
    const float* c2_Wr  = (const float*)d_in[18];
    const float* c2_br  = (const float*)d_in[19];
    const float* c2_att = (const float*)d_in[20];
    const float* c2_bias= (const float*)d_in[21];
    const float* cls_W1 = (const float*)d_in[22];
    const float* cls_b1 = (const float*)d_in[23];
    const float* cls_W2 = (const float*)d_in[24];
    const float* cls_b2 = (const float*)d_in[25];
    float* out = (float*)d_out;

    float* ws = (float*)d_ws;
    // region0 (NU*HC floats = 256MB): user_h H; A/Ix/C/F live only BEFORE conv2
    float* H  = ws;
    float* A  = ws;                                   // user_x   [NU,32]
    float* Ix = A + (size_t)NU * 32;                  // item_x   [NI,32]
    float* C  = Ix + (size_t)NI * 32;                 // xr1      [NI,128]
    float* F  = C + (size_t)NI * HC;                  // item_h   [NI,128]
    size_t off = (size_t)NU * HC;
    float* B  = ws + off; off += (size_t)NU * HC;     // xl1, then xr2
    float* G  = ws + off; off += (size_t)NI * HC;     // xl2
    int* cnt1  = (int*)(ws + off); off += NI;
    int* off1  = (int*)(ws + off); off += NI;
    int* cnt2  = (int*)(ws + off); off += NU;
    int* off2  = (int*)(ws + off); off += NU;
    int* bs    = (int*)(ws + off); off += 1024;
    int* bss   = (int*)(ws + off); off += 1024;
    int* sSrc1 = (int*)(ws + off); off += NE;
    float* sAtt1 = ws + off;       off += (size_t)NE * 3;
    int* sFund = (int*)(ws + off); off += NE;

    hipMemsetAsync(cnt1, 0, NI * sizeof(int), stream);
    hipMemsetAsync(cnt2, 0, NU * sizeof(int), stream);

    // CSR build
    hist_both<<<1024, 256, 0, stream>>>(edge_src, edge_dst, cnt2, cnt1, NE);
    const int nb1 = (NI + 1023) / 1024;
    const int nb2 = (NU + 1023) / 1024;
    scan_blocks<<<nb1, 256, 0, stream>>>(cnt1, off1, bs, NI);
    scan_blocks<<<1,   256, 0, stream>>>(bs, bss, nullptr, nb1);
    scan_add<<<nb1, 256, 0, stream>>>(off1, bss, NI);
    scan_blocks<<<nb2, 256, 0, stream>>>(cnt2, off2, bs, NU);
    scan_blocks<<<1,   256, 0, stream>>>(bs, bss, nullptr, nb2);
    scan_add<<<nb2, 256, 0, stream>>>(off2, bss, NU);
    scatter_both<<<1024, 256, 0, stream>>>(edge_src, edge_dst, edge_attr,
                                           off2, off1, sFund, sSrc1, sAtt1, NE);

    const dim3 b32(32, 8, 1);
    const dim3 b128(128, 2, 1);

    // projections
    gemm_rows<<<4096, b32, 101 * 32 * 4, stream>>>(customer_x, user_W, user_b, A,
                                                   NU, 101, 32, 0);
    gemm_rows<<<1024, b32, 1 * 32 * 4, stream>>>(fund_x, item_W, item_b, Ix,
                                                 NI, 1, 32, 0);
    gemm_rows<<<8192, b128, 32 * 128 * 4, stream>>>(A, c1_Wl, c1_bl, B,
                                                    NU, 32, HC, 0);
    gemm_rows<<<2048, b128, 32 * 128 * 4, stream>>>(Ix, c1_Wr, c1_br, C,
                                                    NI, 32, HC, 0);

    // conv1: customer -> fund (+bias+relu)
    conv1_fused<<<NI / 4, 256, 0, stream>>>(B, C, off1, cnt1, sSrc1, sAtt1,
                                            c1_We, c1_att, c1_bias, F, NI);

    // xl2 = item_h @ c2_Wl + c2_bl
    gemm_rows<<<2048, b128, 128 * 128 * 4, stream>>>(F, c2_Wl, c2_bl, G,
                                                     NI, HC, HC, 0);
    // xr2 = user_x @ c2_Wr + c2_br   (overwrites B; xl1 is dead)
    gemm_rows<<<8192, b128, 32 * 128 * 4, stream>>>(A, c2_Wr, c2_br, B,
                                                    NU, 32, HC, 0);

    // conv2: fund -> customer, writes user_h (+c2_bias)
    conv2_fused<<<NU / 4, 256, 0, stream>>>(G, B, off2, cnt2, sFund,
                                            c2_att, c2_bias, H, NU);

    // classifier
    classifier_tiled<<<(NU + 63) / 64, 256, 0, stream>>>(H, cls_W1, cls_b1,
                                                         cls_W2, cls_b2, out, NU);
}

// Round 4
// 1441.733 us; speedup vs baseline: 2.9002x; 1.5323x over previous
//
#include <hip/hip_runtime.h>
#include <cstdint>
#include <cstddef>

#define NU 500000
#define NI 50000
#define NE 1000000
#define HC 128   // H*C
#define NH 4

__device__ __forceinline__ float rl(float v, int k) {
    return __int_as_float(__builtin_amdgcn_readlane(__float_as_int(v), k));
}

// ---------------------------------------------------------------------------
// Generic row GEMM (kept only for tiny K=1 item projection)
// ---------------------------------------------------------------------------
__global__ void gemm_rows(const float* __restrict__ in, const float* __restrict__ W,
                          const float* __restrict__ b, float* __restrict__ out,
                          int M, int K, int N, int act)
{
    extern __shared__ float Wlds[];
    const int nthreads = blockDim.x * blockDim.y;
    const int tid = threadIdx.y * blockDim.x + threadIdx.x;
    for (int i = tid; i < K * N; i += nthreads) Wlds[i] = W[i];
    __syncthreads();

    const int rpb = blockDim.y;
    const int c = threadIdx.x;
    const float bias = b[c];

    for (int row = blockIdx.x * rpb + threadIdx.y; row < M; row += gridDim.x * rpb) {
        const float* inr = in + (size_t)row * K;
        float acc = bias;
        for (int k = 0; k < K; ++k) acc = fmaf(inr[k], Wlds[k * N + c], acc);
        if (act == 1) acc = fmaxf(acc, 0.f);
        out[(size_t)row * N + c] = acc;
    }
}

// ---------------------------------------------------------------------------
// [M,32] @ [32,128] + b : one wave per row, weights in VGPRs, readlane bcast.
// lane handles cols 2l,2l+1.
// ---------------------------------------------------------------------------
__global__ __launch_bounds__(256, 4)
void gemm_user_readlane(const float* __restrict__ in, const float* __restrict__ W,
                        const float* __restrict__ b, float* __restrict__ out, int M)
{
    const int lane = threadIdx.x & 63;
    const int ch = lane * 2;
    float2 w[32];
    #pragma unroll
    for (int k = 0; k < 32; ++k) w[k] = *(const float2*)(W + k * HC + ch);
    const float2 bv = *(const float2*)(b + ch);

    const int gw = (blockIdx.x * blockDim.x + threadIdx.x) >> 6;
    const int nw = (gridDim.x * blockDim.x) >> 6;
    for (int row = gw; row < M; row += nw) {
        const float uv = (lane < 32) ? in[(size_t)row * 32 + lane] : 0.f;
        float a0 = bv.x, a1 = bv.y;
        #pragma unroll
        for (int k = 0; k < 32; ++k) {
            const float uk = rl(uv, k);
            a0 = fmaf(uk, w[k].x, a0);
            a1 = fmaf(uk, w[k].y, a1);
        }
        *(float2*)(out + (size_t)row * HC + ch) = make_float2(a0, a1);
    }
}

// ---------------------------------------------------------------------------
// [M,101] @ [101,32] + b : one wave per row; lanes 0-31 store cols (upper
// half redundant). Weights (one column per lane) in VGPRs.
// ---------------------------------------------------------------------------
__global__ __launch_bounds__(256, 3)
void gemm_cx_readlane(const float* __restrict__ in, const float* __restrict__ W,
                      const float* __restrict__ b, float* __restrict__ out, int M)
{
    const int lane = threadIdx.x & 63;
    const int col = lane & 31;
    float w[101];
    #pragma unroll
    for (int k = 0; k < 101; ++k) w[k] = W[k * 32 + col];
    const float bv = b[col];

    const int gw = (blockIdx.x * blockDim.x + threadIdx.x) >> 6;
    const int nw = (gridDim.x * blockDim.x) >> 6;
    for (int row = gw; row < M; row += nw) {
        const float r0 = in[(size_t)row * 101 + lane];
        const float r1 = (lane + 64 < 101) ? in[(size_t)row * 101 + 64 + lane] : 0.f;
        float acc = bv;
        #pragma unroll
        for (int k = 0; k < 64; ++k) acc = fmaf(rl(r0, k), w[k], acc);
        #pragma unroll
        for (int k = 64; k < 101; ++k) acc = fmaf(rl(r1, k - 64), w[k], acc);
        if (lane < 32) out[(size_t)row * 32 + col] = acc;
    }
}

// ---------------------------------------------------------------------------
// [M,128] @ [128,128] + b : wave handles (row, col-half); weights in VGPRs.
// ---------------------------------------------------------------------------
__global__ __launch_bounds__(256, 3)
void gemm_item_readlane(const float* __restrict__ in, const float* __restrict__ W,
                        const float* __restrict__ b, float* __restrict__ out, int M)
{
    const int lane = threadIdx.x & 63;
    const int gw = (blockIdx.x * blockDim.x + threadIdx.x) >> 6;
    const int nw = (gridDim.x * blockDim.x) >> 6;
    const int half = gw & 1;
    const int col = half * 64 + lane;

    float w[128];
    #pragma unroll
    for (int k = 0; k < 128; ++k) w[k] = W[k * 128 + col];
    const float bv = b[col];

    for (int row = gw >> 1; row < M; row += (nw >> 1)) {
        const float r0 = in[(size_t)row * 128 + lane];
        const float r1 = in[(size_t)row * 128 + 64 + lane];
        float acc = bv;
        #pragma unroll
        for (int k = 0; k < 64; ++k) acc = fmaf(rl(r0, k), w[k], acc);
        #pragma unroll
        for (int k = 0; k < 64; ++k) acc = fmaf(rl(r1, k), w[k + 64], acc);
        out[(size_t)row * 128 + col] = acc;
    }
}

// ---------------------------------------------------------------------------
// CSR build
// ---------------------------------------------------------------------------
__global__ void hist_both(const int* __restrict__ src, const int* __restrict__ dst,
                          int* __restrict__ cntU, int* __restrict__ cntI, int E)
{
    for (int i = blockIdx.x * blockDim.x + threadIdx.x; i < E;
         i += gridDim.x * blockDim.x) {
        atomicAdd(&cntU[src[i]], 1);
        atomicAdd(&cntI[dst[i]], 1);
    }
}

__global__ void scan_blocks(const int* __restrict__ in, int* __restrict__ out,
                            int* __restrict__ blockSums, int n)
{
    __shared__ int lds[256];
    const int tid = threadIdx.x;
    const int base = blockIdx.x * 1024 + tid * 4;
    int v[4];
    #pragma unroll
    for (int j = 0; j < 4; ++j) { int idx = base + j; v[j] = (idx < n) ? in[idx] : 0; }
    int t = v[0] + v[1] + v[2] + v[3];
    lds[tid] = t;
    __syncthreads();
    for (int off = 1; off < 256; off <<= 1) {
        int x = (tid >= off) ? lds[tid - off] : 0;
        __syncthreads();
        lds[tid] += x;
        __syncthreads();
    }
    int excl = lds[tid] - t;
    if (tid == 255 && blockSums) blockSums[blockIdx.x] = lds[255];
    int run = excl;
    #pragma unroll
    for (int j = 0; j < 4; ++j) {
        int idx = base + j;
        if (idx < n) out[idx] = run;
        run += v[j];
    }
}

__global__ void scan_add(int* __restrict__ out, const int* __restrict__ bss, int n)
{
    const int add = bss[blockIdx.x];
    const int base = blockIdx.x * 1024 + threadIdx.x * 4;
    #pragma unroll
    for (int j = 0; j < 4; ++j) { int idx = base + j; if (idx < n) out[idx] += add; }
}

__global__ void scatter_both(const int* __restrict__ src, const int* __restrict__ dst,
                             const float* __restrict__ eattr,
                             int* __restrict__ offU, int* __restrict__ offI,
                             int* __restrict__ sFund, int* __restrict__ sSrc1,
                             float* __restrict__ sAtt1, int E)
{
    for (int i = blockIdx.x * blockDim.x + threadIdx.x; i < E;
         i += gridDim.x * blockDim.x) {
        const int s = src[i];
        const int d = dst[i];
        const float a0 = eattr[3 * (size_t)i];
        const float a1 = eattr[3 * (size_t)i + 1];
        const float a2 = eattr[3 * (size_t)i + 2];
        const int p1 = atomicAdd(&offI[d], 1);
        sSrc1[p1] = s;
        sAtt1[3 * (size_t)p1]     = a0;
        sAtt1[3 * (size_t)p1 + 1] = a1;
        sAtt1[3 * (size_t)p1 + 2] = a2;
        const int p2 = atomicAdd(&offU[s], 1);
        sFund[p2] = d;
    }
}

// ---------------------------------------------------------------------------
// conv1 fused: one wave per fund d.
// ---------------------------------------------------------------------------
__global__ void conv1_fused(const float* __restrict__ xl, const float* __restrict__ xr,
                            const int* __restrict__ off_end, const int* __restrict__ cnt,
                            const int* __restrict__ sSrc, const float* __restrict__ sAtt,
                            const float* __restrict__ We, const float* __restrict__ att,
                            const float* __restrict__ bias,
                            float* __restrict__ outF, int ndst)
{
    const int tid = threadIdx.x;
    const int lane = tid & 63;
    const int wid = tid >> 6;
    const int d = blockIdx.x * 4 + wid;
    if (d >= ndst) return;

    const int ch = lane * 2;
    const float2 av = *(const float2*)(att + ch);
    const float2 w0 = *(const float2*)(We + ch);
    const float2 w1 = *(const float2*)(We + HC + ch);
    const float2 w2 = *(const float2*)(We + 2 * HC + ch);
    const float2 bv = *(const float2*)(bias + ch);
    const float2 vr = *(const float2*)(xr + (size_t)d * HC + ch);

    const int end = off_end[d];
    const int start = end - cnt[d];

    float acc0 = 0.f, acc1 = 0.f, s = 0.f;
    for (int pos = start; pos < end; ++pos) {
        const int sidx = sSrc[pos];
        const float2 vl = *(const float2*)(xl + (size_t)sidx * HC + ch);
        const float e0 = sAtt[3 * (size_t)pos];
        const float e1 = sAtt[3 * (size_t)pos + 1];
        const float e2 = sAtt[3 * (size_t)pos + 2];
        float h0 = vl.x + vr.x + e0 * w0.x + e1 * w1.x + e2 * w2.x;
        float h1 = vl.y + vr.y + e0 * w0.y + e1 * w1.y + e2 * w2.y;
        h0 = h0 > 0.f ? h0 : 0.2f * h0;
        h1 = h1 > 0.f ? h1 : 0.2f * h1;
        float p = h0 * av.x + h1 * av.y;
        p += __shfl_xor(p, 8, 16);
        p += __shfl_xor(p, 4, 16);
        p += __shfl_xor(p, 2, 16);
        p += __shfl_xor(p, 1, 16);
        const float ex = __expf(p);
        acc0 += ex * vl.x;
        acc1 += ex * vl.y;
        s += ex;
    }
    const float inv = 1.f / (s + 1e-16f);
    float o0 = fmaxf(acc0 * inv + bv.x, 0.f);
    float o1 = fmaxf(acc1 * inv + bv.y, 0.f);
    *(float2*)(outF + (size_t)d * HC + ch) = make_float2(o0, o1);
}

// ---------------------------------------------------------------------------
// conv2 fused: one wave per user u.
// ---------------------------------------------------------------------------
__global__ void conv2_fused(const float* __restrict__ xl2, const float* __restrict__ xr2,
                            const int* __restrict__ off_end, const int* __restrict__ cnt,
                            const int* __restrict__ sFund,
                            const float* __restrict__ att, const float* __restrict__ cbias,
                            float* __restrict__ H, int nusr)
{
    const int tid = threadIdx.x;
    const int lane = tid & 63;
    const int wid = tid >> 6;
    const int u = blockIdx.x * 4 + wid;
    if (u >= nusr) return;

    const int ch = lane * 2;
    const float2 av = *(const float2*)(att + ch);
    const float2 bv = *(const float2*)(cbias + ch);
    const float2 vr = *(const float2*)(xr2 + (size_t)u * HC + ch);

    const int end = off_end[u];
    const int start = end - cnt[u];

    float acc0 = 0.f, acc1 = 0.f, s = 0.f;
    for (int pos = start; pos < end; ++pos) {
        const int f = sFund[pos];
        const float2 vl = *(const float2*)(xl2 + (size_t)f * HC + ch);
        float h0 = vl.x + vr.x;
        float h1 = vl.y + vr.y;
        h0 = h0 > 0.f ? h0 : 0.2f * h0;
        h1 = h1 > 0.f ? h1 : 0.2f * h1;
        float p = h0 * av.x + h1 * av.y;
        p += __shfl_xor(p, 8, 16);
        p += __shfl_xor(p, 4, 16);
        p += __shfl_xor(p, 2, 16);
        p += __shfl_xor(p, 1, 16);
        const float ex = __expf(p);
        acc0 += ex * vl.x;
        acc1 += ex * vl.y;
        s += ex;
    }
    const float inv = 1.f / (s + 1e-16f);
    *(float2*)(H + (size_t)u * HC + ch) =
        make_float2(acc0 * inv + bv.x, acc1 * inv + bv.y);
}

// ---------------------------------------------------------------------------
// Classifier: out = sigmoid(relu(X@W1+b1)@W2+b2)
// ---------------------------------------------------------------------------
__global__ void classifier_tiled(const float* __restrict__ X,
                                 const float* __restrict__ W1, const float* __restrict__ b1,
                                 const float* __restrict__ W2, const float* __restrict__ b2,
                                 float* __restrict__ out, int M)
{
    __shared__ float W1L[128 * 64];
    __shared__ float Xs[64 * 68];

    const int tid = threadIdx.x;
    for (int i = tid; i < 128 * 64 / 4; i += 256)
        ((float4*)W1L)[i] = ((const float4*)W1)[i];

    const int u0 = blockIdx.x * 64;
    const int rows = min(64, M - u0);

    const int cg = tid & 15;
    const int rg = tid >> 4;
    const int c  = cg * 4;
    const int r0 = rg * 4;

    const float4 b1v = *(const float4*)(b1 + c);
    const float4 w2v = *(const float4*)(W2 + c);

    float acc[4][4] = {{0.f}};

    for (int half = 0; half < 2; ++half) {
        __syncthreads();
        for (int i = tid; i < 1024; i += 256) {
            const int r = i >> 4;
            const int f4 = i & 15;
            float4 v = make_float4(0.f, 0.f, 0.f, 0.f);
            if (r < rows)
                v = *(const float4*)(X + (size_t)(u0 + r) * HC + half * 64 + f4 * 4);
            *(float4*)(Xs + r * 68 + f4 * 4) = v;
        }
        __syncthreads();

        const float* W1h = W1L + half * 64 * 64;
        #pragma unroll 4
        for (int kc = 0; kc < 64; kc += 4) {
            const float4 wa = *(const float4*)(W1h + (kc    ) * 64 + c);
            const float4 wb = *(const float4*)(W1h + (kc + 1) * 64 + c);
            const float4 wc = *(const float4*)(W1h + (kc + 2) * 64 + c);
            const float4 wd = *(const float4*)(W1h + (kc + 3) * 64 + c);
            #pragma unroll
            for (int i = 0; i < 4; ++i) {
                const float4 xv = *(const float4*)(Xs + (r0 + i) * 68 + kc);
                acc[i][0] = fmaf(xv.x, wa.x, fmaf(xv.y, wb.x, fmaf(xv.z, wc.x, fmaf(xv.w, wd.x, acc[i][0]))));
                acc[i][1] = fmaf(xv.x, wa.y, fmaf(xv.y, wb.y, fmaf(xv.z, wc.y, fmaf(xv.w, wd.y, acc[i][1]))));
                acc[i][2] = fmaf(xv.x, wa.z, fmaf(xv.y, wb.z, fmaf(xv.z, wc.z, fmaf(xv.w, wd.z, acc[i][2]))));
                acc[i][3] = fmaf(xv.x, wa.w, fmaf(xv.y, wb.w, fmaf(xv.z, wc.w, fmaf(xv.w, wd.w, acc[i][3]))));
            }
        }
    }

    float p[4];
    #pragma unroll
    for (int i = 0; i < 4; ++i) {
        float h = fmaxf(acc[i][0] + b1v.x, 0.f) * w2v.x;
        h = fmaf(fmaxf(acc[i][1] + b1v.y, 0.f), w2v.y, h);
        h = fmaf(fmaxf(acc[i][2] + b1v.z, 0.f), w2v.z, h);
        h = fmaf(fmaxf(acc[i][3] + b1v.w, 0.f), w2v.w, h);
        p[i] = h;
    }
    #pragma unroll
    for (int i = 0; i < 4; ++i) {
        p[i] += __shfl_xor(p[i], 1, 16);
        p[i] += __shfl_xor(p[i], 2, 16);
        p[i] += __shfl_xor(p[i], 4, 16);
        p[i] += __shfl_xor(p[i], 8, 16);
    }
    if (cg == 0) {
        const float bb = b2[0];
        #pragma unroll
        for (int i = 0; i < 4; ++i) {
            const int r = r0 + i;
            if (r < rows) out[u0 + r] = 1.f / (1.f + expf(-(p[i] + bb)));
        }
    }
}

// ---------------------------------------------------------------------------
extern "C" void kernel_launch(void* const* d_in, const int* in_sizes, int n_in,
                              void* d_out, int out_size, void* d_ws, size_t ws_size,
                              hipStream_t stream)
{
    const float* customer_x = (const float*)d_in[0];
    const float* fund_x     = (const float*)d_in[1];
    const float* edge_attr  = (const float*)d_in[2];
    const int*   edge_src   = (const int*)d_in[3];
    const int*   edge_dst   = (const int*)d_in[4];
    const float* user_W = (const float*)d_in[5];
    const float* user_b = (const float*)d_in[6];
    const float* item_W = (const float*)d_in[7];
    const float* item_b = (const float*)d_in[8];
    const float* c1_Wl  = (const float*)d_in[9];
    const float* c1_bl  = (const float*)d_in[10];
    const float* c1_Wr  = (const float*)d_in[11];
    const float* c1_br  = (const float*)d_in[12];
    const float* c1_We  = (const float*)d_in[13];
    const float* c1_att = (const float*)d_in[14];
    const float* c1_bias= (const float*)d_in[15];
    const float* c2_Wl  = (const float*)d_in[16];
    const float* c2_bl  = (const float*)d_in[17];
    const float* c2_Wr  = (const float*)d_in[18];
    const float* c2_br  = (const float*)d_in[19];
    const float* c2_att = (const float*)d_in[20];
    const float* c2_bias= (const float*)d_in[21];
    const float* cls_W1 = (const float*)d_in[22];
    const float* cls_b1 = (const float*)d_in[23];
    const float* cls_W2 = (const float*)d_in[24];
    const float* cls_b2 = (const float*)d_in[25];
    float* out = (float*)d_out;

    float* ws = (float*)d_ws;
    float* H  = ws;
    float* A  = ws;                                   // user_x   [NU,32]
    float* Ix = A + (size_t)NU * 32;                  // item_x   [NI,32]
    float* C  = Ix + (size_t)NI * 32;                 // xr1      [NI,128]
    float* F  = C + (size_t)NI * HC;                  // item_h   [NI,128]
    size_t off = (size_t)NU * HC;
    float* B  = ws + off; off += (size_t)NU * HC;     // xl1, then xr2
    float* G  = ws + off; off += (size_t)NI * HC;     // xl2
    int* cnt1  = (int*)(ws + off); off += NI;
    int* off1  = (int*)(ws + off); off += NI;
    int* cnt2  = (int*)(ws + off); off += NU;
    int* off2  = (int*)(ws + off); off += NU;
    int* bs    = (int*)(ws + off); off += 1024;
    int* bss   = (int*)(ws + off); off += 1024;
    int* sSrc1 = (int*)(ws + off); off += NE;
    float* sAtt1 = ws + off;       off += (size_t)NE * 3;
    int* sFund = (int*)(ws + off); off += NE;

    hipMemsetAsync(cnt1, 0, NI * sizeof(int), stream);
    hipMemsetAsync(cnt2, 0, NU * sizeof(int), stream);

    // CSR build
    hist_both<<<1024, 256, 0, stream>>>(edge_src, edge_dst, cnt2, cnt1, NE);
    const int nb1 = (NI + 1023) / 1024;
    const int nb2 = (NU + 1023) / 1024;
    scan_blocks<<<nb1, 256, 0, stream>>>(cnt1, off1, bs, NI);
    scan_blocks<<<1,   256, 0, stream>>>(bs, bss, nullptr, nb1);
    scan_add<<<nb1, 256, 0, stream>>>(off1, bss, NI);
    scan_blocks<<<nb2, 256, 0, stream>>>(cnt2, off2, bs, NU);
    scan_blocks<<<1,   256, 0, stream>>>(bs, bss, nullptr, nb2);
    scan_add<<<nb2, 256, 0, stream>>>(off2, bss, NU);
    scatter_both<<<1024, 256, 0, stream>>>(edge_src, edge_dst, edge_attr,
                                           off2, off1, sFund, sSrc1, sAtt1, NE);

    // projections
    gemm_cx_readlane<<<2048, 256, 0, stream>>>(customer_x, user_W, user_b, A, NU);
    const dim3 b32(32, 8, 1);
    gemm_rows<<<1024, b32, 1 * 32 * 4, stream>>>(fund_x, item_W, item_b, Ix,
                                                 NI, 1, 32, 0);
    gemm_user_readlane<<<2048, 256, 0, stream>>>(A, c1_Wl, c1_bl, B, NU);   // xl1
    gemm_user_readlane<<<512, 256, 0, stream>>>(Ix, c1_Wr, c1_br, C, NI);   // xr1

    // conv1: customer -> fund (+bias+relu)
    conv1_fused<<<NI / 4, 256, 0, stream>>>(B, C, off1, cnt1, sSrc1, sAtt1,
                                            c1_We, c1_att, c1_bias, F, NI);

    // xl2 = item_h @ c2_Wl + c2_bl
    gemm_item_readlane<<<512, 256, 0, stream>>>(F, c2_Wl, c2_bl, G, NI);
    // xr2 = user_x @ c2_Wr + c2_br (overwrites B; xl1 dead after conv1)
    gemm_user_readlane<<<2048, 256, 0, stream>>>(A, c2_Wr, c2_br, B, NU);

    // conv2: fund -> customer
    conv2_fused<<<NU / 4, 256, 0, stream>>>(G, B, off2, cnt2, sFund,
                                            c2_att, c2_bias, H, NU);

    // classifier
    classifier_tiled<<<(NU + 63) / 64, 256, 0, stream>>>(H, cls_W1, cls_b1,
                                                         cls_W2, cls_b2, out, NU);
}

// Round 5
// 1126.290 us; speedup vs baseline: 3.7125x; 1.2801x over previous
//
#include <hip/hip_runtime.h>
#include <cstdint>
#include <cstddef>

#define NU 500000
#define NI 50000
#define NE 1000000
#define HC 128   // H*C
#define NH 4

__device__ __forceinline__ float rl(float v, int k) {
    return __int_as_float(__builtin_amdgcn_readlane(__float_as_int(v), k));
}

// bf16 pack/unpack (RNE)
__device__ __forceinline__ unsigned int pack_bf2(float x, float y) {
    unsigned int xb = __float_as_uint(x);
    unsigned int yb = __float_as_uint(y);
    xb += 0x7fffu + ((xb >> 16) & 1u);
    yb += 0x7fffu + ((yb >> 16) & 1u);
    return (xb >> 16) | (yb & 0xffff0000u);
}
__device__ __forceinline__ float2 unpack_bf2(unsigned int v) {
    return make_float2(__uint_as_float(v << 16),
                       __uint_as_float(v & 0xffff0000u));
}
__device__ __forceinline__ unsigned short pack_bf1(float x) {
    unsigned int b = __float_as_uint(x);
    b += 0x7fffu + ((b >> 16) & 1u);
    return (unsigned short)(b >> 16);
}

__device__ __forceinline__ float head_reduce(float p) {
    p += __shfl_xor(p, 8, 16);
    p += __shfl_xor(p, 4, 16);
    p += __shfl_xor(p, 2, 16);
    p += __shfl_xor(p, 1, 16);
    return p;
}

// ---------------------------------------------------------------------------
// Generic row GEMM (kept only for tiny K=1 item projection)
// ---------------------------------------------------------------------------
__global__ void gemm_rows(const float* __restrict__ in, const float* __restrict__ W,
                          const float* __restrict__ b, float* __restrict__ out,
                          int M, int K, int N, int act)
{
    extern __shared__ float Wlds[];
    const int nthreads = blockDim.x * blockDim.y;
    const int tid = threadIdx.y * blockDim.x + threadIdx.x;
    for (int i = tid; i < K * N; i += nthreads) Wlds[i] = W[i];
    __syncthreads();

    const int rpb = blockDim.y;
    const int c = threadIdx.x;
    const float bias = b[c];

    for (int row = blockIdx.x * rpb + threadIdx.y; row < M; row += gridDim.x * rpb) {
        const float* inr = in + (size_t)row * K;
        float acc = bias;
        for (int k = 0; k < K; ++k) acc = fmaf(inr[k], Wlds[k * N + c], acc);
        if (act == 1) acc = fmaxf(acc, 0.f);
        out[(size_t)row * N + c] = acc;
    }
}

// ---------------------------------------------------------------------------
// [M,32] @ [32,128] + b -> bf16 packed : one wave per row, W in VGPRs.
// ---------------------------------------------------------------------------
__global__ __launch_bounds__(256, 4)
void gemm_user_readlane_bf16(const float* __restrict__ in, const float* __restrict__ W,
                             const float* __restrict__ b, unsigned int* __restrict__ out,
                             int M)
{
    const int lane = threadIdx.x & 63;
    const int ch = lane * 2;
    float2 w[32];
    #pragma unroll
    for (int k = 0; k < 32; ++k) w[k] = *(const float2*)(W + k * HC + ch);
    const float2 bv = *(const float2*)(b + ch);

    const int gw = (blockIdx.x * blockDim.x + threadIdx.x) >> 6;
    const int nw = (gridDim.x * blockDim.x) >> 6;
    for (int row = gw; row < M; row += nw) {
        const float uv = (lane < 32) ? in[(size_t)row * 32 + lane] : 0.f;
        float a0 = bv.x, a1 = bv.y;
        #pragma unroll
        for (int k = 0; k < 32; ++k) {
            const float uk = rl(uv, k);
            a0 = fmaf(uk, w[k].x, a0);
            a1 = fmaf(uk, w[k].y, a1);
        }
        out[(size_t)row * 64 + lane] = pack_bf2(a0, a1);
    }
}

// ---------------------------------------------------------------------------
// [M,101] @ [101,32] + b : one wave per row; weights (one col/lane) in VGPRs.
// ---------------------------------------------------------------------------
__global__ __launch_bounds__(256, 3)
void gemm_cx_readlane(const float* __restrict__ in, const float* __restrict__ W,
                      const float* __restrict__ b, float* __restrict__ out, int M)
{
    const int lane = threadIdx.x & 63;
    const int col = lane & 31;
    float w[101];
    #pragma unroll
    for (int k = 0; k < 101; ++k) w[k] = W[k * 32 + col];
    const float bv = b[col];

    const int gw = (blockIdx.x * blockDim.x + threadIdx.x) >> 6;
    const int nw = (gridDim.x * blockDim.x) >> 6;
    for (int row = gw; row < M; row += nw) {
        const float r0 = in[(size_t)row * 101 + lane];
        const float r1 = (lane + 64 < 101) ? in[(size_t)row * 101 + 64 + lane] : 0.f;
        float acc = bv;
        #pragma unroll
        for (int k = 0; k < 64; ++k) acc = fmaf(rl(r0, k), w[k], acc);
        #pragma unroll
        for (int k = 64; k < 101; ++k) acc = fmaf(rl(r1, k - 64), w[k], acc);
        if (lane < 32) out[(size_t)row * 32 + col] = acc;
    }
}

// ---------------------------------------------------------------------------
// [M,128] @ [128,128] + b -> bf16 (scalar ushort stores; M is small)
// ---------------------------------------------------------------------------
__global__ __launch_bounds__(256, 3)
void gemm_item_readlane_bf16(const float* __restrict__ in, const float* __restrict__ W,
                             const float* __restrict__ b,
                             unsigned short* __restrict__ out, int M)
{
    const int lane = threadIdx.x & 63;
    const int gw = (blockIdx.x * blockDim.x + threadIdx.x) >> 6;
    const int nw = (gridDim.x * blockDim.x) >> 6;
    const int half = gw & 1;
    const int col = half * 64 + lane;

    float w[128];
    #pragma unroll
    for (int k = 0; k < 128; ++k) w[k] = W[k * 128 + col];
    const float bv = b[col];

    for (int row = gw >> 1; row < M; row += (nw >> 1)) {
        const float r0 = in[(size_t)row * 128 + lane];
        const float r1 = in[(size_t)row * 128 + 64 + lane];
        float acc = bv;
        #pragma unroll
        for (int k = 0; k < 64; ++k) acc = fmaf(rl(r0, k), w[k], acc);
        #pragma unroll
        for (int k = 0; k < 64; ++k) acc = fmaf(rl(r1, k), w[k + 64], acc);
        out[(size_t)row * 128 + col] = pack_bf1(acc);
    }
}

// ---------------------------------------------------------------------------
// CSR build
// ---------------------------------------------------------------------------
__global__ void hist_both(const int* __restrict__ src, const int* __restrict__ dst,
                          int* __restrict__ cntU, int* __restrict__ cntI, int E)
{
    for (int i = blockIdx.x * blockDim.x + threadIdx.x; i < E;
         i += gridDim.x * blockDim.x) {
        atomicAdd(&cntU[src[i]], 1);
        atomicAdd(&cntI[dst[i]], 1);
    }
}

__global__ void scan_blocks(const int* __restrict__ in, int* __restrict__ out,
                            int* __restrict__ blockSums, int n)
{
    __shared__ int lds[256];
    const int tid = threadIdx.x;
    const int base = blockIdx.x * 1024 + tid * 4;
    int v[4];
    #pragma unroll
    for (int j = 0; j < 4; ++j) { int idx = base + j; v[j] = (idx < n) ? in[idx] : 0; }
    int t = v[0] + v[1] + v[2] + v[3];
    lds[tid] = t;
    __syncthreads();
    for (int off = 1; off < 256; off <<= 1) {
        int x = (tid >= off) ? lds[tid - off] : 0;
        __syncthreads();
        lds[tid] += x;
        __syncthreads();
    }
    int excl = lds[tid] - t;
    if (tid == 255 && blockSums) blockSums[blockIdx.x] = lds[255];
    int run = excl;
    #pragma unroll
    for (int j = 0; j < 4; ++j) {
        int idx = base + j;
        if (idx < n) out[idx] = run;
        run += v[j];
    }
}

__global__ void scan_add(int* __restrict__ out, const int* __restrict__ bss, int n)
{
    const int add = bss[blockIdx.x];
    const int base = blockIdx.x * 1024 + threadIdx.x * 4;
    #pragma unroll
    for (int j = 0; j < 4; ++j) { int idx = base + j; if (idx < n) out[idx] += add; }
}

// scatter: conv1 payload packed as uint4 {src, a0, a1, a2}; conv2 as uint fund
__global__ void scatter_both(const int* __restrict__ src, const int* __restrict__ dst,
                             const float* __restrict__ eattr,
                             int* __restrict__ offU, int* __restrict__ offI,
                             int* __restrict__ sFund, uint4* __restrict__ sE1, int E)
{
    for (int i = blockIdx.x * blockDim.x + threadIdx.x; i < E;
         i += gridDim.x * blockDim.x) {
        const int s = src[i];
        const int d = dst[i];
        const float a0 = eattr[3 * (size_t)i];
        const float a1 = eattr[3 * (size_t)i + 1];
        const float a2 = eattr[3 * (size_t)i + 2];
        const int p1 = atomicAdd(&offI[d], 1);
        sE1[p1] = make_uint4((unsigned int)s, __float_as_uint(a0),
                             __float_as_uint(a1), __float_as_uint(a2));
        const int p2 = atomicAdd(&offU[s], 1);
        sFund[p2] = d;
    }
}

// ---------------------------------------------------------------------------
// conv1 fused: one wave per fund d; xl is bf16-packed; 4-way unrolled gathers.
// ---------------------------------------------------------------------------
__device__ __forceinline__ void conv1_edge(uint4 e, unsigned int vbits, float2 vr,
                                           float2 av, float2 w0, float2 w1, float2 w2,
                                           float& acc0, float& acc1, float& s)
{
    const float2 vl = unpack_bf2(vbits);
    const float e0 = __uint_as_float(e.y);
    const float e1 = __uint_as_float(e.z);
    const float e2 = __uint_as_float(e.w);
    float h0 = vl.x + vr.x + e0 * w0.x + e1 * w1.x + e2 * w2.x;
    float h1 = vl.y + vr.y + e0 * w0.y + e1 * w1.y + e2 * w2.y;
    h0 = h0 > 0.f ? h0 : 0.2f * h0;
    h1 = h1 > 0.f ? h1 : 0.2f * h1;
    const float p = head_reduce(h0 * av.x + h1 * av.y);
    const float ex = __expf(p);
    acc0 = fmaf(ex, vl.x, acc0);
    acc1 = fmaf(ex, vl.y, acc1);
    s += ex;
}

__global__ void conv1_fused(const unsigned int* __restrict__ xl,
                            const float* __restrict__ xr,
                            const int* __restrict__ off_end, const int* __restrict__ cnt,
                            const uint4* __restrict__ sE,
                            const float* __restrict__ We, const float* __restrict__ att,
                            const float* __restrict__ bias,
                            float* __restrict__ outF, int ndst)
{
    const int tid = threadIdx.x;
    const int lane = tid & 63;
    const int wid = tid >> 6;
    const int d = blockIdx.x * 4 + wid;
    if (d >= ndst) return;

    const int ch = lane * 2;
    const float2 av = *(const float2*)(att + ch);
    const float2 w0 = *(const float2*)(We + ch);
    const float2 w1 = *(const float2*)(We + HC + ch);
    const float2 w2 = *(const float2*)(We + 2 * HC + ch);
    const float2 bv = *(const float2*)(bias + ch);
    const float2 vr = *(const float2*)(xr + (size_t)d * HC + ch);

    const int end = off_end[d];
    const int start = end - cnt[d];

    float acc0 = 0.f, acc1 = 0.f, s = 0.f;
    int pos = start;
    for (; pos + 4 <= end; pos += 4) {
        const uint4 ea = sE[pos], eb = sE[pos + 1], ec = sE[pos + 2], ed = sE[pos + 3];
        const unsigned int va = xl[(size_t)ea.x * 64 + lane];
        const unsigned int vb = xl[(size_t)eb.x * 64 + lane];
        const unsigned int vc = xl[(size_t)ec.x * 64 + lane];
        const unsigned int vd = xl[(size_t)ed.x * 64 + lane];
        conv1_edge(ea, va, vr, av, w0, w1, w2, acc0, acc1, s);
        conv1_edge(eb, vb, vr, av, w0, w1, w2, acc0, acc1, s);
        conv1_edge(ec, vc, vr, av, w0, w1, w2, acc0, acc1, s);
        conv1_edge(ed, vd, vr, av, w0, w1, w2, acc0, acc1, s);
    }
    for (; pos < end; ++pos) {
        const uint4 e = sE[pos];
        const unsigned int v = xl[(size_t)e.x * 64 + lane];
        conv1_edge(e, v, vr, av, w0, w1, w2, acc0, acc1, s);
    }
    const float inv = 1.f / (s + 1e-16f);
    const float o0 = fmaxf(acc0 * inv + bv.x, 0.f);
    const float o1 = fmaxf(acc1 * inv + bv.y, 0.f);
    *(float2*)(outF + (size_t)d * HC + ch) = make_float2(o0, o1);
}

// ---------------------------------------------------------------------------
// conv2 fused: one wave per user u; bf16 xl2/xr2; bf16 H out; 2-way unroll.
// ---------------------------------------------------------------------------
__device__ __forceinline__ void conv2_edge(unsigned int vbits, float2 vr, float2 av,
                                           float& acc0, float& acc1, float& s)
{
    const float2 vl = unpack_bf2(vbits);
    float h0 = vl.x + vr.x;
    float h1 = vl.y + vr.y;
    h0 = h0 > 0.f ? h0 : 0.2f * h0;
    h1 = h1 > 0.f ? h1 : 0.2f * h1;
    const float p = head_reduce(h0 * av.x + h1 * av.y);
    const float ex = __expf(p);
    acc0 = fmaf(ex, vl.x, acc0);
    acc1 = fmaf(ex, vl.y, acc1);
    s += ex;
}

__global__ void conv2_fused(const unsigned int* __restrict__ xl2,
                            const unsigned int* __restrict__ xr2,
                            const int* __restrict__ off_end, const int* __restrict__ cnt,
                            const int* __restrict__ sFund,
                            const float* __restrict__ att, const float* __restrict__ cbias,
                            unsigned int* __restrict__ H, int nusr)
{
    const int tid = threadIdx.x;
    const int lane = tid & 63;
    const int wid = tid >> 6;
    const int u = blockIdx.x * 4 + wid;
    if (u >= nusr) return;

    const int ch = lane * 2;
    const float2 av = *(const float2*)(att + ch);
    const float2 bv = *(const float2*)(cbias + ch);
    const float2 vr = unpack_bf2(xr2[(size_t)u * 64 + lane]);

    const int end = off_end[u];
    const int start = end - cnt[u];

    float acc0 = 0.f, acc1 = 0.f, s = 0.f;
    int pos = start;
    for (; pos + 2 <= end; pos += 2) {
        const int fa = sFund[pos];
        const int fb = sFund[pos + 1];
        const unsigned int va = xl2[(size_t)fa * 64 + lane];
        const unsigned int vb = xl2[(size_t)fb * 64 + lane];
        conv2_edge(va, vr, av, acc0, acc1, s);
        conv2_edge(vb, vr, av, acc0, acc1, s);
    }
    if (pos < end) {
        const unsigned int v = xl2[(size_t)sFund[pos] * 64 + lane];
        conv2_edge(v, vr, av, acc0, acc1, s);
    }
    const float inv = 1.f / (s + 1e-16f);
    H[(size_t)u * 64 + lane] = pack_bf2(acc0 * inv + bv.x, acc1 * inv + bv.y);
}

// ---------------------------------------------------------------------------
// Classifier: out = sigmoid(relu(X@W1+b1)@W2+b2), X bf16-packed [M,128]
// ---------------------------------------------------------------------------
__global__ void classifier_tiled(const unsigned int* __restrict__ X,
                                 const float* __restrict__ W1, const float* __restrict__ b1,
                                 const float* __restrict__ W2, const float* __restrict__ b2,
                                 float* __restrict__ out, int M)
{
    __shared__ float W1L[128 * 64];
    __shared__ float Xs[64 * 68];

    const int tid = threadIdx.x;
    for (int i = tid; i < 128 * 64 / 4; i += 256)
        ((float4*)W1L)[i] = ((const float4*)W1)[i];

    const int u0 = blockIdx.x * 64;
    const int rows = min(64, M - u0);

    const int cg = tid & 15;
    const int rg = tid >> 4;
    const int c  = cg * 4;
    const int r0 = rg * 4;

    const float4 b1v = *(const float4*)(b1 + c);
    const float4 w2v = *(const float4*)(W2 + c);

    float acc[4][4] = {{0.f}};

    for (int half = 0; half < 2; ++half) {
        __syncthreads();
        for (int i = tid; i < 1024; i += 256) {
            const int r = i >> 4;
            const int f4 = i & 15;
            float4 v = make_float4(0.f, 0.f, 0.f, 0.f);
            if (r < rows) {
                const uint2 u2 = ((const uint2*)X)[(size_t)(u0 + r) * 32 + half * 16 + f4];
                const float2 ab = unpack_bf2(u2.x);
                const float2 cd = unpack_bf2(u2.y);
                v = make_float4(ab.x, ab.y, cd.x, cd.y);
            }
            *(float4*)(Xs + r * 68 + f4 * 4) = v;
        }
        __syncthreads();

        const float* W1h = W1L + half * 64 * 64;
        #pragma unroll 4
        for (int kc = 0; kc < 64; kc += 4) {
            const float4 wa = *(const float4*)(W1h + (kc    ) * 64 + c);
            const float4 wb = *(const float4*)(W1h + (kc + 1) * 64 + c);
            const float4 wc = *(const float4*)(W1h + (kc + 2) * 64 + c);
            const float4 wd = *(const float4*)(W1h + (kc + 3) * 64 + c);
            #pragma unroll
            for (int i = 0; i < 4; ++i) {
                const float4 xv = *(const float4*)(Xs + (r0 + i) * 68 + kc);
                acc[i][0] = fmaf(xv.x, wa.x, fmaf(xv.y, wb.x, fmaf(xv.z, wc.x, fmaf(xv.w, wd.x, acc[i][0]))));
                acc[i][1] = fmaf(xv.x, wa.y, fmaf(xv.y, wb.y, fmaf(xv.z, wc.y, fmaf(xv.w, wd.y, acc[i][1]))));
                acc[i][2] = fmaf(xv.x, wa.z, fmaf(xv.y, wb.z, fmaf(xv.z, wc.z, fmaf(xv.w, wd.z, acc[i][2]))));
                acc[i][3] = fmaf(xv.x, wa.w, fmaf(xv.y, wb.w, fmaf(xv.z, wc.w, fmaf(xv.w, wd.w, acc[i][3]))));
            }
        }
    }

    float p[4];
    #pragma unroll
    for (int i = 0; i < 4; ++i) {
        float h = fmaxf(acc[i][0] + b1v.x, 0.f) * w2v.x;
        h = fmaf(fmaxf(acc[i][1] + b1v.y, 0.f), w2v.y, h);
        h = fmaf(fmaxf(acc[i][2] + b1v.z, 0.f), w2v.z, h);
        h = fmaf(fmaxf(acc[i][3] + b1v.w, 0.f), w2v.w, h);
        p[i] = h;
    }
    #pragma unroll
    for (int i = 0; i < 4; ++i) {
        p[i] += __shfl_xor(p[i], 1, 16);
        p[i] += __shfl_xor(p[i], 2, 16);
        p[i] += __shfl_xor(p[i], 4, 16);
        p[i] += __shfl_xor(p[i], 8, 16);
    }
    if (cg == 0) {
        const float bb = b2[0];
        #pragma unroll
        for (int i = 0; i < 4; ++i) {
            const int r = r0 + i;
            if (r < rows) out[u0 + r] = 1.f / (1.f + expf(-(p[i] + bb)));
        }
    }
}

// ---------------------------------------------------------------------------
extern "C" void kernel_launch(void* const* d_in, const int* in_sizes, int n_in,
                              void* d_out, int out_size, void* d_ws, size_t ws_size,
                              hipStream_t stream)
{
    const float* customer_x = (const float*)d_in[0];
    const float* fund_x     = (const float*)d_in[1];
    const float* edge_attr  = (const float*)d_in[2];
    const int*   edge_src   = (const int*)d_in[3];
    const int*   edge_dst   = (const int*)d_in[4];
    const float* user_W = (const float*)d_in[5];
    const float* user_b = (const float*)d_in[6];
    const float* item_W = (const float*)d_in[7];
    const float* item_b = (const float*)d_in[8];
    const float* c1_Wl  = (const float*)d_in[9];
    const float* c1_bl  = (const float*)d_in[10];
    const float* c1_Wr  = (const float*)d_in[11];
    const float* c1_br  = (const float*)d_in[12];
    const float* c1_We  = (const float*)d_in[13];
    const float* c1_att = (const float*)d_in[14];
    const float* c1_bias= (const float*)d_in[15];
    const float* c2_Wl  = (const float*)d_in[16];
    const float* c2_bl  = (const float*)d_in[17];
    const float* c2_Wr  = (const float*)d_in[18];
    const float* c2_br  = (const float*)d_in[19];
    const float* c2_att = (const float*)d_in[20];
    const float* c2_bias= (const float*)d_in[21];
    const float* cls_W1 = (const float*)d_in[22];
    const float* cls_b1 = (const float*)d_in[23];
    const float* cls_W2 = (const float*)d_in[24];
    const float* cls_b2 = (const float*)d_in[25];
    float* out = (float*)d_out;

    float* ws = (float*)d_ws;
    // region0 (32M floats = 128MB): early A/Ix/C/F, later H (bf16 [NU,64] uints)
    unsigned int* H = (unsigned int*)ws;
    float* A  = ws;                                   // user_x   [NU,32]
    float* Ix = A + (size_t)NU * 32;                  // item_x   [NI,32]
    float* C  = Ix + (size_t)NI * 32;                 // xr1      [NI,128] fp32
    float* F  = C + (size_t)NI * HC;                  // item_h   [NI,128] fp32
    size_t off = (size_t)NU * 64;                     // 32M elems
    unsigned int* B = (unsigned int*)(ws + off); off += (size_t)NU * 64;  // xl1/xr2 bf16
    unsigned int* G = (unsigned int*)(ws + off); off += (size_t)NI * 64;  // xl2 bf16
    int* cnt1  = (int*)(ws + off); off += NI;
    int* off1  = (int*)(ws + off); off += NI;
    int* cnt2  = (int*)(ws + off); off += NU;
    int* off2  = (int*)(ws + off); off += NU;
    int* bs    = (int*)(ws + off); off += 1024;
    int* bss   = (int*)(ws + off); off += 1024;
    uint4* sE1 = (uint4*)(ws + off); off += (size_t)NE * 4;   // conv1 edge payload
    int* sFund = (int*)(ws + off); off += NE;

    hipMemsetAsync(cnt1, 0, NI * sizeof(int), stream);
    hipMemsetAsync(cnt2, 0, NU * sizeof(int), stream);

    // CSR build
    hist_both<<<1024, 256, 0, stream>>>(edge_src, edge_dst, cnt2, cnt1, NE);
    const int nb1 = (NI + 1023) / 1024;
    const int nb2 = (NU + 1023) / 1024;
    scan_blocks<<<nb1, 256, 0, stream>>>(cnt1, off1, bs, NI);
    scan_blocks<<<1,   256, 0, stream>>>(bs, bss, nullptr, nb1);
    scan_add<<<nb1, 256, 0, stream>>>(off1, bss, NI);
    scan_blocks<<<nb2, 256, 0, stream>>>(cnt2, off2, bs, NU);
    scan_blocks<<<1,   256, 0, stream>>>(bs, bss, nullptr, nb2);
    scan_add<<<nb2, 256, 0, stream>>>(off2, bss, NU);
    scatter_both<<<1024, 256, 0, stream>>>(edge_src, edge_dst, edge_attr,
                                           off2, off1, sFund, sE1, NE);

    // projections
    gemm_cx_readlane<<<2048, 256, 0, stream>>>(customer_x, user_W, user_b, A, NU);
    const dim3 b32(32, 8, 1);
    gemm_rows<<<1024, b32, 1 * 32 * 4, stream>>>(fund_x, item_W, item_b, Ix,
                                                 NI, 1, 32, 0);
    gemm_user_readlane_bf16<<<2048, 256, 0, stream>>>(A, c1_Wl, c1_bl, B, NU);  // xl1
    gemm_rows<<<2048, dim3(128, 2, 1), 32 * 128 * 4, stream>>>(Ix, c1_Wr, c1_br, C,
                                                               NI, 32, HC, 0);  // xr1 fp32

    // conv1: customer -> fund (+bias+relu), fp32 out F
    conv1_fused<<<NI / 4, 256, 0, stream>>>(B, C, off1, cnt1, sE1,
                                            c1_We, c1_att, c1_bias, F, NI);

    // xl2 = item_h @ c2_Wl + c2_bl  (bf16 out)
    gemm_item_readlane_bf16<<<512, 256, 0, stream>>>(F, c2_Wl, c2_bl,
                                                     (unsigned short*)G, NI);
    // xr2 = user_x @ c2_Wr + c2_br  (bf16 out, overwrites B)
    gemm_user_readlane_bf16<<<2048, 256, 0, stream>>>(A, c2_Wr, c2_br, B, NU);

    // conv2: fund -> customer, bf16 H
    conv2_fused<<<NU / 4, 256, 0, stream>>>(G, B, off2, cnt2, sFund,
                                            c2_att, c2_bias, H, NU);

    // classifier
    classifier_tiled<<<(NU + 63) / 64, 256, 0, stream>>>(H, cls_W1, cls_b1,
                                                         cls_W2, cls_b2, out, NU);
}

// Round 7
// 823.404 us; speedup vs baseline: 5.0781x; 1.3678x over previous
//
#include <hip/hip_runtime.h>
#include <cstdint>
#include <cstddef>

#define NU 500000
#define NI 50000
#define NE 1000000
#define HC 128   // H*C
#define NH 4

typedef __attribute__((ext_vector_type(8))) short bf16x8;
typedef __attribute__((ext_vector_type(4))) float f32x4;

union frag_u { bf16x8 v; unsigned int u[4]; };

// bf16 pack/unpack (RNE)
__device__ __forceinline__ unsigned int pack_bf2(float x, float y) {
    unsigned int xb = __float_as_uint(x);
    unsigned int yb = __float_as_uint(y);
    xb += 0x7fffu + ((xb >> 16) & 1u);
    yb += 0x7fffu + ((yb >> 16) & 1u);
    return (xb >> 16) | (yb & 0xffff0000u);
}
__device__ __forceinline__ float2 unpack_bf2(unsigned int v) {
    return make_float2(__uint_as_float(v << 16),
                       __uint_as_float(v & 0xffff0000u));
}
__device__ __forceinline__ unsigned short pack_bf1(float x) {
    unsigned int b = __float_as_uint(x);
    b += 0x7fffu + ((b >> 16) & 1u);
    return (unsigned short)(b >> 16);
}

__device__ __forceinline__ float head_reduce(float p) {
    p += __shfl_xor(p, 8, 16);
    p += __shfl_xor(p, 4, 16);
    p += __shfl_xor(p, 2, 16);
    p += __shfl_xor(p, 1, 16);
    return p;
}

// ---------------------------------------------------------------------------
// Weight prep: Bp holds 3 matrices in MFMA B-fragment order, bf16.
//  mat0: Wc1[k][n] = user_W@c1_Wl (k<101); row k=101 = user_b@c1_Wl + c1_bl
//  mat1: Wc2[k][n] = user_W@c2_Wr (k<101); row k=101 = user_b@c2_Wr + c2_br
//  mat2: c2_Wl[k][n] (k<128)
// B-frag layout (16x16x32): lane = (n&15) + 16*((k>>3)&3), elem j = k&7
// ---------------------------------------------------------------------------
__global__ void wprep(const float* __restrict__ user_W, const float* __restrict__ user_b,
                      const float* __restrict__ c1_Wl, const float* __restrict__ c1_bl,
                      const float* __restrict__ c2_Wr, const float* __restrict__ c2_br,
                      const float* __restrict__ c2_Wl, unsigned short* __restrict__ Bp)
{
    const int t = blockIdx.x * 256 + threadIdx.x;   // 0..49151
    const int mat = t >> 14;
    const int k = (t >> 7) & 127;
    const int n = t & 127;
    float val = 0.f;
    if (mat == 2) {
        val = c2_Wl[k * 128 + n];
    } else {
        const float* W2 = mat ? c2_Wr : c1_Wl;
        if (k < 101) {
            for (int q = 0; q < 32; ++q) val = fmaf(user_W[k * 32 + q], W2[q * 128 + n], val);
        } else if (k == 101) {
            for (int q = 0; q < 32; ++q) val = fmaf(user_b[q], W2[q * 128 + n], val);
            val += (mat ? c2_br : c1_bl)[n];
        }
    }
    const int fi = (mat * 8 + (n >> 4)) * 4 + (k >> 5);
    const int lane_ = (n & 15) + ((k >> 3) & 3) * 16;
    Bp[(size_t)fi * 512 + lane_ * 8 + (k & 7)] = pack_bf1(val);
}

// ---------------------------------------------------------------------------
// xr1 rank-1: wv[j] = item_W@c1_Wr, bb[j] = item_b@c1_Wr + c1_br
// ---------------------------------------------------------------------------
__global__ void wvbb_prep(const float* __restrict__ item_W, const float* __restrict__ item_b,
                          const float* __restrict__ c1_Wr, const float* __restrict__ c1_br,
                          float* __restrict__ wvbb)
{
    const int j = threadIdx.x;
    if (j >= 128) return;
    float wv = 0.f, bb = 0.f;
    for (int q = 0; q < 32; ++q) {
        wv = fmaf(item_W[q], c1_Wr[q * 128 + j], wv);
        bb = fmaf(item_b[q], c1_Wr[q * 128 + j], bb);
    }
    wvbb[j] = wv;
    wvbb[128 + j] = bb + c1_br[j];
}

__global__ void xr1_outer(const float* __restrict__ fund_x, const float* __restrict__ wvbb,
                          float* __restrict__ C, int n)
{
    for (int i = blockIdx.x * blockDim.x + threadIdx.x; i < n;
         i += gridDim.x * blockDim.x) {
        const int row = i >> 7, j = i & 127;
        C[i] = fmaf(fund_x[row], wvbb[j], wvbb[128 + j]);
    }
}

// ---------------------------------------------------------------------------
// MFMA: [NU,101(+bias)] fp32 @ Wc{1,2} -> xl1, xr2 (bf16). Wave = 16 rows x 256 cols.
// A-frag: row = lane&15, k = 8*(lane>>4)+j. D: col = lane&15, row = 4*(lane>>4)+j.
// ---------------------------------------------------------------------------
__global__ __launch_bounds__(256)
void mfma_user(const float* __restrict__ cx, const unsigned short* __restrict__ Bp,
               unsigned short* __restrict__ outL, unsigned short* __restrict__ outR, int M)
{
    const int lane = threadIdx.x & 63;
    const int wt = (blockIdx.x * blockDim.x + threadIdx.x) >> 6;
    const int rowbase = wt * 16;
    if (rowbase >= M) return;
    const int chunk = lane >> 4;
    const float* rowp = cx + (size_t)(rowbase + (lane & 15)) * 101;

    frag_u a[4];
    #pragma unroll
    for (int ks = 0; ks < 3; ++ks) {
        const int kb = ks * 32 + chunk * 8;
        const float v0 = rowp[kb + 0], v1 = rowp[kb + 1];
        const float v2 = rowp[kb + 2], v3 = rowp[kb + 3];
        const float v4 = rowp[kb + 4], v5 = rowp[kb + 5];
        const float v6 = rowp[kb + 6], v7 = rowp[kb + 7];
        a[ks].u[0] = pack_bf2(v0, v1);
        a[ks].u[1] = pack_bf2(v2, v3);
        a[ks].u[2] = pack_bf2(v4, v5);
        a[ks].u[3] = pack_bf2(v6, v7);
    }
    {   // kstep 3: k 96..100 real, k=101 -> 1.0 (bias row), rest 0
        float v0 = 0.f, v1 = 0.f, v2 = 0.f, v3 = 0.f, v4 = 0.f, v5 = 0.f;
        if (chunk == 0) {
            v0 = rowp[96]; v1 = rowp[97]; v2 = rowp[98]; v3 = rowp[99]; v4 = rowp[100];
            v5 = 1.0f;
        }
        a[3].u[0] = pack_bf2(v0, v1);
        a[3].u[1] = pack_bf2(v2, v3);
        a[3].u[2] = pack_bf2(v4, v5);
        a[3].u[3] = 0u;
    }

    const bf16x8* bfr = (const bf16x8*)Bp;
    #pragma unroll
    for (int mat = 0; mat < 2; ++mat) {
        unsigned short* outp = mat ? outR : outL;
        #pragma unroll
        for (int nf = 0; nf < 8; ++nf) {
            f32x4 acc = {0.f, 0.f, 0.f, 0.f};
            const int fi = (mat * 8 + nf) * 4;
            acc = __builtin_amdgcn_mfma_f32_16x16x32_bf16(a[0].v, bfr[(fi + 0) * 64 + lane], acc, 0, 0, 0);
            acc = __builtin_amdgcn_mfma_f32_16x16x32_bf16(a[1].v, bfr[(fi + 1) * 64 + lane], acc, 0, 0, 0);
            acc = __builtin_amdgcn_mfma_f32_16x16x32_bf16(a[2].v, bfr[(fi + 2) * 64 + lane], acc, 0, 0, 0);
            acc = __builtin_amdgcn_mfma_f32_16x16x32_bf16(a[3].v, bfr[(fi + 3) * 64 + lane], acc, 0, 0, 0);
            const int col = nf * 16 + (lane & 15);
            #pragma unroll
            for (int j = 0; j < 4; ++j)
                outp[(size_t)(rowbase + chunk * 4 + j) * 128 + col] = pack_bf1(acc[j]);
        }
    }
}

// ---------------------------------------------------------------------------
// MFMA: xl2 = item_h[NI,128] @ c2_Wl + c2_bl -> bf16
// ---------------------------------------------------------------------------
__global__ __launch_bounds__(256)
void mfma_xl2(const float* __restrict__ X, const unsigned short* __restrict__ Bp,
              const float* __restrict__ bias, unsigned short* __restrict__ outp, int M)
{
    const int lane = threadIdx.x & 63;
    const int wt = (blockIdx.x * blockDim.x + threadIdx.x) >> 6;
    const int rowbase = wt * 16;
    if (rowbase >= M) return;
    const int chunk = lane >> 4;
    const float* rowp = X + (size_t)(rowbase + (lane & 15)) * 128;

    frag_u a[4];
    #pragma unroll
    for (int ks = 0; ks < 4; ++ks) {
        const int kb = ks * 32 + chunk * 8;
        const float4 p = *(const float4*)(rowp + kb);
        const float4 q = *(const float4*)(rowp + kb + 4);
        a[ks].u[0] = pack_bf2(p.x, p.y);
        a[ks].u[1] = pack_bf2(p.z, p.w);
        a[ks].u[2] = pack_bf2(q.x, q.y);
        a[ks].u[3] = pack_bf2(q.z, q.w);
    }

    const bf16x8* bfr = (const bf16x8*)Bp;
    #pragma unroll
    for (int nf = 0; nf < 8; ++nf) {
        f32x4 acc = {0.f, 0.f, 0.f, 0.f};
        const int fi = (16 + nf) * 4;   // mat 2
        acc = __builtin_amdgcn_mfma_f32_16x16x32_bf16(a[0].v, bfr[(fi + 0) * 64 + lane], acc, 0, 0, 0);
        acc = __builtin_amdgcn_mfma_f32_16x16x32_bf16(a[1].v, bfr[(fi + 1) * 64 + lane], acc, 0, 0, 0);
        acc = __builtin_amdgcn_mfma_f32_16x16x32_bf16(a[2].v, bfr[(fi + 2) * 64 + lane], acc, 0, 0, 0);
        acc = __builtin_amdgcn_mfma_f32_16x16x32_bf16(a[3].v, bfr[(fi + 3) * 64 + lane], acc, 0, 0, 0);
        const int col = nf * 16 + (lane & 15);
        const float bv = bias[col];
        #pragma unroll
        for (int j = 0; j < 4; ++j)
            outp[(size_t)(rowbase + chunk * 4 + j) * 128 + col] = pack_bf1(acc[j] + bv);
    }
}

// ---------------------------------------------------------------------------
// CSR build
// ---------------------------------------------------------------------------
__global__ void hist_both(const int* __restrict__ src, const int* __restrict__ dst,
                          int* __restrict__ cntU, int* __restrict__ cntI, int E)
{
    for (int i = blockIdx.x * blockDim.x + threadIdx.x; i < E;
         i += gridDim.x * blockDim.x) {
        atomicAdd(&cntU[src[i]], 1);
        atomicAdd(&cntI[dst[i]], 1);
    }
}

__global__ void scan_blocks(const int* __restrict__ in, int* __restrict__ out,
                            int* __restrict__ blockSums, int n)
{
    __shared__ int lds[256];
    const int tid = threadIdx.x;
    const int base = blockIdx.x * 1024 + tid * 4;
    int v[4];
    #pragma unroll
    for (int j = 0; j < 4; ++j) { int idx = base + j; v[j] = (idx < n) ? in[idx] : 0; }
    int t = v[0] + v[1] + v[2] + v[3];
    lds[tid] = t;
    __syncthreads();
    for (int off = 1; off < 256; off <<= 1) {
        int x = (tid >= off) ? lds[tid - off] : 0;
        __syncthreads();
        lds[tid] += x;
        __syncthreads();
    }
    int excl = lds[tid] - t;
    if (tid == 255 && blockSums) blockSums[blockIdx.x] = lds[255];
    int run = excl;
    #pragma unroll
    for (int j = 0; j < 4; ++j) {
        int idx = base + j;
        if (idx < n) out[idx] = run;
        run += v[j];
    }
}

__global__ void scan_add(int* __restrict__ out, const int* __restrict__ bss, int n)
{
    const int add = bss[blockIdx.x];
    const int base = blockIdx.x * 1024 + threadIdx.x * 4;
    #pragma unroll
    for (int j = 0; j < 4; ++j) { int idx = base + j; if (idx < n) out[idx] += add; }
}

__global__ void scatter_both(const int* __restrict__ src, const int* __restrict__ dst,
                             const float* __restrict__ eattr,
                             int* __restrict__ offU, int* __restrict__ offI,
                             int* __restrict__ sFund, uint4* __restrict__ sE1, int E)
{
    for (int i = blockIdx.x * blockDim.x + threadIdx.x; i < E;
         i += gridDim.x * blockDim.x) {
        const int s = src[i];
        const int d = dst[i];
        const float a0 = eattr[3 * (size_t)i];
        const float a1 = eattr[3 * (size_t)i + 1];
        const float a2 = eattr[3 * (size_t)i + 2];
        const int p1 = atomicAdd(&offI[d], 1);
        sE1[p1] = make_uint4((unsigned int)s, __float_as_uint(a0),
                             __float_as_uint(a1), __float_as_uint(a2));
        const int p2 = atomicAdd(&offU[s], 1);
        sFund[p2] = d;
    }
}

// ---------------------------------------------------------------------------
// conv1 fused: one wave per fund d; xl bf16-packed; 4-way unrolled gathers.
// ---------------------------------------------------------------------------
__device__ __forceinline__ void conv1_edge(uint4 e, unsigned int vbits, float2 vr,
                                           float2 av, float2 w0, float2 w1, float2 w2,
                                           float& acc0, float& acc1, float& s)
{
    const float2 vl = unpack_bf2(vbits);
    const float e0 = __uint_as_float(e.y);
    const float e1 = __uint_as_float(e.z);
    const float e2 = __uint_as_float(e.w);
    float h0 = vl.x + vr.x + e0 * w0.x + e1 * w1.x + e2 * w2.x;
    float h1 = vl.y + vr.y + e0 * w0.y + e1 * w1.y + e2 * w2.y;
    h0 = h0 > 0.f ? h0 : 0.2f * h0;
    h1 = h1 > 0.f ? h1 : 0.2f * h1;
    const float p = head_reduce(h0 * av.x + h1 * av.y);
    const float ex = __expf(p);
    acc0 = fmaf(ex, vl.x, acc0);
    acc1 = fmaf(ex, vl.y, acc1);
    s += ex;
}

__global__ void conv1_fused(const unsigned int* __restrict__ xl,
                            const float* __restrict__ xr,
                            const int* __restrict__ off_end, const int* __restrict__ cnt,
                            const uint4* __restrict__ sE,
                            const float* __restrict__ We, const float* __restrict__ att,
                            const float* __restrict__ bias,
                            float* __restrict__ outF, int ndst)
{
    const int tid = threadIdx.x;
    const int lane = tid & 63;
    const int wid = tid >> 6;
    const int d = blockIdx.x * 4 + wid;
    if (d >= ndst) return;

    const int ch = lane * 2;
    const float2 av = *(const float2*)(att + ch);
    const float2 w0 = *(const float2*)(We + ch);
    const float2 w1 = *(const float2*)(We + HC + ch);
    const float2 w2 = *(const float2*)(We + 2 * HC + ch);
    const float2 bv = *(const float2*)(bias + ch);
    const float2 vr = *(const float2*)(xr + (size_t)d * HC + ch);

    const int end = off_end[d];
    const int start = end - cnt[d];

    float acc0 = 0.f, acc1 = 0.f, s = 0.f;
    int pos = start;
    for (; pos + 4 <= end; pos += 4) {
        const uint4 ea = sE[pos], eb = sE[pos + 1], ec = sE[pos + 2], ed = sE[pos + 3];
        const unsigned int va = xl[(size_t)ea.x * 64 + lane];
        const unsigned int vb = xl[(size_t)eb.x * 64 + lane];
        const unsigned int vc = xl[(size_t)ec.x * 64 + lane];
        const unsigned int vd = xl[(size_t)ed.x * 64 + lane];
        conv1_edge(ea, va, vr, av, w0, w1, w2, acc0, acc1, s);
        conv1_edge(eb, vb, vr, av, w0, w1, w2, acc0, acc1, s);
        conv1_edge(ec, vc, vr, av, w0, w1, w2, acc0, acc1, s);
        conv1_edge(ed, vd, vr, av, w0, w1, w2, acc0, acc1, s);
    }
    for (; pos < end; ++pos) {
        const uint4 e = sE[pos];
        const unsigned int v = xl[(size_t)e.x * 64 + lane];
        conv1_edge(e, v, vr, av, w0, w1, w2, acc0, acc1, s);
    }
    const float inv = 1.f / (s + 1e-16f);
    const float o0 = fmaxf(acc0 * inv + bv.x, 0.f);
    const float o1 = fmaxf(acc1 * inv + bv.y, 0.f);
    *(float2*)(outF + (size_t)d * HC + ch) = make_float2(o0, o1);
}

// ---------------------------------------------------------------------------
// conv2 fused: one wave per user u; bf16 in/out; 2-way unroll.
// ---------------------------------------------------------------------------
__device__ __forceinline__ void conv2_edge(unsigned int vbits, float2 vr, float2 av,
                                           float& acc0, float& acc1, float& s)
{
    const float2 vl = unpack_bf2(vbits);
    float h0 = vl.x + vr.x;
    float h1 = vl.y + vr.y;
    h0 = h0 > 0.f ? h0 : 0.2f * h0;
    h1 = h1 > 0.f ? h1 : 0.2f * h1;
    const float p = head_reduce(h0 * av.x + h1 * av.y);
    const float ex = __expf(p);
    acc0 = fmaf(ex, vl.x, acc0);
    acc1 = fmaf(ex, vl.y, acc1);
    s += ex;
}

__global__ void conv2_fused(const unsigned int* __restrict__ xl2,
                            const unsigned int* __restrict__ xr2,
                            const int* __restrict__ off_end, const int* __restrict__ cnt,
                            const int* __restrict__ sFund,
                            const float* __restrict__ att, const float* __restrict__ cbias,
                            unsigned int* __restrict__ H, int nusr)
{
    const int tid = threadIdx.x;
    const int lane = tid & 63;
    const int wid = tid >> 6;
    const int u = blockIdx.x * 4 + wid;
    if (u >= nusr) return;

    const int ch = lane * 2;
    const float2 av = *(const float2*)(att + ch);
    const float2 bv = *(const float2*)(cbias + ch);
    const float2 vr = unpack_bf2(xr2[(size_t)u * 64 + lane]);

    const int end = off_end[u];
    const int start = end - cnt[u];

    float acc0 = 0.f, acc1 = 0.f, s = 0.f;
    int pos = start;
    for (; pos + 2 <= end; pos += 2) {
        const int fa = sFund[pos];
        const int fb = sFund[pos + 1];
        const unsigned int va = xl2[(size_t)fa * 64 + lane];
        const unsigned int vb = xl2[(size_t)fb * 64 + lane];
        conv2_edge(va, vr, av, acc0, acc1, s);
        conv2_edge(vb, vr, av, acc0, acc1, s);
    }
    if (pos < end) {
        const unsigned int v = xl2[(size_t)sFund[pos] * 64 + lane];
        conv2_edge(v, vr, av, acc0, acc1, s);
    }
    const float inv = 1.f / (s + 1e-16f);
    H[(size_t)u * 64 + lane] = pack_bf2(acc0 * inv + bv.x, acc1 * inv + bv.y);
}

// ---------------------------------------------------------------------------
// Classifier: out = sigmoid(relu(X@W1+b1)@W2+b2), X bf16-packed [M,128]
// ---------------------------------------------------------------------------
__global__ void classifier_tiled(const unsigned int* __restrict__ X,
                                 const float* __restrict__ W1, const float* __restrict__ b1,
                                 const float* __restrict__ W2, const float* __restrict__ b2,
                                 float* __restrict__ out, int M)
{
    __shared__ float W1L[128 * 64];
    __shared__ float Xs[64 * 68];

    const int tid = threadIdx.x;
    for (int i = tid; i < 128 * 64 / 4; i += 256)
        ((float4*)W1L)[i] = ((const float4*)W1)[i];

    const int u0 = blockIdx.x * 64;
    const int rows = min(64, M - u0);

    const int cg = tid & 15;
    const int rg = tid >> 4;
    const int c  = cg * 4;
    const int r0 = rg * 4;

    const float4 b1v = *(const float4*)(b1 + c);
    const float4 w2v = *(const float4*)(W2 + c);

    float acc[4][4] = {{0.f}};

    for (int half = 0; half < 2; ++half) {
        __syncthreads();
        for (int i = tid; i < 1024; i += 256) {
            const int r = i >> 4;
            const int f4 = i & 15;
            float4 v = make_float4(0.f, 0.f, 0.f, 0.f);
            if (r < rows) {
                const uint2 u2 = ((const uint2*)X)[(size_t)(u0 + r) * 32 + half * 16 + f4];
                const float2 ab = unpack_bf2(u2.x);
                const float2 cd = unpack_bf2(u2.y);
                v = make_float4(ab.x, ab.y, cd.x, cd.y);
            }
            *(float4*)(Xs + r * 68 + f4 * 4) = v;
        }
        __syncthreads();

        const float* W1h = W1L + half * 64 * 64;
        #pragma unroll 4
        for (int kc = 0; kc < 64; kc += 4) {
            const float4 wa = *(const float4*)(W1h + (kc    ) * 64 + c);
            const float4 wb = *(const float4*)(W1h + (kc + 1) * 64 + c);
            const float4 wc = *(const float4*)(W1h + (kc + 2) * 64 + c);
            const float4 wd = *(const float4*)(W1h + (kc + 3) * 64 + c);
            #pragma unroll
            for (int i = 0; i < 4; ++i) {
                const float4 xv = *(const float4*)(Xs + (r0 + i) * 68 + kc);
                acc[i][0] = fmaf(xv.x, wa.x, fmaf(xv.y, wb.x, fmaf(xv.z, wc.x, fmaf(xv.w, wd.x, acc[i][0]))));
                acc[i][1] = fmaf(xv.x, wa.y, fmaf(xv.y, wb.y, fmaf(xv.z, wc.y, fmaf(xv.w, wd.y, acc[i][1]))));
                acc[i][2] = fmaf(xv.x, wa.z, fmaf(xv.y, wb.z, fmaf(xv.z, wc.z, fmaf(xv.w, wd.z, acc[i][2]))));
                acc[i][3] = fmaf(xv.x, wa.w, fmaf(xv.y, wb.w, fmaf(xv.z, wc.w, fmaf(xv.w, wd.w, acc[i][3]))));
            }
        }
    }

    float p[4];
    #pragma unroll
    for (int i = 0; i < 4; ++i) {
        float h = fmaxf(acc[i][0] + b1v.x, 0.f) * w2v.x;
        h = fmaf(fmaxf(acc[i][1] + b1v.y, 0.f), w2v.y, h);
        h = fmaf(fmaxf(acc[i][2] + b1v.z, 0.f), w2v.z, h);
        h = fmaf(fmaxf(acc[i][3] + b1v.w, 0.f), w2v.w, h);
        p[i] = h;
    }
    #pragma unroll
    for (int i = 0; i < 4; ++i) {
        p[i] += __shfl_xor(p[i], 1, 16);
        p[i] += __shfl_xor(p[i], 2, 16);
        p[i] += __shfl_xor(p[i], 4, 16);
        p[i] += __shfl_xor(p[i], 8, 16);
    }
    if (cg == 0) {
        const float bb = b2[0];
        #pragma unroll
        for (int i = 0; i < 4; ++i) {
            const int r = r0 + i;
            if (r < rows) out[u0 + r] = 1.f / (1.f + expf(-(p[i] + bb)));
        }
    }
}

// ---------------------------------------------------------------------------
extern "C" void kernel_launch(void* const* d_in, const int* in_sizes, int n_in,
                              void* d_out, int out_size, void* d_ws, size_t ws_size,
                              hipStream_t stream)
{
    const float* customer_x = (const float*)d_in[0];
    const float* fund_x     = (const float*)d_in[1];
    const float* edge_attr  = (const float*)d_in[2];
    const int*   edge_src   = (const int*)d_in[3];
    const int*   edge_dst   = (const int*)d_in[4];
    const float* user_W = (const float*)d_in[5];
    const float* user_b = (const float*)d_in[6];
    const float* item_W = (const float*)d_in[7];
    const float* item_b = (const float*)d_in[8];
    const float* c1_Wl  = (const float*)d_in[9];
    const float* c1_bl  = (const float*)d_in[10];
    const float* c1_Wr  = (const float*)d_in[11];
    const float* c1_br  = (const float*)d_in[12];
    const float* c1_We  = (const float*)d_in[13];
    const float* c1_att = (const float*)d_in[14];
    const float* c1_bias= (const float*)d_in[15];
    const float* c2_Wl  = (const float*)d_in[16];
    const float* c2_bl  = (const float*)d_in[17];
    const float* c2_Wr  = (const float*)d_in[18];
    const float* c2_br  = (const float*)d_in[19];
    const float* c2_att = (const float*)d_in[20];
    const float* c2_bias= (const float*)d_in[21];
    const float* cls_W1 = (const float*)d_in[22];
    const float* cls_b1 = (const float*)d_in[23];
    const float* cls_W2 = (const float*)d_in[24];
    const float* cls_b2 = (const float*)d_in[25];
    float* out = (float*)d_out;

    float* ws = (float*)d_ws;
    size_t off = 0;
    unsigned short* B1 = (unsigned short*)(ws + off); off += (size_t)NU * 64; // xl1 bf16; H aliases after conv1
    unsigned short* B2 = (unsigned short*)(ws + off); off += (size_t)NU * 64; // xr2 bf16
    float* C = ws + off; off += (size_t)NI * HC;                              // xr1 fp32
    float* F = ws + off; off += (size_t)NI * HC;                              // item_h fp32
    unsigned short* G = (unsigned short*)(ws + off); off += (size_t)NI * 64;  // xl2 bf16
    int* cnt1  = (int*)(ws + off); off += NI;
    int* off1  = (int*)(ws + off); off += NI;
    int* cnt2  = (int*)(ws + off); off += NU;
    int* off2  = (int*)(ws + off); off += NU;
    int* bs    = (int*)(ws + off); off += 1024;
    int* bss   = (int*)(ws + off); off += 1024;
    uint4* sE1 = (uint4*)(ws + off); off += (size_t)NE * 4;
    int* sFund = (int*)(ws + off); off += NE;
    unsigned short* Bp = (unsigned short*)(ws + off); off += 12288 + 256;     // 96KB frags
    float* wvbb = ws + off; off += 256;
    unsigned int* H = (unsigned int*)B1;

    hipMemsetAsync(cnt1, 0, NI * sizeof(int), stream);
    hipMemsetAsync(cnt2, 0, NU * sizeof(int), stream);

    // CSR build
    hist_both<<<1024, 256, 0, stream>>>(edge_src, edge_dst, cnt2, cnt1, NE);
    const int nb1 = (NI + 1023) / 1024;
    const int nb2 = (NU + 1023) / 1024;
    scan_blocks<<<nb1, 256, 0, stream>>>(cnt1, off1, bs, NI);
    scan_blocks<<<1,   256, 0, stream>>>(bs, bss, nullptr, nb1);
    scan_add<<<nb1, 256, 0, stream>>>(off1, bss, NI);
    scan_blocks<<<nb2, 256, 0, stream>>>(cnt2, off2, bs, NU);
    scan_blocks<<<1,   256, 0, stream>>>(bs, bss, nullptr, nb2);
    scan_add<<<nb2, 256, 0, stream>>>(off2, bss, NU);
    scatter_both<<<1024, 256, 0, stream>>>(edge_src, edge_dst, edge_attr,
                                           off2, off1, sFund, sE1, NE);

    // weight prep (3 B-matrices in fragment layout) + xr1 rank-1 weights
    wprep<<<192, 256, 0, stream>>>(user_W, user_b, c1_Wl, c1_bl,
                                   c2_Wr, c2_br, c2_Wl, Bp);
    wvbb_prep<<<1, 128, 0, stream>>>(item_W, item_b, c1_Wr, c1_br, wvbb);

    // xr1 = fund_x (rank-1) : [NI,128] fp32
    xr1_outer<<<2048, 256, 0, stream>>>(fund_x, wvbb, C, NI * HC);

    // xl1 & xr2 in one MFMA pass over customer_x
    mfma_user<<<(NU / 16 + 3) / 4, 256, 0, stream>>>(customer_x, Bp, B1, B2, NU);

    // conv1: customer -> fund (+bias+relu), fp32 out F
    conv1_fused<<<NI / 4, 256, 0, stream>>>((const unsigned int*)B1, C, off1, cnt1, sE1,
                                            c1_We, c1_att, c1_bias, F, NI);

    // xl2 = item_h @ c2_Wl + c2_bl (bf16)
    mfma_xl2<<<(NI / 16 + 3) / 4, 256, 0, stream>>>(F, Bp, c2_bl, G, NI);

    // conv2: fund -> customer, bf16 H (aliases B1; xl1 dead)
    conv2_fused<<<NU / 4, 256, 0, stream>>>((const unsigned int*)G, (const unsigned int*)B2,
                                            off2, cnt2, sFund, c2_att, c2_bias, H, NU);

    // classifier
    classifier_tiled<<<(NU + 63) / 64, 256, 0, stream>>>(H, cls_W1, cls_b1,
                                                         cls_W2, cls_b2, out, NU);
}

// Round 8
// 742.411 us; speedup vs baseline: 5.6321x; 1.1091x over previous
//
#include <hip/hip_runtime.h>
#include <cstdint>
#include <cstddef>

#define NU 500000
#define NI 50000
#define NE 1000000
#define HC 128   // H*C
#define NH 4

typedef __attribute__((ext_vector_type(8))) short bf16x8;
typedef __attribute__((ext_vector_type(4))) float f32x4;

union frag_u { bf16x8 v; unsigned int u[4]; };

// bf16 pack/unpack (RNE)
__device__ __forceinline__ unsigned int pack_bf2(float x, float y) {
    unsigned int xb = __float_as_uint(x);
    unsigned int yb = __float_as_uint(y);
    xb += 0x7fffu + ((xb >> 16) & 1u);
    yb += 0x7fffu + ((yb >> 16) & 1u);
    return (xb >> 16) | (yb & 0xffff0000u);
}
__device__ __forceinline__ float2 unpack_bf2(unsigned int v) {
    return make_float2(__uint_as_float(v << 16),
                       __uint_as_float(v & 0xffff0000u));
}
__device__ __forceinline__ unsigned short pack_bf1(float x) {
    unsigned int b = __float_as_uint(x);
    b += 0x7fffu + ((b >> 16) & 1u);
    return (unsigned short)(b >> 16);
}

__device__ __forceinline__ float head_reduce(float p) {
    p += __shfl_xor(p, 8, 16);
    p += __shfl_xor(p, 4, 16);
    p += __shfl_xor(p, 2, 16);
    p += __shfl_xor(p, 1, 16);
    return p;
}

// ---------------------------------------------------------------------------
// Weight prep: Bp holds 3 matrices in MFMA B-fragment order, bf16.
//  mat0: Wc1[k][n] = user_W@c1_Wl (k<101); row k=101 = user_b@c1_Wl + c1_bl
//  mat1: Wc2[k][n] = user_W@c2_Wr (k<101); row k=101 = user_b@c2_Wr + c2_br
//  mat2: c2_Wl[k][n] (k<128)
// B-frag layout (16x16x32): lane = (n&15) + 16*((k>>3)&3), elem j = k&7
// ---------------------------------------------------------------------------
__global__ void wprep(const float* __restrict__ user_W, const float* __restrict__ user_b,
                      const float* __restrict__ c1_Wl, const float* __restrict__ c1_bl,
                      const float* __restrict__ c2_Wr, const float* __restrict__ c2_br,
                      const float* __restrict__ c2_Wl, unsigned short* __restrict__ Bp)
{
    const int t = blockIdx.x * 256 + threadIdx.x;   // 0..49151
    const int mat = t >> 14;
    const int k = (t >> 7) & 127;
    const int n = t & 127;
    float val = 0.f;
    if (mat == 2) {
        val = c2_Wl[k * 128 + n];
    } else {
        const float* W2 = mat ? c2_Wr : c1_Wl;
        if (k < 101) {
            for (int q = 0; q < 32; ++q) val = fmaf(user_W[k * 32 + q], W2[q * 128 + n], val);
        } else if (k == 101) {
            for (int q = 0; q < 32; ++q) val = fmaf(user_b[q], W2[q * 128 + n], val);
            val += (mat ? c2_br : c1_bl)[n];
        }
    }
    const int fi = (mat * 8 + (n >> 4)) * 4 + (k >> 5);
    const int lane_ = (n & 15) + ((k >> 3) & 3) * 16;
    Bp[(size_t)fi * 512 + lane_ * 8 + (k & 7)] = pack_bf1(val);
}

// ---------------------------------------------------------------------------
// W1 (classifier, 128x64) -> B-fragment order, 16 frags (4 nf x 4 ks)
// ---------------------------------------------------------------------------
__global__ void w1prep(const float* __restrict__ W1, unsigned short* __restrict__ Bp1)
{
    const int t = blockIdx.x * 256 + threadIdx.x;   // 0..8191
    const int k = t >> 6;       // 0..127
    const int n = t & 63;       // 0..63
    const float val = W1[k * 64 + n];
    const int fi = (n >> 4) * 4 + (k >> 5);
    const int lane_ = (n & 15) + ((k >> 3) & 3) * 16;
    Bp1[(size_t)fi * 512 + lane_ * 8 + (k & 7)] = pack_bf1(val);
}

// ---------------------------------------------------------------------------
// xr1 rank-1: wv[j] = item_W@c1_Wr, bb[j] = item_b@c1_Wr + c1_br
// ---------------------------------------------------------------------------
__global__ void wvbb_prep(const float* __restrict__ item_W, const float* __restrict__ item_b,
                          const float* __restrict__ c1_Wr, const float* __restrict__ c1_br,
                          float* __restrict__ wvbb)
{
    const int j = threadIdx.x;
    if (j >= 128) return;
    float wv = 0.f, bb = 0.f;
    for (int q = 0; q < 32; ++q) {
        wv = fmaf(item_W[q], c1_Wr[q * 128 + j], wv);
        bb = fmaf(item_b[q], c1_Wr[q * 128 + j], bb);
    }
    wvbb[j] = wv;
    wvbb[128 + j] = bb + c1_br[j];
}

__global__ void xr1_outer(const float* __restrict__ fund_x, const float* __restrict__ wvbb,
                          float* __restrict__ C, int n)
{
    for (int i = blockIdx.x * blockDim.x + threadIdx.x; i < n;
         i += gridDim.x * blockDim.x) {
        const int row = i >> 7, j = i & 127;
        C[i] = fmaf(fund_x[row], wvbb[j], wvbb[128 + j]);
    }
}

// ---------------------------------------------------------------------------
// MFMA: [NU,101(+bias)] fp32 @ Wc{1,2} -> xl1, xr2 (bf16). Wave = 16 rows x 256 cols.
// A-frag: row = lane&15, k = 8*(lane>>4)+j (per kstep). D: col = lane&15, row = 4*(lane>>4)+j.
// ---------------------------------------------------------------------------
__global__ __launch_bounds__(256)
void mfma_user(const float* __restrict__ cx, const unsigned short* __restrict__ Bp,
               unsigned short* __restrict__ outL, unsigned short* __restrict__ outR, int M)
{
    const int lane = threadIdx.x & 63;
    const int wt = (blockIdx.x * blockDim.x + threadIdx.x) >> 6;
    const int rowbase = wt * 16;
    if (rowbase >= M) return;
    const int chunk = lane >> 4;
    const float* rowp = cx + (size_t)(rowbase + (lane & 15)) * 101;

    frag_u a[4];
    #pragma unroll
    for (int ks = 0; ks < 3; ++ks) {
        const int kb = ks * 32 + chunk * 8;
        const float v0 = rowp[kb + 0], v1 = rowp[kb + 1];
        const float v2 = rowp[kb + 2], v3 = rowp[kb + 3];
        const float v4 = rowp[kb + 4], v5 = rowp[kb + 5];
        const float v6 = rowp[kb + 6], v7 = rowp[kb + 7];
        a[ks].u[0] = pack_bf2(v0, v1);
        a[ks].u[1] = pack_bf2(v2, v3);
        a[ks].u[2] = pack_bf2(v4, v5);
        a[ks].u[3] = pack_bf2(v6, v7);
    }
    {   // kstep 3: k 96..100 real, k=101 -> 1.0 (bias row), rest 0
        float v0 = 0.f, v1 = 0.f, v2 = 0.f, v3 = 0.f, v4 = 0.f, v5 = 0.f;
        if (chunk == 0) {
            v0 = rowp[96]; v1 = rowp[97]; v2 = rowp[98]; v3 = rowp[99]; v4 = rowp[100];
            v5 = 1.0f;
        }
        a[3].u[0] = pack_bf2(v0, v1);
        a[3].u[1] = pack_bf2(v2, v3);
        a[3].u[2] = pack_bf2(v4, v5);
        a[3].u[3] = 0u;
    }

    const bf16x8* bfr = (const bf16x8*)Bp;
    #pragma unroll
    for (int mat = 0; mat < 2; ++mat) {
        unsigned short* outp = mat ? outR : outL;
        #pragma unroll
        for (int nf = 0; nf < 8; ++nf) {
            f32x4 acc = {0.f, 0.f, 0.f, 0.f};
            const int fi = (mat * 8 + nf) * 4;
            acc = __builtin_amdgcn_mfma_f32_16x16x32_bf16(a[0].v, bfr[(fi + 0) * 64 + lane], acc, 0, 0, 0);
            acc = __builtin_amdgcn_mfma_f32_16x16x32_bf16(a[1].v, bfr[(fi + 1) * 64 + lane], acc, 0, 0, 0);
            acc = __builtin_amdgcn_mfma_f32_16x16x32_bf16(a[2].v, bfr[(fi + 2) * 64 + lane], acc, 0, 0, 0);
            acc = __builtin_amdgcn_mfma_f32_16x16x32_bf16(a[3].v, bfr[(fi + 3) * 64 + lane], acc, 0, 0, 0);
            const int col = nf * 16 + (lane & 15);
            #pragma unroll
            for (int j = 0; j < 4; ++j)
                outp[(size_t)(rowbase + chunk * 4 + j) * 128 + col] = pack_bf1(acc[j]);
        }
    }
}

// ---------------------------------------------------------------------------
// MFMA: xl2 = item_h[NI,128] @ c2_Wl + c2_bl -> bf16
// ---------------------------------------------------------------------------
__global__ __launch_bounds__(256)
void mfma_xl2(const float* __restrict__ X, const unsigned short* __restrict__ Bp,
              const float* __restrict__ bias, unsigned short* __restrict__ outp, int M)
{
    const int lane = threadIdx.x & 63;
    const int wt = (blockIdx.x * blockDim.x + threadIdx.x) >> 6;
    const int rowbase = wt * 16;
    if (rowbase >= M) return;
    const int chunk = lane >> 4;
    const float* rowp = X + (size_t)(rowbase + (lane & 15)) * 128;

    frag_u a[4];
    #pragma unroll
    for (int ks = 0; ks < 4; ++ks) {
        const int kb = ks * 32 + chunk * 8;
        const float4 p = *(const float4*)(rowp + kb);
        const float4 q = *(const float4*)(rowp + kb + 4);
        a[ks].u[0] = pack_bf2(p.x, p.y);
        a[ks].u[1] = pack_bf2(p.z, p.w);
        a[ks].u[2] = pack_bf2(q.x, q.y);
        a[ks].u[3] = pack_bf2(q.z, q.w);
    }

    const bf16x8* bfr = (const bf16x8*)Bp;
    #pragma unroll
    for (int nf = 0; nf < 8; ++nf) {
        f32x4 acc = {0.f, 0.f, 0.f, 0.f};
        const int fi = (16 + nf) * 4;   // mat 2
        acc = __builtin_amdgcn_mfma_f32_16x16x32_bf16(a[0].v, bfr[(fi + 0) * 64 + lane], acc, 0, 0, 0);
        acc = __builtin_amdgcn_mfma_f32_16x16x32_bf16(a[1].v, bfr[(fi + 1) * 64 + lane], acc, 0, 0, 0);
        acc = __builtin_amdgcn_mfma_f32_16x16x32_bf16(a[2].v, bfr[(fi + 2) * 64 + lane], acc, 0, 0, 0);
        acc = __builtin_amdgcn_mfma_f32_16x16x32_bf16(a[3].v, bfr[(fi + 3) * 64 + lane], acc, 0, 0, 0);
        const int col = nf * 16 + (lane & 15);
        const float bv = bias[col];
        #pragma unroll
        for (int j = 0; j < 4; ++j)
            outp[(size_t)(rowbase + chunk * 4 + j) * 128 + col] = pack_bf1(acc[j] + bv);
    }
}

// ---------------------------------------------------------------------------
// CSR build
// ---------------------------------------------------------------------------
__global__ void hist_both(const int* __restrict__ src, const int* __restrict__ dst,
                          int* __restrict__ cntU, int* __restrict__ cntI, int E)
{
    for (int i = blockIdx.x * blockDim.x + threadIdx.x; i < E;
         i += gridDim.x * blockDim.x) {
        atomicAdd(&cntU[src[i]], 1);
        atomicAdd(&cntI[dst[i]], 1);
    }
}

__global__ void scan_blocks(const int* __restrict__ in, int* __restrict__ out,
                            int* __restrict__ blockSums, int n)
{
    __shared__ int lds[256];
    const int tid = threadIdx.x;
    const int base = blockIdx.x * 1024 + tid * 4;
    int v[4];
    #pragma unroll
    for (int j = 0; j < 4; ++j) { int idx = base + j; v[j] = (idx < n) ? in[idx] : 0; }
    int t = v[0] + v[1] + v[2] + v[3];
    lds[tid] = t;
    __syncthreads();
    for (int off = 1; off < 256; off <<= 1) {
        int x = (tid >= off) ? lds[tid - off] : 0;
        __syncthreads();
        lds[tid] += x;
        __syncthreads();
    }
    int excl = lds[tid] - t;
    if (tid == 255 && blockSums) blockSums[blockIdx.x] = lds[255];
    int run = excl;
    #pragma unroll
    for (int j = 0; j < 4; ++j) {
        int idx = base + j;
        if (idx < n) out[idx] = run;
        run += v[j];
    }
}

__global__ void scan_add(int* __restrict__ out, const int* __restrict__ bss, int n)
{
    const int add = bss[blockIdx.x];
    const int base = blockIdx.x * 1024 + threadIdx.x * 4;
    #pragma unroll
    for (int j = 0; j < 4; ++j) { int idx = base + j; if (idx < n) out[idx] += add; }
}

__global__ void scatter_both(const int* __restrict__ src, const int* __restrict__ dst,
                             const float* __restrict__ eattr,
                             int* __restrict__ offU, int* __restrict__ offI,
                             int* __restrict__ sFund, uint4* __restrict__ sE1, int E)
{
    for (int i = blockIdx.x * blockDim.x + threadIdx.x; i < E;
         i += gridDim.x * blockDim.x) {
        const int s = src[i];
        const int d = dst[i];
        const float a0 = eattr[3 * (size_t)i];
        const float a1 = eattr[3 * (size_t)i + 1];
        const float a2 = eattr[3 * (size_t)i + 2];
        const int p1 = atomicAdd(&offI[d], 1);
        sE1[p1] = make_uint4((unsigned int)s, __float_as_uint(a0),
                             __float_as_uint(a1), __float_as_uint(a2));
        const int p2 = atomicAdd(&offU[s], 1);
        sFund[p2] = d;
    }
}

// ---------------------------------------------------------------------------
// conv1 fused: one wave per fund d; xl bf16-packed; 4-way unrolled gathers.
// ---------------------------------------------------------------------------
__device__ __forceinline__ void conv1_edge(uint4 e, unsigned int vbits, float2 vr,
                                           float2 av, float2 w0, float2 w1, float2 w2,
                                           float& acc0, float& acc1, float& s)
{
    const float2 vl = unpack_bf2(vbits);
    const float e0 = __uint_as_float(e.y);
    const float e1 = __uint_as_float(e.z);
    const float e2 = __uint_as_float(e.w);
    float h0 = vl.x + vr.x + e0 * w0.x + e1 * w1.x + e2 * w2.x;
    float h1 = vl.y + vr.y + e0 * w0.y + e1 * w1.y + e2 * w2.y;
    h0 = h0 > 0.f ? h0 : 0.2f * h0;
    h1 = h1 > 0.f ? h1 : 0.2f * h1;
    const float p = head_reduce(h0 * av.x + h1 * av.y);
    const float ex = __expf(p);
    acc0 = fmaf(ex, vl.x, acc0);
    acc1 = fmaf(ex, vl.y, acc1);
    s += ex;
}

__global__ void conv1_fused(const unsigned int* __restrict__ xl,
                            const float* __restrict__ xr,
                            const int* __restrict__ off_end, const int* __restrict__ cnt,
                            const uint4* __restrict__ sE,
                            const float* __restrict__ We, const float* __restrict__ att,
                            const float* __restrict__ bias,
                            float* __restrict__ outF, int ndst)
{
    const int tid = threadIdx.x;
    const int lane = tid & 63;
    const int wid = tid >> 6;
    const int d = blockIdx.x * 4 + wid;
    if (d >= ndst) return;

    const int ch = lane * 2;
    const float2 av = *(const float2*)(att + ch);
    const float2 w0 = *(const float2*)(We + ch);
    const float2 w1 = *(const float2*)(We + HC + ch);
    const float2 w2 = *(const float2*)(We + 2 * HC + ch);
    const float2 bv = *(const float2*)(bias + ch);
    const float2 vr = *(const float2*)(xr + (size_t)d * HC + ch);

    const int end = off_end[d];
    const int start = end - cnt[d];

    float acc0 = 0.f, acc1 = 0.f, s = 0.f;
    int pos = start;
    for (; pos + 4 <= end; pos += 4) {
        const uint4 ea = sE[pos], eb = sE[pos + 1], ec = sE[pos + 2], ed = sE[pos + 3];
        const unsigned int va = xl[(size_t)ea.x * 64 + lane];
        const unsigned int vb = xl[(size_t)eb.x * 64 + lane];
        const unsigned int vc = xl[(size_t)ec.x * 64 + lane];
        const unsigned int vd = xl[(size_t)ed.x * 64 + lane];
        conv1_edge(ea, va, vr, av, w0, w1, w2, acc0, acc1, s);
        conv1_edge(eb, vb, vr, av, w0, w1, w2, acc0, acc1, s);
        conv1_edge(ec, vc, vr, av, w0, w1, w2, acc0, acc1, s);
        conv1_edge(ed, vd, vr, av, w0, w1, w2, acc0, acc1, s);
    }
    for (; pos < end; ++pos) {
        const uint4 e = sE[pos];
        const unsigned int v = xl[(size_t)e.x * 64 + lane];
        conv1_edge(e, v, vr, av, w0, w1, w2, acc0, acc1, s);
    }
    const float inv = 1.f / (s + 1e-16f);
    const float o0 = fmaxf(acc0 * inv + bv.x, 0.f);
    const float o1 = fmaxf(acc1 * inv + bv.y, 0.f);
    *(float2*)(outF + (size_t)d * HC + ch) = make_float2(o0, o1);
}

// ---------------------------------------------------------------------------
// conv2 + classifier fused: one wave per 16 users.
//  Per user: edge softmax-aggregate -> x row (bf16) in wave-private LDS slab.
//  Then MLP via MFMA: hid = relu(x@W1+b1); out = sigmoid(hid@W2+b2).
// LDS row pitch 136 halfwords (272B -> 4-bank rotation per row, 2-way free).
// ---------------------------------------------------------------------------
__device__ __forceinline__ void conv2_edge(unsigned int vbits, float2 vr, float2 av,
                                           float& acc0, float& acc1, float& s)
{
    const float2 vl = unpack_bf2(vbits);
    float h0 = vl.x + vr.x;
    float h1 = vl.y + vr.y;
    h0 = h0 > 0.f ? h0 : 0.2f * h0;
    h1 = h1 > 0.f ? h1 : 0.2f * h1;
    const float p = head_reduce(h0 * av.x + h1 * av.y);
    const float ex = __expf(p);
    acc0 = fmaf(ex, vl.x, acc0);
    acc1 = fmaf(ex, vl.y, acc1);
    s += ex;
}

__global__ __launch_bounds__(256)
void conv2_cls(const unsigned int* __restrict__ xl2,
               const unsigned int* __restrict__ xr2,
               const int* __restrict__ off_end, const int* __restrict__ cnt,
               const int* __restrict__ sFund,
               const float* __restrict__ att, const float* __restrict__ cbias,
               const unsigned short* __restrict__ Bp1,
               const float* __restrict__ b1, const float* __restrict__ W2,
               const float* __restrict__ b2,
               float* __restrict__ out, int nusr)
{
    __shared__ unsigned short xs[4][16][136];

    const int lane = threadIdx.x & 63;
    const int wid = threadIdx.x >> 6;
    const int wt = (blockIdx.x * blockDim.x + threadIdx.x) >> 6;
    const int u0 = wt * 16;
    if (u0 >= nusr) return;

    const int ch = lane * 2;
    const float2 av = *(const float2*)(att + ch);
    const float2 bv = *(const float2*)(cbias + ch);

    // --- phase 1: 16 users' softmax-aggregated features into LDS ---
    for (int i = 0; i < 16; ++i) {
        const int u = u0 + i;
        const float2 vr = unpack_bf2(xr2[(size_t)u * 64 + lane]);
        const int end = off_end[u];
        const int start = end - cnt[u];
        float acc0 = 0.f, acc1 = 0.f, s = 0.f;
        int pos = start;
        for (; pos + 2 <= end; pos += 2) {
            const int fa = sFund[pos];
            const int fb = sFund[pos + 1];
            const unsigned int va = xl2[(size_t)fa * 64 + lane];
            const unsigned int vb = xl2[(size_t)fb * 64 + lane];
            conv2_edge(va, vr, av, acc0, acc1, s);
            conv2_edge(vb, vr, av, acc0, acc1, s);
        }
        if (pos < end) {
            const unsigned int v = xl2[(size_t)sFund[pos] * 64 + lane];
            conv2_edge(v, vr, av, acc0, acc1, s);
        }
        const float inv = 1.f / (s + 1e-16f);
        *(unsigned int*)&xs[wid][i][ch] = pack_bf2(acc0 * inv + bv.x,
                                                   acc1 * inv + bv.y);
    }

    // --- phase 2: MLP via MFMA (A = 16 user rows, K=128) ---
    const int row = lane & 15;
    const int chunk = lane >> 4;
    bf16x8 a[4];
    #pragma unroll
    for (int ks = 0; ks < 4; ++ks)
        a[ks] = *(const bf16x8*)&xs[wid][row][ks * 32 + chunk * 8];

    const bf16x8* bfr = (const bf16x8*)Bp1;
    float racc[4] = {0.f, 0.f, 0.f, 0.f};
    #pragma unroll
    for (int g = 0; g < 4; ++g) {
        f32x4 acc = {0.f, 0.f, 0.f, 0.f};
        const int fi = g * 4;
        acc = __builtin_amdgcn_mfma_f32_16x16x32_bf16(a[0], bfr[(fi + 0) * 64 + lane], acc, 0, 0, 0);
        acc = __builtin_amdgcn_mfma_f32_16x16x32_bf16(a[1], bfr[(fi + 1) * 64 + lane], acc, 0, 0, 0);
        acc = __builtin_amdgcn_mfma_f32_16x16x32_bf16(a[2], bfr[(fi + 2) * 64 + lane], acc, 0, 0, 0);
        acc = __builtin_amdgcn_mfma_f32_16x16x32_bf16(a[3], bfr[(fi + 3) * 64 + lane], acc, 0, 0, 0);
        const int col = g * 16 + row;
        const float b1v = b1[col];
        const float w2v = W2[col];
        #pragma unroll
        for (int j = 0; j < 4; ++j)
            racc[j] = fmaf(fmaxf(acc[j] + b1v, 0.f), w2v, racc[j]);
    }
    #pragma unroll
    for (int j = 0; j < 4; ++j) {
        racc[j] += __shfl_xor(racc[j], 1, 16);
        racc[j] += __shfl_xor(racc[j], 2, 16);
        racc[j] += __shfl_xor(racc[j], 4, 16);
        racc[j] += __shfl_xor(racc[j], 8, 16);
    }
    if (row == 0) {
        const float b2v = b2[0];
        #pragma unroll
        for (int j = 0; j < 4; ++j) {
            const int r = u0 + chunk * 4 + j;
            if (r < nusr) out[r] = 1.f / (1.f + expf(-(racc[j] + b2v)));
        }
    }
}

// ---------------------------------------------------------------------------
extern "C" void kernel_launch(void* const* d_in, const int* in_sizes, int n_in,
                              void* d_out, int out_size, void* d_ws, size_t ws_size,
                              hipStream_t stream)
{
    const float* customer_x = (const float*)d_in[0];
    const float* fund_x     = (const float*)d_in[1];
    const float* edge_attr  = (const float*)d_in[2];
    const int*   edge_src   = (const int*)d_in[3];
    const int*   edge_dst   = (const int*)d_in[4];
    const float* user_W = (const float*)d_in[5];
    const float* user_b = (const float*)d_in[6];
    const float* item_W = (const float*)d_in[7];
    const float* item_b = (const float*)d_in[8];
    const float* c1_Wl  = (const float*)d_in[9];
    const float* c1_bl  = (const float*)d_in[10];
    const float* c1_Wr  = (const float*)d_in[11];
    const float* c1_br  = (const float*)d_in[12];
    const float* c1_We  = (const float*)d_in[13];
    const float* c1_att = (const float*)d_in[14];
    const float* c1_bias= (const float*)d_in[15];
    const float* c2_Wl  = (const float*)d_in[16];
    const float* c2_bl  = (const float*)d_in[17];
    const float* c2_Wr  = (const float*)d_in[18];
    const float* c2_br  = (const float*)d_in[19];
    const float* c2_att = (const float*)d_in[20];
    const float* c2_bias= (const float*)d_in[21];
    const float* cls_W1 = (const float*)d_in[22];
    const float* cls_b1 = (const float*)d_in[23];
    const float* cls_W2 = (const float*)d_in[24];
    const float* cls_b2 = (const float*)d_in[25];
    float* out = (float*)d_out;

    float* ws = (float*)d_ws;
    size_t off = 0;
    unsigned short* B1 = (unsigned short*)(ws + off); off += (size_t)NU * 64; // xl1 bf16
    unsigned short* B2 = (unsigned short*)(ws + off); off += (size_t)NU * 64; // xr2 bf16
    float* C = ws + off; off += (size_t)NI * HC;                              // xr1 fp32
    float* F = ws + off; off += (size_t)NI * HC;                              // item_h fp32
    unsigned short* G = (unsigned short*)(ws + off); off += (size_t)NI * 64;  // xl2 bf16
    int* cnt1  = (int*)(ws + off); off += NI;
    int* off1  = (int*)(ws + off); off += NI;
    int* cnt2  = (int*)(ws + off); off += NU;
    int* off2  = (int*)(ws + off); off += NU;
    int* bs    = (int*)(ws + off); off += 1024;
    int* bss   = (int*)(ws + off); off += 1024;
    uint4* sE1 = (uint4*)(ws + off); off += (size_t)NE * 4;
    int* sFund = (int*)(ws + off); off += NE;
    unsigned short* Bp = (unsigned short*)(ws + off); off += 12288 + 256;     // 96KB frags
    unsigned short* Bp1 = (unsigned short*)(ws + off); off += 4096 + 256;     // 16KB W1 frags
    float* wvbb = ws + off; off += 256;

    hipMemsetAsync(cnt1, 0, NI * sizeof(int), stream);
    hipMemsetAsync(cnt2, 0, NU * sizeof(int), stream);

    // CSR build
    hist_both<<<1024, 256, 0, stream>>>(edge_src, edge_dst, cnt2, cnt1, NE);
    const int nb1 = (NI + 1023) / 1024;
    const int nb2 = (NU + 1023) / 1024;
    scan_blocks<<<nb1, 256, 0, stream>>>(cnt1, off1, bs, NI);
    scan_blocks<<<1,   256, 0, stream>>>(bs, bss, nullptr, nb1);
    scan_add<<<nb1, 256, 0, stream>>>(off1, bss, NI);
    scan_blocks<<<nb2, 256, 0, stream>>>(cnt2, off2, bs, NU);
    scan_blocks<<<1,   256, 0, stream>>>(bs, bss, nullptr, nb2);
    scan_add<<<nb2, 256, 0, stream>>>(off2, bss, NU);
    scatter_both<<<1024, 256, 0, stream>>>(edge_src, edge_dst, edge_attr,
                                           off2, off1, sFund, sE1, NE);

    // weight prep
    wprep<<<192, 256, 0, stream>>>(user_W, user_b, c1_Wl, c1_bl,
                                   c2_Wr, c2_br, c2_Wl, Bp);
    w1prep<<<32, 256, 0, stream>>>(cls_W1, Bp1);
    wvbb_prep<<<1, 128, 0, stream>>>(item_W, item_b, c1_Wr, c1_br, wvbb);

    // xr1 = fund_x (rank-1) : [NI,128] fp32
    xr1_outer<<<2048, 256, 0, stream>>>(fund_x, wvbb, C, NI * HC);

    // xl1 & xr2 in one MFMA pass over customer_x
    mfma_user<<<(NU / 16 + 3) / 4, 256, 0, stream>>>(customer_x, Bp, B1, B2, NU);

    // conv1: customer -> fund (+bias+relu), fp32 out F
    conv1_fused<<<NI / 4, 256, 0, stream>>>((const unsigned int*)B1, C, off1, cnt1, sE1,
                                            c1_We, c1_att, c1_bias, F, NI);

    // xl2 = item_h @ c2_Wl + c2_bl (bf16)
    mfma_xl2<<<(NI / 16 + 3) / 4, 256, 0, stream>>>(F, Bp, c2_bl, G, NI);

    // conv2 + classifier fused: one wave per 16 users
    const int waves2 = (NU + 15) / 16;             // 31250
    conv2_cls<<<(waves2 + 3) / 4, 256, 0, stream>>>(
        (const unsigned int*)G, (const unsigned int*)B2, off2, cnt2, sFund,
        c2_att, c2_bias, Bp1, cls_b1, cls_W2, cls_b2, out, NU);
}

// Round 9
// 663.610 us; speedup vs baseline: 6.3009x; 1.1187x over previous
//
#include <hip/hip_runtime.h>
#include <cstdint>
#include <cstddef>

#define NU 500000
#define NI 50000
#define NE 1000000
#define HC 128   // H*C
#define NH 4

typedef __attribute__((ext_vector_type(8))) short bf16x8;
typedef __attribute__((ext_vector_type(4))) float f32x4;

union frag_u { bf16x8 v; unsigned int u[4]; };

// bf16 pack/unpack (RNE)
__device__ __forceinline__ unsigned int pack_bf2(float x, float y) {
    unsigned int xb = __float_as_uint(x);
    unsigned int yb = __float_as_uint(y);
    xb += 0x7fffu + ((xb >> 16) & 1u);
    yb += 0x7fffu + ((yb >> 16) & 1u);
    return (xb >> 16) | (yb & 0xffff0000u);
}
__device__ __forceinline__ float2 unpack_bf2(unsigned int v) {
    return make_float2(__uint_as_float(v << 16),
                       __uint_as_float(v & 0xffff0000u));
}
__device__ __forceinline__ unsigned short pack_bf1(float x) {
    unsigned int b = __float_as_uint(x);
    b += 0x7fffu + ((b >> 16) & 1u);
    return (unsigned short)(b >> 16);
}

__device__ __forceinline__ float head_reduce(float p) {
    p += __shfl_xor(p, 8, 16);
    p += __shfl_xor(p, 4, 16);
    p += __shfl_xor(p, 2, 16);
    p += __shfl_xor(p, 1, 16);
    return p;
}

// ---------------------------------------------------------------------------
// Weight prep: Bp holds 3 matrices in MFMA B-fragment order, bf16.
// ---------------------------------------------------------------------------
__global__ void wprep(const float* __restrict__ user_W, const float* __restrict__ user_b,
                      const float* __restrict__ c1_Wl, const float* __restrict__ c1_bl,
                      const float* __restrict__ c2_Wr, const float* __restrict__ c2_br,
                      const float* __restrict__ c2_Wl, unsigned short* __restrict__ Bp)
{
    const int t = blockIdx.x * 256 + threadIdx.x;   // 0..49151
    const int mat = t >> 14;
    const int k = (t >> 7) & 127;
    const int n = t & 127;
    float val = 0.f;
    if (mat == 2) {
        val = c2_Wl[k * 128 + n];
    } else {
        const float* W2 = mat ? c2_Wr : c1_Wl;
        if (k < 101) {
            for (int q = 0; q < 32; ++q) val = fmaf(user_W[k * 32 + q], W2[q * 128 + n], val);
        } else if (k == 101) {
            for (int q = 0; q < 32; ++q) val = fmaf(user_b[q], W2[q * 128 + n], val);
            val += (mat ? c2_br : c1_bl)[n];
        }
    }
    const int fi = (mat * 8 + (n >> 4)) * 4 + (k >> 5);
    const int lane_ = (n & 15) + ((k >> 3) & 3) * 16;
    Bp[(size_t)fi * 512 + lane_ * 8 + (k & 7)] = pack_bf1(val);
}

// ---------------------------------------------------------------------------
// W1 (classifier, 128x64) -> B-fragment order, 16 frags
// ---------------------------------------------------------------------------
__global__ void w1prep(const float* __restrict__ W1, unsigned short* __restrict__ Bp1)
{
    const int t = blockIdx.x * 256 + threadIdx.x;   // 0..8191
    const int k = t >> 6;
    const int n = t & 63;
    const float val = W1[k * 64 + n];
    const int fi = (n >> 4) * 4 + (k >> 5);
    const int lane_ = (n & 15) + ((k >> 3) & 3) * 16;
    Bp1[(size_t)fi * 512 + lane_ * 8 + (k & 7)] = pack_bf1(val);
}

// ---------------------------------------------------------------------------
// xr1 rank-1 weights
// ---------------------------------------------------------------------------
__global__ void wvbb_prep(const float* __restrict__ item_W, const float* __restrict__ item_b,
                          const float* __restrict__ c1_Wr, const float* __restrict__ c1_br,
                          float* __restrict__ wvbb)
{
    const int j = threadIdx.x;
    if (j >= 128) return;
    float wv = 0.f, bb = 0.f;
    for (int q = 0; q < 32; ++q) {
        wv = fmaf(item_W[q], c1_Wr[q * 128 + j], wv);
        bb = fmaf(item_b[q], c1_Wr[q * 128 + j], bb);
    }
    wvbb[j] = wv;
    wvbb[128 + j] = bb + c1_br[j];
}

__global__ void xr1_outer(const float* __restrict__ fund_x, const float* __restrict__ wvbb,
                          float* __restrict__ C, int n)
{
    for (int i = blockIdx.x * blockDim.x + threadIdx.x; i < n;
         i += gridDim.x * blockDim.x) {
        const int row = i >> 7, j = i & 127;
        C[i] = fmaf(fund_x[row], wvbb[j], wvbb[128 + j]);
    }
}

// ---------------------------------------------------------------------------
// MFMA: [NU,101(+bias)] fp32 @ Wc{1,2} -> xl1, xr2 (bf16)
// ---------------------------------------------------------------------------
__global__ __launch_bounds__(256)
void mfma_user(const float* __restrict__ cx, const unsigned short* __restrict__ Bp,
               unsigned short* __restrict__ outL, unsigned short* __restrict__ outR, int M)
{
    const int lane = threadIdx.x & 63;
    const int wt = (blockIdx.x * blockDim.x + threadIdx.x) >> 6;
    const int rowbase = wt * 16;
    if (rowbase >= M) return;
    const int chunk = lane >> 4;
    const float* rowp = cx + (size_t)(rowbase + (lane & 15)) * 101;

    frag_u a[4];
    #pragma unroll
    for (int ks = 0; ks < 3; ++ks) {
        const int kb = ks * 32 + chunk * 8;
        const float v0 = rowp[kb + 0], v1 = rowp[kb + 1];
        const float v2 = rowp[kb + 2], v3 = rowp[kb + 3];
        const float v4 = rowp[kb + 4], v5 = rowp[kb + 5];
        const float v6 = rowp[kb + 6], v7 = rowp[kb + 7];
        a[ks].u[0] = pack_bf2(v0, v1);
        a[ks].u[1] = pack_bf2(v2, v3);
        a[ks].u[2] = pack_bf2(v4, v5);
        a[ks].u[3] = pack_bf2(v6, v7);
    }
    {
        float v0 = 0.f, v1 = 0.f, v2 = 0.f, v3 = 0.f, v4 = 0.f, v5 = 0.f;
        if (chunk == 0) {
            v0 = rowp[96]; v1 = rowp[97]; v2 = rowp[98]; v3 = rowp[99]; v4 = rowp[100];
            v5 = 1.0f;
        }
        a[3].u[0] = pack_bf2(v0, v1);
        a[3].u[1] = pack_bf2(v2, v3);
        a[3].u[2] = pack_bf2(v4, v5);
        a[3].u[3] = 0u;
    }

    const bf16x8* bfr = (const bf16x8*)Bp;
    #pragma unroll
    for (int mat = 0; mat < 2; ++mat) {
        unsigned short* outp = mat ? outR : outL;
        #pragma unroll
        for (int nf = 0; nf < 8; ++nf) {
            f32x4 acc = {0.f, 0.f, 0.f, 0.f};
            const int fi = (mat * 8 + nf) * 4;
            acc = __builtin_amdgcn_mfma_f32_16x16x32_bf16(a[0].v, bfr[(fi + 0) * 64 + lane], acc, 0, 0, 0);
            acc = __builtin_amdgcn_mfma_f32_16x16x32_bf16(a[1].v, bfr[(fi + 1) * 64 + lane], acc, 0, 0, 0);
            acc = __builtin_amdgcn_mfma_f32_16x16x32_bf16(a[2].v, bfr[(fi + 2) * 64 + lane], acc, 0, 0, 0);
            acc = __builtin_amdgcn_mfma_f32_16x16x32_bf16(a[3].v, bfr[(fi + 3) * 64 + lane], acc, 0, 0, 0);
            const int col = nf * 16 + (lane & 15);
            #pragma unroll
            for (int j = 0; j < 4; ++j)
                outp[(size_t)(rowbase + chunk * 4 + j) * 128 + col] = pack_bf1(acc[j]);
        }
    }
}

// ---------------------------------------------------------------------------
// MFMA: xl2 = item_h[NI,128] @ c2_Wl + c2_bl -> bf16
// ---------------------------------------------------------------------------
__global__ __launch_bounds__(256)
void mfma_xl2(const float* __restrict__ X, const unsigned short* __restrict__ Bp,
              const float* __restrict__ bias, unsigned short* __restrict__ outp, int M)
{
    const int lane = threadIdx.x & 63;
    const int wt = (blockIdx.x * blockDim.x + threadIdx.x) >> 6;
    const int rowbase = wt * 16;
    if (rowbase >= M) return;
    const int chunk = lane >> 4;
    const float* rowp = X + (size_t)(rowbase + (lane & 15)) * 128;

    frag_u a[4];
    #pragma unroll
    for (int ks = 0; ks < 4; ++ks) {
        const int kb = ks * 32 + chunk * 8;
        const float4 p = *(const float4*)(rowp + kb);
        const float4 q = *(const float4*)(rowp + kb + 4);
        a[ks].u[0] = pack_bf2(p.x, p.y);
        a[ks].u[1] = pack_bf2(p.z, p.w);
        a[ks].u[2] = pack_bf2(q.x, q.y);
        a[ks].u[3] = pack_bf2(q.z, q.w);
    }

    const bf16x8* bfr = (const bf16x8*)Bp;
    #pragma unroll
    for (int nf = 0; nf < 8; ++nf) {
        f32x4 acc = {0.f, 0.f, 0.f, 0.f};
        const int fi = (16 + nf) * 4;   // mat 2
        acc = __builtin_amdgcn_mfma_f32_16x16x32_bf16(a[0].v, bfr[(fi + 0) * 64 + lane], acc, 0, 0, 0);
        acc = __builtin_amdgcn_mfma_f32_16x16x32_bf16(a[1].v, bfr[(fi + 1) * 64 + lane], acc, 0, 0, 0);
        acc = __builtin_amdgcn_mfma_f32_16x16x32_bf16(a[2].v, bfr[(fi + 2) * 64 + lane], acc, 0, 0, 0);
        acc = __builtin_amdgcn_mfma_f32_16x16x32_bf16(a[3].v, bfr[(fi + 3) * 64 + lane], acc, 0, 0, 0);
        const int col = nf * 16 + (lane & 15);
        const float bv = bias[col];
        #pragma unroll
        for (int j = 0; j < 4; ++j)
            outp[(size_t)(rowbase + chunk * 4 + j) * 128 + col] = pack_bf1(acc[j] + bv);
    }
}

// ---------------------------------------------------------------------------
// CSR build
// ---------------------------------------------------------------------------
__global__ void hist_both(const int* __restrict__ src, const int* __restrict__ dst,
                          int* __restrict__ cntU, int* __restrict__ cntI, int E)
{
    for (int i = blockIdx.x * blockDim.x + threadIdx.x; i < E;
         i += gridDim.x * blockDim.x) {
        atomicAdd(&cntU[src[i]], 1);
        atomicAdd(&cntI[dst[i]], 1);
    }
}

__global__ void scan_blocks(const int* __restrict__ in, int* __restrict__ out,
                            int* __restrict__ blockSums, int n)
{
    __shared__ int lds[256];
    const int tid = threadIdx.x;
    const int base = blockIdx.x * 1024 + tid * 4;
    int v[4];
    #pragma unroll
    for (int j = 0; j < 4; ++j) { int idx = base + j; v[j] = (idx < n) ? in[idx] : 0; }
    int t = v[0] + v[1] + v[2] + v[3];
    lds[tid] = t;
    __syncthreads();
    for (int off = 1; off < 256; off <<= 1) {
        int x = (tid >= off) ? lds[tid - off] : 0;
        __syncthreads();
        lds[tid] += x;
        __syncthreads();
    }
    int excl = lds[tid] - t;
    if (tid == 255 && blockSums) blockSums[blockIdx.x] = lds[255];
    int run = excl;
    #pragma unroll
    for (int j = 0; j < 4; ++j) {
        int idx = base + j;
        if (idx < n) out[idx] = run;
        run += v[j];
    }
}

__global__ void scan_add(int* __restrict__ out, const int* __restrict__ bss, int n)
{
    const int add = bss[blockIdx.x];
    const int base = blockIdx.x * 1024 + threadIdx.x * 4;
    #pragma unroll
    for (int j = 0; j < 4; ++j) { int idx = base + j; if (idx < n) out[idx] += add; }
}

__global__ void scatter_both(const int* __restrict__ src, const int* __restrict__ dst,
                             const float* __restrict__ eattr,
                             int* __restrict__ offU, int* __restrict__ offI,
                             int* __restrict__ sFund, uint4* __restrict__ sE1, int E)
{
    for (int i = blockIdx.x * blockDim.x + threadIdx.x; i < E;
         i += gridDim.x * blockDim.x) {
        const int s = src[i];
        const int d = dst[i];
        const float a0 = eattr[3 * (size_t)i];
        const float a1 = eattr[3 * (size_t)i + 1];
        const float a2 = eattr[3 * (size_t)i + 2];
        const int p1 = atomicAdd(&offI[d], 1);
        sE1[p1] = make_uint4((unsigned int)s, __float_as_uint(a0),
                             __float_as_uint(a1), __float_as_uint(a2));
        const int p2 = atomicAdd(&offU[s], 1);
        sFund[p2] = d;
    }
}

// ---------------------------------------------------------------------------
// conv1 fused: one wave per fund d; 8-deep gather pipeline.
// ---------------------------------------------------------------------------
__device__ __forceinline__ void conv1_edge(uint4 e, unsigned int vbits, float2 vr,
                                           float2 av, float2 w0, float2 w1, float2 w2,
                                           float& acc0, float& acc1, float& s)
{
    const float2 vl = unpack_bf2(vbits);
    const float e0 = __uint_as_float(e.y);
    const float e1 = __uint_as_float(e.z);
    const float e2 = __uint_as_float(e.w);
    float h0 = vl.x + vr.x + e0 * w0.x + e1 * w1.x + e2 * w2.x;
    float h1 = vl.y + vr.y + e0 * w0.y + e1 * w1.y + e2 * w2.y;
    h0 = h0 > 0.f ? h0 : 0.2f * h0;
    h1 = h1 > 0.f ? h1 : 0.2f * h1;
    const float p = head_reduce(h0 * av.x + h1 * av.y);
    const float ex = __expf(p);
    acc0 = fmaf(ex, vl.x, acc0);
    acc1 = fmaf(ex, vl.y, acc1);
    s += ex;
}

__global__ void conv1_fused(const unsigned int* __restrict__ xl,
                            const float* __restrict__ xr,
                            const int* __restrict__ off_end, const int* __restrict__ cnt,
                            const uint4* __restrict__ sE,
                            const float* __restrict__ We, const float* __restrict__ att,
                            const float* __restrict__ bias,
                            float* __restrict__ outF, int ndst)
{
    const int tid = threadIdx.x;
    const int lane = tid & 63;
    const int wid = tid >> 6;
    const int d = blockIdx.x * 4 + wid;
    if (d >= ndst) return;

    const int ch = lane * 2;
    const float2 av = *(const float2*)(att + ch);
    const float2 w0 = *(const float2*)(We + ch);
    const float2 w1 = *(const float2*)(We + HC + ch);
    const float2 w2 = *(const float2*)(We + 2 * HC + ch);
    const float2 bv = *(const float2*)(bias + ch);
    const float2 vr = *(const float2*)(xr + (size_t)d * HC + ch);

    const int end = off_end[d];
    const int start = end - cnt[d];

    float acc0 = 0.f, acc1 = 0.f, s = 0.f;
    int pos = start;
    for (; pos + 8 <= end; pos += 8) {
        uint4 e[8];
        unsigned int v[8];
        #pragma unroll
        for (int j = 0; j < 8; ++j) e[j] = sE[pos + j];
        #pragma unroll
        for (int j = 0; j < 8; ++j) v[j] = xl[(size_t)e[j].x * 64 + lane];
        #pragma unroll
        for (int j = 0; j < 8; ++j)
            conv1_edge(e[j], v[j], vr, av, w0, w1, w2, acc0, acc1, s);
    }
    for (; pos + 4 <= end; pos += 4) {
        uint4 e[4];
        unsigned int v[4];
        #pragma unroll
        for (int j = 0; j < 4; ++j) e[j] = sE[pos + j];
        #pragma unroll
        for (int j = 0; j < 4; ++j) v[j] = xl[(size_t)e[j].x * 64 + lane];
        #pragma unroll
        for (int j = 0; j < 4; ++j)
            conv1_edge(e[j], v[j], vr, av, w0, w1, w2, acc0, acc1, s);
    }
    for (; pos < end; ++pos) {
        const uint4 e = sE[pos];
        const unsigned int v = xl[(size_t)e.x * 64 + lane];
        conv1_edge(e, v, vr, av, w0, w1, w2, acc0, acc1, s);
    }
    const float inv = 1.f / (s + 1e-16f);
    const float o0 = fmaxf(acc0 * inv + bv.x, 0.f);
    const float o1 = fmaxf(acc1 * inv + bv.y, 0.f);
    *(float2*)(outF + (size_t)d * HC + ch) = make_float2(o0, o1);
}

// ---------------------------------------------------------------------------
// conv2 + classifier fused: one wave per 16 users, FLATTENED edge stream.
// Consecutive users' CSR buckets are contiguous -> one range [S,E) with
// wave-uniform boundary events; 4-deep cross-user gather pipeline.
// ---------------------------------------------------------------------------
__device__ __forceinline__ void conv2_edge(unsigned int vbits, float2 vr, float2 av,
                                           float& acc0, float& acc1, float& s)
{
    const float2 vl = unpack_bf2(vbits);
    float h0 = vl.x + vr.x;
    float h1 = vl.y + vr.y;
    h0 = h0 > 0.f ? h0 : 0.2f * h0;
    h1 = h1 > 0.f ? h1 : 0.2f * h1;
    const float p = head_reduce(h0 * av.x + h1 * av.y);
    const float ex = __expf(p);
    acc0 = fmaf(ex, vl.x, acc0);
    acc1 = fmaf(ex, vl.y, acc1);
    s += ex;
}

__global__ __launch_bounds__(256)
void conv2_cls(const unsigned int* __restrict__ xl2,
               const unsigned int* __restrict__ xr2,
               const int* __restrict__ off_end, const int* __restrict__ cnt,
               const int* __restrict__ sFund,
               const float* __restrict__ att, const float* __restrict__ cbias,
               const unsigned short* __restrict__ Bp1,
               const float* __restrict__ b1, const float* __restrict__ W2,
               const float* __restrict__ b2,
               float* __restrict__ out, int nusr)
{
    __shared__ unsigned short xs[4][16][136];

    const int lane = threadIdx.x & 63;
    const int wid = threadIdx.x >> 6;
    const int wt = (blockIdx.x * blockDim.x + threadIdx.x) >> 6;
    const int u0 = wt * 16;
    if (u0 >= nusr) return;

    const int ch = lane * 2;
    const float2 av = *(const float2*)(att + ch);
    const float2 bv = *(const float2*)(cbias + ch);

    // lane-parallel offsets for this wave's 16 users (NU % 16 == 0)
    int eo = 0, ctv = 0;
    if (lane < 16) {
        eo = off_end[u0 + lane];
        ctv = cnt[u0 + lane];
    }
    const int S = __builtin_amdgcn_readlane(eo, 0) - __builtin_amdgcn_readlane(ctv, 0);
    const int E = __builtin_amdgcn_readlane(eo, 15);

    int u = 0;
    int end_u = __builtin_amdgcn_readlane(eo, 0);
    unsigned int vrb_next = xr2[(size_t)(u0 + 1) * 64 + lane];   // prefetch user 1
    float2 vr = unpack_bf2(xr2[(size_t)u0 * 64 + lane]);          // user 0
    float acc0 = 0.f, acc1 = 0.f, s = 0.f;

    #define FINALIZE() {                                                        \
        const float inv = 1.f / (s + 1e-16f);                                   \
        *(unsigned int*)&xs[wid][u][ch] = pack_bf2(acc0 * inv + bv.x,           \
                                                   acc1 * inv + bv.y);          \
        acc0 = acc1 = s = 0.f;                                                  \
        ++u;                                                                    \
        if (u < 16) {                                                           \
            end_u = __builtin_amdgcn_readlane(eo, u);                           \
            vr = unpack_bf2(vrb_next);                                          \
            if (u + 1 < 16) vrb_next = xr2[(size_t)(u0 + u + 1) * 64 + lane];   \
        }                                                                       \
    }

    int pos = S;
    while (pos < E) {
        const int f0 = sFund[pos];
        const int f1 = (pos + 1 < E) ? sFund[pos + 1] : f0;
        const int f2 = (pos + 2 < E) ? sFund[pos + 2] : f0;
        const int f3 = (pos + 3 < E) ? sFund[pos + 3] : f0;
        const unsigned int v0 = xl2[(size_t)f0 * 64 + lane];
        const unsigned int v1 = xl2[(size_t)f1 * 64 + lane];
        const unsigned int v2 = xl2[(size_t)f2 * 64 + lane];
        const unsigned int v3 = xl2[(size_t)f3 * 64 + lane];

        while (pos == end_u) FINALIZE();
        conv2_edge(v0, vr, av, acc0, acc1, s);
        if (pos + 1 < E) {
            while (pos + 1 == end_u) FINALIZE();
            conv2_edge(v1, vr, av, acc0, acc1, s);
        }
        if (pos + 2 < E) {
            while (pos + 2 == end_u) FINALIZE();
            conv2_edge(v2, vr, av, acc0, acc1, s);
        }
        if (pos + 3 < E) {
            while (pos + 3 == end_u) FINALIZE();
            conv2_edge(v3, vr, av, acc0, acc1, s);
        }
        pos += 4;
    }
    while (u < 16) FINALIZE();
    #undef FINALIZE

    // --- phase 2: MLP via MFMA (A = 16 user rows, K=128) ---
    const int row = lane & 15;
    const int chunk = lane >> 4;
    bf16x8 a[4];
    #pragma unroll
    for (int ks = 0; ks < 4; ++ks)
        a[ks] = *(const bf16x8*)&xs[wid][row][ks * 32 + chunk * 8];

    const bf16x8* bfr = (const bf16x8*)Bp1;
    float racc[4] = {0.f, 0.f, 0.f, 0.f};
    #pragma unroll
    for (int g = 0; g < 4; ++g) {
        f32x4 acc = {0.f, 0.f, 0.f, 0.f};
        const int fi = g * 4;
        acc = __builtin_amdgcn_mfma_f32_16x16x32_bf16(a[0], bfr[(fi + 0) * 64 + lane], acc, 0, 0, 0);
        acc = __builtin_amdgcn_mfma_f32_16x16x32_bf16(a[1], bfr[(fi + 1) * 64 + lane], acc, 0, 0, 0);
        acc = __builtin_amdgcn_mfma_f32_16x16x32_bf16(a[2], bfr[(fi + 2) * 64 + lane], acc, 0, 0, 0);
        acc = __builtin_amdgcn_mfma_f32_16x16x32_bf16(a[3], bfr[(fi + 3) * 64 + lane], acc, 0, 0, 0);
        const int col = g * 16 + row;
        const float b1v = b1[col];
        const float w2v = W2[col];
        #pragma unroll
        for (int j = 0; j < 4; ++j)
            racc[j] = fmaf(fmaxf(acc[j] + b1v, 0.f), w2v, racc[j]);
    }
    #pragma unroll
    for (int j = 0; j < 4; ++j) {
        racc[j] += __shfl_xor(racc[j], 1, 16);
        racc[j] += __shfl_xor(racc[j], 2, 16);
        racc[j] += __shfl_xor(racc[j], 4, 16);
        racc[j] += __shfl_xor(racc[j], 8, 16);
    }
    if (row == 0) {
        const float b2v = b2[0];
        #pragma unroll
        for (int j = 0; j < 4; ++j) {
            const int r = u0 + chunk * 4 + j;
            if (r < nusr) out[r] = 1.f / (1.f + expf(-(racc[j] + b2v)));
        }
    }
}

// ---------------------------------------------------------------------------
extern "C" void kernel_launch(void* const* d_in, const int* in_sizes, int n_in,
                              void* d_out, int out_size, void* d_ws, size_t ws_size,
                              hipStream_t stream)
{
    const float* customer_x = (const float*)d_in[0];
    const float* fund_x     = (const float*)d_in[1];
    const float* edge_attr  = (const float*)d_in[2];
    const int*   edge_src   = (const int*)d_in[3];
    const int*   edge_dst   = (const int*)d_in[4];
    const float* user_W = (const float*)d_in[5];
    const float* user_b = (const float*)d_in[6];
    const float* item_W = (const float*)d_in[7];
    const float* item_b = (const float*)d_in[8];
    const float* c1_Wl  = (const float*)d_in[9];
    const float* c1_bl  = (const float*)d_in[10];
    const float* c1_Wr  = (const float*)d_in[11];
    const float* c1_br  = (const float*)d_in[12];
    const float* c1_We  = (const float*)d_in[13];
    const float* c1_att = (const float*)d_in[14];
    const float* c1_bias= (const float*)d_in[15];
    const float* c2_Wl  = (const float*)d_in[16];
    const float* c2_bl  = (const float*)d_in[17];
    const float* c2_Wr  = (const float*)d_in[18];
    const float* c2_br  = (const float*)d_in[19];
    const float* c2_att = (const float*)d_in[20];
    const float* c2_bias= (const float*)d_in[21];
    const float* cls_W1 = (const float*)d_in[22];
    const float* cls_b1 = (const float*)d_in[23];
    const float* cls_W2 = (const float*)d_in[24];
    const float* cls_b2 = (const float*)d_in[25];
    float* out = (float*)d_out;

    float* ws = (float*)d_ws;
    size_t off = 0;
    unsigned short* B1 = (unsigned short*)(ws + off); off += (size_t)NU * 64; // xl1 bf16
    unsigned short* B2 = (unsigned short*)(ws + off); off += (size_t)NU * 64; // xr2 bf16
    float* C = ws + off; off += (size_t)NI * HC;                              // xr1 fp32
    float* F = ws + off; off += (size_t)NI * HC;                              // item_h fp32
    unsigned short* G = (unsigned short*)(ws + off); off += (size_t)NI * 64;  // xl2 bf16
    int* cnt1  = (int*)(ws + off); off += NI;
    int* off1  = (int*)(ws + off); off += NI;
    int* cnt2  = (int*)(ws + off); off += NU;
    int* off2  = (int*)(ws + off); off += NU;
    int* bs    = (int*)(ws + off); off += 1024;
    int* bss   = (int*)(ws + off); off += 1024;
    uint4* sE1 = (uint4*)(ws + off); off += (size_t)NE * 4;
    int* sFund = (int*)(ws + off); off += NE;
    unsigned short* Bp = (unsigned short*)(ws + off); off += 12288 + 256;     // 96KB frags
    unsigned short* Bp1 = (unsigned short*)(ws + off); off += 4096 + 256;     // 16KB W1 frags
    float* wvbb = ws + off; off += 256;

    hipMemsetAsync(cnt1, 0, NI * sizeof(int), stream);
    hipMemsetAsync(cnt2, 0, NU * sizeof(int), stream);

    // CSR build
    hist_both<<<1024, 256, 0, stream>>>(edge_src, edge_dst, cnt2, cnt1, NE);
    const int nb1 = (NI + 1023) / 1024;
    const int nb2 = (NU + 1023) / 1024;
    scan_blocks<<<nb1, 256, 0, stream>>>(cnt1, off1, bs, NI);
    scan_blocks<<<1,   256, 0, stream>>>(bs, bss, nullptr, nb1);
    scan_add<<<nb1, 256, 0, stream>>>(off1, bss, NI);
    scan_blocks<<<nb2, 256, 0, stream>>>(cnt2, off2, bs, NU);
    scan_blocks<<<1,   256, 0, stream>>>(bs, bss, nullptr, nb2);
    scan_add<<<nb2, 256, 0, stream>>>(off2, bss, NU);
    scatter_both<<<1024, 256, 0, stream>>>(edge_src, edge_dst, edge_attr,
                                           off2, off1, sFund, sE1, NE);

    // weight prep
    wprep<<<192, 256, 0, stream>>>(user_W, user_b, c1_Wl, c1_bl,
                                   c2_Wr, c2_br, c2_Wl, Bp);
    w1prep<<<32, 256, 0, stream>>>(cls_W1, Bp1);
    wvbb_prep<<<1, 128, 0, stream>>>(item_W, item_b, c1_Wr, c1_br, wvbb);

    // xr1 = fund_x (rank-1) : [NI,128] fp32
    xr1_outer<<<2048, 256, 0, stream>>>(fund_x, wvbb, C, NI * HC);

    // xl1 & xr2 in one MFMA pass over customer_x
    mfma_user<<<(NU / 16 + 3) / 4, 256, 0, stream>>>(customer_x, Bp, B1, B2, NU);

    // conv1: customer -> fund (+bias+relu), fp32 out F
    conv1_fused<<<NI / 4, 256, 0, stream>>>((const unsigned int*)B1, C, off1, cnt1, sE1,
                                            c1_We, c1_att, c1_bias, F, NI);

    // xl2 = item_h @ c2_Wl + c2_bl (bf16)
    mfma_xl2<<<(NI / 16 + 3) / 4, 256, 0, stream>>>(F, Bp, c2_bl, G, NI);

    // conv2 + classifier fused: one wave per 16 users
    const int waves2 = (NU + 15) / 16;             // 31250
    conv2_cls<<<(waves2 + 3) / 4, 256, 0, stream>>>(
        (const unsigned int*)G, (const unsigned int*)B2, off2, cnt2, sFund,
        c2_att, c2_bias, Bp1, cls_b1, cls_W2, cls_b2, out, NU);
}

// Round 10
// 638.627 us; speedup vs baseline: 6.5474x; 1.0391x over previous
//
#include <hip/hip_runtime.h>
#include <cstdint>
#include <cstddef>

#define NU 500000
#define NI 50000
#define NE 1000000
#define HC 128   // H*C
#define NH 4

typedef __attribute__((ext_vector_type(8))) short bf16x8;
typedef __attribute__((ext_vector_type(4))) float f32x4;

union frag_u { bf16x8 v; unsigned int u[4]; };

// bf16 pack/unpack (RNE)
__device__ __forceinline__ unsigned int pack_bf2(float x, float y) {
    unsigned int xb = __float_as_uint(x);
    unsigned int yb = __float_as_uint(y);
    xb += 0x7fffu + ((xb >> 16) & 1u);
    yb += 0x7fffu + ((yb >> 16) & 1u);
    return (xb >> 16) | (yb & 0xffff0000u);
}
__device__ __forceinline__ float2 unpack_bf2(unsigned int v) {
    return make_float2(__uint_as_float(v << 16),
                       __uint_as_float(v & 0xffff0000u));
}
__device__ __forceinline__ unsigned short pack_bf1(float x) {
    unsigned int b = __float_as_uint(x);
    b += 0x7fffu + ((b >> 16) & 1u);
    return (unsigned short)(b >> 16);
}

__device__ __forceinline__ float head_reduce(float p) {
    p += __shfl_xor(p, 8, 16);
    p += __shfl_xor(p, 4, 16);
    p += __shfl_xor(p, 2, 16);
    p += __shfl_xor(p, 1, 16);
    return p;
}

// ---------------------------------------------------------------------------
// Weight prep: Bp holds 3 matrices in MFMA B-fragment order, bf16.
// ---------------------------------------------------------------------------
__global__ void wprep(const float* __restrict__ user_W, const float* __restrict__ user_b,
                      const float* __restrict__ c1_Wl, const float* __restrict__ c1_bl,
                      const float* __restrict__ c2_Wr, const float* __restrict__ c2_br,
                      const float* __restrict__ c2_Wl, unsigned short* __restrict__ Bp)
{
    const int t = blockIdx.x * 256 + threadIdx.x;   // 0..49151
    const int mat = t >> 14;
    const int k = (t >> 7) & 127;
    const int n = t & 127;
    float val = 0.f;
    if (mat == 2) {
        val = c2_Wl[k * 128 + n];
    } else {
        const float* W2 = mat ? c2_Wr : c1_Wl;
        if (k < 101) {
            for (int q = 0; q < 32; ++q) val = fmaf(user_W[k * 32 + q], W2[q * 128 + n], val);
        } else if (k == 101) {
            for (int q = 0; q < 32; ++q) val = fmaf(user_b[q], W2[q * 128 + n], val);
            val += (mat ? c2_br : c1_bl)[n];
        }
    }
    const int fi = (mat * 8 + (n >> 4)) * 4 + (k >> 5);
    const int lane_ = (n & 15) + ((k >> 3) & 3) * 16;
    Bp[(size_t)fi * 512 + lane_ * 8 + (k & 7)] = pack_bf1(val);
}

// ---------------------------------------------------------------------------
// W1 (classifier, 128x64) -> B-fragment order, 16 frags
// ---------------------------------------------------------------------------
__global__ void w1prep(const float* __restrict__ W1, unsigned short* __restrict__ Bp1)
{
    const int t = blockIdx.x * 256 + threadIdx.x;   // 0..8191
    const int k = t >> 6;
    const int n = t & 63;
    const float val = W1[k * 64 + n];
    const int fi = (n >> 4) * 4 + (k >> 5);
    const int lane_ = (n & 15) + ((k >> 3) & 3) * 16;
    Bp1[(size_t)fi * 512 + lane_ * 8 + (k & 7)] = pack_bf1(val);
}

// ---------------------------------------------------------------------------
// xr1 rank-1 weights
// ---------------------------------------------------------------------------
__global__ void wvbb_prep(const float* __restrict__ item_W, const float* __restrict__ item_b,
                          const float* __restrict__ c1_Wr, const float* __restrict__ c1_br,
                          float* __restrict__ wvbb)
{
    const int j = threadIdx.x;
    if (j >= 128) return;
    float wv = 0.f, bb = 0.f;
    for (int q = 0; q < 32; ++q) {
        wv = fmaf(item_W[q], c1_Wr[q * 128 + j], wv);
        bb = fmaf(item_b[q], c1_Wr[q * 128 + j], bb);
    }
    wvbb[j] = wv;
    wvbb[128 + j] = bb + c1_br[j];
}

__global__ void xr1_outer(const float* __restrict__ fund_x, const float* __restrict__ wvbb,
                          float* __restrict__ C, int n)
{
    for (int i = blockIdx.x * blockDim.x + threadIdx.x; i < n;
         i += gridDim.x * blockDim.x) {
        const int row = i >> 7, j = i & 127;
        C[i] = fmaf(fund_x[row], wvbb[j], wvbb[128 + j]);
    }
}

// ---------------------------------------------------------------------------
// MFMA: [NU,101(+bias)] fp32 @ Wc{1,2} -> xl1, xr2 (bf16).
// Block = 64 rows staged in LDS (coalesced); wave = 16 rows x 256 cols.
// LDS pitch 108 floats (432B): float4-aligned A-reads, 2-way free aliasing.
// D stored via per-wave LDS transpose -> 1KB coalesced dwordx4 stores.
// ---------------------------------------------------------------------------
__global__ __launch_bounds__(256)
void mfma_user(const float* __restrict__ cx, const unsigned short* __restrict__ Bp,
               unsigned short* __restrict__ outL, unsigned short* __restrict__ outR, int M)
{
    __shared__ float xs[64 * 108];   // 27648 B

    const int tid = threadIdx.x;
    const int lane = tid & 63;
    const int wid = tid >> 6;
    const int rowblk = blockIdx.x * 64;
    const int rows = min(64, M - rowblk);

    // stage: source region is contiguous (row pitch = 101 floats)
    const float* src = cx + (size_t)rowblk * 101;
    const int total = rows * 101;
    for (int i = tid; i < total; i += 256) {
        const int r = i / 101;
        const int c = i - r * 101;
        xs[r * 108 + c] = src[i];
    }
    __syncthreads();

    const int rowbase = wid * 16;            // within block
    if (rowbase >= rows) return;             // (M % 16 == 0 -> full waves only)
    const int row = lane & 15;
    const int chunk = lane >> 4;
    const float* rowp = xs + (rowbase + row) * 108;

    frag_u a[4];
    #pragma unroll
    for (int ks = 0; ks < 3; ++ks) {
        const int kb = ks * 32 + chunk * 8;
        const float4 p = *(const float4*)(rowp + kb);
        const float4 q = *(const float4*)(rowp + kb + 4);
        a[ks].u[0] = pack_bf2(p.x, p.y);
        a[ks].u[1] = pack_bf2(p.z, p.w);
        a[ks].u[2] = pack_bf2(q.x, q.y);
        a[ks].u[3] = pack_bf2(q.z, q.w);
    }
    {   // kstep 3: k 96..100 real, k=101 -> 1.0 (bias row), rest 0
        float v0 = 0.f, v1 = 0.f, v2 = 0.f, v3 = 0.f, v4 = 0.f, v5 = 0.f;
        if (chunk == 0) {
            const float4 p = *(const float4*)(rowp + 96);
            v0 = p.x; v1 = p.y; v2 = p.z; v3 = p.w;
            v4 = rowp[100];
            v5 = 1.0f;
        }
        a[3].u[0] = pack_bf2(v0, v1);
        a[3].u[1] = pack_bf2(v2, v3);
        a[3].u[2] = pack_bf2(v4, v5);
        a[3].u[3] = 0u;
    }

    // per-wave output slab overlays this wave's own staging region
    // (A-frags already in registers; DS ops within a wave execute in order)
    unsigned short* xpo = (unsigned short*)(xs + (size_t)wid * 16 * 108);

    const bf16x8* bfr = (const bf16x8*)Bp;
    #pragma unroll
    for (int mat = 0; mat < 2; ++mat) {
        unsigned short* outp = mat ? outR : outL;
        #pragma unroll
        for (int nf = 0; nf < 8; ++nf) {
            f32x4 acc = {0.f, 0.f, 0.f, 0.f};
            const int fi = (mat * 8 + nf) * 4;
            acc = __builtin_amdgcn_mfma_f32_16x16x32_bf16(a[0].v, bfr[(fi + 0) * 64 + lane], acc, 0, 0, 0);
            acc = __builtin_amdgcn_mfma_f32_16x16x32_bf16(a[1].v, bfr[(fi + 1) * 64 + lane], acc, 0, 0, 0);
            acc = __builtin_amdgcn_mfma_f32_16x16x32_bf16(a[2].v, bfr[(fi + 2) * 64 + lane], acc, 0, 0, 0);
            acc = __builtin_amdgcn_mfma_f32_16x16x32_bf16(a[3].v, bfr[(fi + 3) * 64 + lane], acc, 0, 0, 0);
            const int col = nf * 16 + row;
            #pragma unroll
            for (int j = 0; j < 4; ++j)
                xpo[(chunk * 4 + j) * 136 + col] = pack_bf1(acc[j]);
        }
        // coalesced write-out: 4 instrs x 1KB contiguous
        #pragma unroll
        for (int i = 0; i < 4; ++i) {
            const int r = i * 4 + chunk;
            const bf16x8 v = *(const bf16x8*)&xpo[r * 136 + row * 8];
            *(bf16x8*)(outp + (size_t)(rowblk + rowbase + r) * 128 + row * 8) = v;
        }
    }
}

// ---------------------------------------------------------------------------
// MFMA: xl2 = item_h[NI,128] @ c2_Wl + c2_bl -> bf16
// ---------------------------------------------------------------------------
__global__ __launch_bounds__(256)
void mfma_xl2(const float* __restrict__ X, const unsigned short* __restrict__ Bp,
              const float* __restrict__ bias, unsigned short* __restrict__ outp, int M)
{
    const int lane = threadIdx.x & 63;
    const int wt = (blockIdx.x * blockDim.x + threadIdx.x) >> 6;
    const int rowbase = wt * 16;
    if (rowbase >= M) return;
    const int chunk = lane >> 4;
    const float* rowp = X + (size_t)(rowbase + (lane & 15)) * 128;

    frag_u a[4];
    #pragma unroll
    for (int ks = 0; ks < 4; ++ks) {
        const int kb = ks * 32 + chunk * 8;
        const float4 p = *(const float4*)(rowp + kb);
        const float4 q = *(const float4*)(rowp + kb + 4);
        a[ks].u[0] = pack_bf2(p.x, p.y);
        a[ks].u[1] = pack_bf2(p.z, p.w);
        a[ks].u[2] = pack_bf2(q.x, q.y);
        a[ks].u[3] = pack_bf2(q.z, q.w);
    }

    const bf16x8* bfr = (const bf16x8*)Bp;
    #pragma unroll
    for (int nf = 0; nf < 8; ++nf) {
        f32x4 acc = {0.f, 0.f, 0.f, 0.f};
        const int fi = (16 + nf) * 4;   // mat 2
        acc = __builtin_amdgcn_mfma_f32_16x16x32_bf16(a[0].v, bfr[(fi + 0) * 64 + lane], acc, 0, 0, 0);
        acc = __builtin_amdgcn_mfma_f32_16x16x32_bf16(a[1].v, bfr[(fi + 1) * 64 + lane], acc, 0, 0, 0);
        acc = __builtin_amdgcn_mfma_f32_16x16x32_bf16(a[2].v, bfr[(fi + 2) * 64 + lane], acc, 0, 0, 0);
        acc = __builtin_amdgcn_mfma_f32_16x16x32_bf16(a[3].v, bfr[(fi + 3) * 64 + lane], acc, 0, 0, 0);
        const int col = nf * 16 + (lane & 15);
        const float bv = bias[col];
        #pragma unroll
        for (int j = 0; j < 4; ++j)
            outp[(size_t)(rowbase + chunk * 4 + j) * 128 + col] = pack_bf1(acc[j] + bv);
    }
}

// ---------------------------------------------------------------------------
// CSR build
// ---------------------------------------------------------------------------
__global__ void hist_both(const int* __restrict__ src, const int* __restrict__ dst,
                          int* __restrict__ cntU, int* __restrict__ cntI, int E)
{
    for (int i = blockIdx.x * blockDim.x + threadIdx.x; i < E;
         i += gridDim.x * blockDim.x) {
        atomicAdd(&cntU[src[i]], 1);
        atomicAdd(&cntI[dst[i]], 1);
    }
}

__global__ void scan_blocks(const int* __restrict__ in, int* __restrict__ out,
                            int* __restrict__ blockSums, int n)
{
    __shared__ int lds[256];
    const int tid = threadIdx.x;
    const int base = blockIdx.x * 1024 + tid * 4;
    int v[4];
    #pragma unroll
    for (int j = 0; j < 4; ++j) { int idx = base + j; v[j] = (idx < n) ? in[idx] : 0; }
    int t = v[0] + v[1] + v[2] + v[3];
    lds[tid] = t;
    __syncthreads();
    for (int off = 1; off < 256; off <<= 1) {
        int x = (tid >= off) ? lds[tid - off] : 0;
        __syncthreads();
        lds[tid] += x;
        __syncthreads();
    }
    int excl = lds[tid] - t;
    if (tid == 255 && blockSums) blockSums[blockIdx.x] = lds[255];
    int run = excl;
    #pragma unroll
    for (int j = 0; j < 4; ++j) {
        int idx = base + j;
        if (idx < n) out[idx] = run;
        run += v[j];
    }
}

__global__ void scan_add(int* __restrict__ out, const int* __restrict__ bss, int n)
{
    const int add = bss[blockIdx.x];
    const int base = blockIdx.x * 1024 + threadIdx.x * 4;
    #pragma unroll
    for (int j = 0; j < 4; ++j) { int idx = base + j; if (idx < n) out[idx] += add; }
}

__global__ void scatter_both(const int* __restrict__ src, const int* __restrict__ dst,
                             const float* __restrict__ eattr,
                             int* __restrict__ offU, int* __restrict__ offI,
                             int* __restrict__ sFund, uint4* __restrict__ sE1, int E)
{
    for (int i = blockIdx.x * blockDim.x + threadIdx.x; i < E;
         i += gridDim.x * blockDim.x) {
        const int s = src[i];
        const int d = dst[i];
        const float a0 = eattr[3 * (size_t)i];
        const float a1 = eattr[3 * (size_t)i + 1];
        const float a2 = eattr[3 * (size_t)i + 2];
        const int p1 = atomicAdd(&offI[d], 1);
        sE1[p1] = make_uint4((unsigned int)s, __float_as_uint(a0),
                             __float_as_uint(a1), __float_as_uint(a2));
        const int p2 = atomicAdd(&offU[s], 1);
        sFund[p2] = d;
    }
}

// ---------------------------------------------------------------------------
// conv1 fused: one wave per fund d; 8-deep gather pipeline.
// ---------------------------------------------------------------------------
__device__ __forceinline__ void conv1_edge(uint4 e, unsigned int vbits, float2 vr,
                                           float2 av, float2 w0, float2 w1, float2 w2,
                                           float& acc0, float& acc1, float& s)
{
    const float2 vl = unpack_bf2(vbits);
    const float e0 = __uint_as_float(e.y);
    const float e1 = __uint_as_float(e.z);
    const float e2 = __uint_as_float(e.w);
    float h0 = vl.x + vr.x + e0 * w0.x + e1 * w1.x + e2 * w2.x;
    float h1 = vl.y + vr.y + e0 * w0.y + e1 * w1.y + e2 * w2.y;
    h0 = h0 > 0.f ? h0 : 0.2f * h0;
    h1 = h1 > 0.f ? h1 : 0.2f * h1;
    const float p = head_reduce(h0 * av.x + h1 * av.y);
    const float ex = __expf(p);
    acc0 = fmaf(ex, vl.x, acc0);
    acc1 = fmaf(ex, vl.y, acc1);
    s += ex;
}

__global__ void conv1_fused(const unsigned int* __restrict__ xl,
                            const float* __restrict__ xr,
                            const int* __restrict__ off_end, const int* __restrict__ cnt,
                            const uint4* __restrict__ sE,
                            const float* __restrict__ We, const float* __restrict__ att,
                            const float* __restrict__ bias,
                            float* __restrict__ outF, int ndst)
{
    const int tid = threadIdx.x;
    const int lane = tid & 63;
    const int wid = tid >> 6;
    const int d = blockIdx.x * 4 + wid;
    if (d >= ndst) return;

    const int ch = lane * 2;
    const float2 av = *(const float2*)(att + ch);
    const float2 w0 = *(const float2*)(We + ch);
    const float2 w1 = *(const float2*)(We + HC + ch);
    const float2 w2 = *(const float2*)(We + 2 * HC + ch);
    const float2 bv = *(const float2*)(bias + ch);
    const float2 vr = *(const float2*)(xr + (size_t)d * HC + ch);

    const int end = off_end[d];
    const int start = end - cnt[d];

    float acc0 = 0.f, acc1 = 0.f, s = 0.f;
    int pos = start;
    for (; pos + 8 <= end; pos += 8) {
        uint4 e[8];
        unsigned int v[8];
        #pragma unroll
        for (int j = 0; j < 8; ++j) e[j] = sE[pos + j];
        #pragma unroll
        for (int j = 0; j < 8; ++j) v[j] = xl[(size_t)e[j].x * 64 + lane];
        #pragma unroll
        for (int j = 0; j < 8; ++j)
            conv1_edge(e[j], v[j], vr, av, w0, w1, w2, acc0, acc1, s);
    }
    for (; pos + 4 <= end; pos += 4) {
        uint4 e[4];
        unsigned int v[4];
        #pragma unroll
        for (int j = 0; j < 4; ++j) e[j] = sE[pos + j];
        #pragma unroll
        for (int j = 0; j < 4; ++j) v[j] = xl[(size_t)e[j].x * 64 + lane];
        #pragma unroll
        for (int j = 0; j < 4; ++j)
            conv1_edge(e[j], v[j], vr, av, w0, w1, w2, acc0, acc1, s);
    }
    for (; pos < end; ++pos) {
        const uint4 e = sE[pos];
        const unsigned int v = xl[(size_t)e.x * 64 + lane];
        conv1_edge(e, v, vr, av, w0, w1, w2, acc0, acc1, s);
    }
    const float inv = 1.f / (s + 1e-16f);
    const float o0 = fmaxf(acc0 * inv + bv.x, 0.f);
    const float o1 = fmaxf(acc1 * inv + bv.y, 0.f);
    *(float2*)(outF + (size_t)d * HC + ch) = make_float2(o0, o1);
}

// ---------------------------------------------------------------------------
// conv2 + classifier fused: one wave per 16 users, FLATTENED edge stream.
// ---------------------------------------------------------------------------
__device__ __forceinline__ void conv2_edge(unsigned int vbits, float2 vr, float2 av,
                                           float& acc0, float& acc1, float& s)
{
    const float2 vl = unpack_bf2(vbits);
    float h0 = vl.x + vr.x;
    float h1 = vl.y + vr.y;
    h0 = h0 > 0.f ? h0 : 0.2f * h0;
    h1 = h1 > 0.f ? h1 : 0.2f * h1;
    const float p = head_reduce(h0 * av.x + h1 * av.y);
    const float ex = __expf(p);
    acc0 = fmaf(ex, vl.x, acc0);
    acc1 = fmaf(ex, vl.y, acc1);
    s += ex;
}

__global__ __launch_bounds__(256)
void conv2_cls(const unsigned int* __restrict__ xl2,
               const unsigned int* __restrict__ xr2,
               const int* __restrict__ off_end, const int* __restrict__ cnt,
               const int* __restrict__ sFund,
               const float* __restrict__ att, const float* __restrict__ cbias,
               const unsigned short* __restrict__ Bp1,
               const float* __restrict__ b1, const float* __restrict__ W2,
               const float* __restrict__ b2,
               float* __restrict__ out, int nusr)
{
    __shared__ unsigned short xs[4][16][136];

    const int lane = threadIdx.x & 63;
    const int wid = threadIdx.x >> 6;
    const int wt = (blockIdx.x * blockDim.x + threadIdx.x) >> 6;
    const int u0 = wt * 16;
    if (u0 >= nusr) return;

    const int ch = lane * 2;
    const float2 av = *(const float2*)(att + ch);
    const float2 bv = *(const float2*)(cbias + ch);

    // lane-parallel offsets for this wave's 16 users (NU % 16 == 0)
    int eo = 0, ctv = 0;
    if (lane < 16) {
        eo = off_end[u0 + lane];
        ctv = cnt[u0 + lane];
    }
    const int S = __builtin_amdgcn_readlane(eo, 0) - __builtin_amdgcn_readlane(ctv, 0);
    const int E = __builtin_amdgcn_readlane(eo, 15);

    int u = 0;
    int end_u = __builtin_amdgcn_readlane(eo, 0);
    unsigned int vrb_next = xr2[(size_t)(u0 + 1) * 64 + lane];
    float2 vr = unpack_bf2(xr2[(size_t)u0 * 64 + lane]);
    float acc0 = 0.f, acc1 = 0.f, s = 0.f;

    #define FINALIZE() {                                                        \
        const float inv = 1.f / (s + 1e-16f);                                   \
        *(unsigned int*)&xs[wid][u][ch] = pack_bf2(acc0 * inv + bv.x,           \
                                                   acc1 * inv + bv.y);          \
        acc0 = acc1 = s = 0.f;                                                  \
        ++u;                                                                    \
        if (u < 16) {                                                           \
            end_u = __builtin_amdgcn_readlane(eo, u);                           \
            vr = unpack_bf2(vrb_next);                                          \
            if (u + 1 < 16) vrb_next = xr2[(size_t)(u0 + u + 1) * 64 + lane];   \
        }                                                                       \
    }

    int pos = S;
    while (pos < E) {
        const int f0 = sFund[pos];
        const int f1 = (pos + 1 < E) ? sFund[pos + 1] : f0;
        const int f2 = (pos + 2 < E) ? sFund[pos + 2] : f0;
        const int f3 = (pos + 3 < E) ? sFund[pos + 3] : f0;
        const unsigned int v0 = xl2[(size_t)f0 * 64 + lane];
        const unsigned int v1 = xl2[(size_t)f1 * 64 + lane];
        const unsigned int v2 = xl2[(size_t)f2 * 64 + lane];
        const unsigned int v3 = xl2[(size_t)f3 * 64 + lane];

        while (pos == end_u) FINALIZE();
        conv2_edge(v0, vr, av, acc0, acc1, s);
        if (pos + 1 < E) {
            while (pos + 1 == end_u) FINALIZE();
            conv2_edge(v1, vr, av, acc0, acc1, s);
        }
        if (pos + 2 < E) {
            while (pos + 2 == end_u) FINALIZE();
            conv2_edge(v2, vr, av, acc0, acc1, s);
        }
        if (pos + 3 < E) {
            while (pos + 3 == end_u) FINALIZE();
            conv2_edge(v3, vr, av, acc0, acc1, s);
        }
        pos += 4;
    }
    while (u < 16) FINALIZE();
    #undef FINALIZE

    // --- phase 2: MLP via MFMA (A = 16 user rows, K=128) ---
    const int row = lane & 15;
    const int chunk = lane >> 4;
    bf16x8 a[4];
    #pragma unroll
    for (int ks = 0; ks < 4; ++ks)
        a[ks] = *(const bf16x8*)&xs[wid][row][ks * 32 + chunk * 8];

    const bf16x8* bfr = (const bf16x8*)Bp1;
    float racc[4] = {0.f, 0.f, 0.f, 0.f};
    #pragma unroll
    for (int g = 0; g < 4; ++g) {
        f32x4 acc = {0.f, 0.f, 0.f, 0.f};
        const int fi = g * 4;
        acc = __builtin_amdgcn_mfma_f32_16x16x32_bf16(a[0], bfr[(fi + 0) * 64 + lane], acc, 0, 0, 0);
        acc = __builtin_amdgcn_mfma_f32_16x16x32_bf16(a[1], bfr[(fi + 1) * 64 + lane], acc, 0, 0, 0);
        acc = __builtin_amdgcn_mfma_f32_16x16x32_bf16(a[2], bfr[(fi + 2) * 64 + lane], acc, 0, 0, 0);
        acc = __builtin_amdgcn_mfma_f32_16x16x32_bf16(a[3], bfr[(fi + 3) * 64 + lane], acc, 0, 0, 0);
        const int col = g * 16 + row;
        const float b1v = b1[col];
        const float w2v = W2[col];
        #pragma unroll
        for (int j = 0; j < 4; ++j)
            racc[j] = fmaf(fmaxf(acc[j] + b1v, 0.f), w2v, racc[j]);
    }
    #pragma unroll
    for (int j = 0; j < 4; ++j) {
        racc[j] += __shfl_xor(racc[j], 1, 16);
        racc[j] += __shfl_xor(racc[j], 2, 16);
        racc[j] += __shfl_xor(racc[j], 4, 16);
        racc[j] += __shfl_xor(racc[j], 8, 16);
    }
    if (row == 0) {
        const float b2v = b2[0];
        #pragma unroll
        for (int j = 0; j < 4; ++j) {
            const int r = u0 + chunk * 4 + j;
            if (r < nusr) out[r] = 1.f / (1.f + expf(-(racc[j] + b2v)));
        }
    }
}

// ---------------------------------------------------------------------------
extern "C" void kernel_launch(void* const* d_in, const int* in_sizes, int n_in,
                              void* d_out, int out_size, void* d_ws, size_t ws_size,
                              hipStream_t stream)
{
    const float* customer_x = (const float*)d_in[0];
    const float* fund_x     = (const float*)d_in[1];
    const float* edge_attr  = (const float*)d_in[2];
    const int*   edge_src   = (const int*)d_in[3];
    const int*   edge_dst   = (const int*)d_in[4];
    const float* user_W = (const float*)d_in[5];
    const float* user_b = (const float*)d_in[6];
    const float* item_W = (const float*)d_in[7];
    const float* item_b = (const float*)d_in[8];
    const float* c1_Wl  = (const float*)d_in[9];
    const float* c1_bl  = (const float*)d_in[10];
    const float* c1_Wr  = (const float*)d_in[11];
    const float* c1_br  = (const float*)d_in[12];
    const float* c1_We  = (const float*)d_in[13];
    const float* c1_att = (const float*)d_in[14];
    const float* c1_bias= (const float*)d_in[15];
    const float* c2_Wl  = (const float*)d_in[16];
    const float* c2_bl  = (const float*)d_in[17];
    const float* c2_Wr  = (const float*)d_in[18];
    const float* c2_br  = (const float*)d_in[19];
    const float* c2_att = (const float*)d_in[20];
    const float* c2_bias= (const float*)d_in[21];
    const float* cls_W1 = (const float*)d_in[22];
    const float* cls_b1 = (const float*)d_in[23];
    const float* cls_W2 = (const float*)d_in[24];
    const float* cls_b2 = (const float*)d_in[25];
    float* out = (float*)d_out;

    float* ws = (float*)d_ws;
    size_t off = 0;
    unsigned short* B1 = (unsigned short*)(ws + off); off += (size_t)NU * 64; // xl1 bf16
    unsigned short* B2 = (unsigned short*)(ws + off); off += (size_t)NU * 64; // xr2 bf16
    float* C = ws + off; off += (size_t)NI * HC;                              // xr1 fp32
    float* F = ws + off; off += (size_t)NI * HC;                              // item_h fp32
    unsigned short* G = (unsigned short*)(ws + off); off += (size_t)NI * 64;  // xl2 bf16
    int* cnt1  = (int*)(ws + off); off += NI;
    int* off1  = (int*)(ws + off); off += NI;
    int* cnt2  = (int*)(ws + off); off += NU;
    int* off2  = (int*)(ws + off); off += NU;
    int* bs    = (int*)(ws + off); off += 1024;
    int* bss   = (int*)(ws + off); off += 1024;
    uint4* sE1 = (uint4*)(ws + off); off += (size_t)NE * 4;
    int* sFund = (int*)(ws + off); off += NE;
    unsigned short* Bp = (unsigned short*)(ws + off); off += 12288 + 256;     // 96KB frags
    unsigned short* Bp1 = (unsigned short*)(ws + off); off += 4096 + 256;     // 16KB W1 frags
    float* wvbb = ws + off; off += 256;

    hipMemsetAsync(cnt1, 0, NI * sizeof(int), stream);
    hipMemsetAsync(cnt2, 0, NU * sizeof(int), stream);

    // CSR build
    hist_both<<<1024, 256, 0, stream>>>(edge_src, edge_dst, cnt2, cnt1, NE);
    const int nb1 = (NI + 1023) / 1024;
    const int nb2 = (NU + 1023) / 1024;
    scan_blocks<<<nb1, 256, 0, stream>>>(cnt1, off1, bs, NI);
    scan_blocks<<<1,   256, 0, stream>>>(bs, bss, nullptr, nb1);
    scan_add<<<nb1, 256, 0, stream>>>(off1, bss, NI);
    scan_blocks<<<nb2, 256, 0, stream>>>(cnt2, off2, bs, NU);
    scan_blocks<<<1,   256, 0, stream>>>(bs, bss, nullptr, nb2);
    scan_add<<<nb2, 256, 0, stream>>>(off2, bss, NU);
    scatter_both<<<1024, 256, 0, stream>>>(edge_src, edge_dst, edge_attr,
                                           off2, off1, sFund, sE1, NE);

    // weight prep
    wprep<<<192, 256, 0, stream>>>(user_W, user_b, c1_Wl, c1_bl,
                                   c2_Wr, c2_br, c2_Wl, Bp);
    w1prep<<<32, 256, 0, stream>>>(cls_W1, Bp1);
    wvbb_prep<<<1, 128, 0, stream>>>(item_W, item_b, c1_Wr, c1_br, wvbb);

    // xr1 = fund_x (rank-1) : [NI,128] fp32
    xr1_outer<<<2048, 256, 0, stream>>>(fund_x, wvbb, C, NI * HC);

    // xl1 & xr2 in one MFMA pass over customer_x (64 rows/block, LDS-staged)
    mfma_user<<<(NU + 63) / 64, 256, 0, stream>>>(customer_x, Bp, B1, B2, NU);

    // conv1: customer -> fund (+bias+relu), fp32 out F
    conv1_fused<<<NI / 4, 256, 0, stream>>>((const unsigned int*)B1, C, off1, cnt1, sE1,
                                            c1_We, c1_att, c1_bias, F, NI);

    // xl2 = item_h @ c2_Wl + c2_bl (bf16)
    mfma_xl2<<<(NI / 16 + 3) / 4, 256, 0, stream>>>(F, Bp, c2_bl, G, NI);

    // conv2 + classifier fused: one wave per 16 users
    const int waves2 = (NU + 15) / 16;             // 31250
    conv2_cls<<<(waves2 + 3) / 4, 256, 0, stream>>>(
        (const unsigned int*)G, (const unsigned int*)B2, off2, cnt2, sFund,
        c2_att, c2_bias, Bp1, cls_b1, cls_W2, cls_b2, out, NU);
}